// Round 13
// baseline (978.725 us; speedup 1.0000x reference)
//
#include <hip/hip_runtime.h>
#include <math.h>
#include <float.h>

#define E0 131072
#define NN 32768
#define NB 1024
#define NSIDE 994
#define ETOT (E0 + NN)

typedef short bf16x8 __attribute__((ext_vector_type(8)));
typedef unsigned short ushort8 __attribute__((ext_vector_type(8)));
typedef float f32x4 __attribute__((ext_vector_type(4)));

__device__ inline float b2f(unsigned short u) { return __uint_as_float(((unsigned)u) << 16); }
__device__ inline unsigned short f2b(float f) {
  unsigned u = __float_as_uint(f);
  return (unsigned short)((u + 0x7fffu + ((u >> 16) & 1u)) >> 16);
}

__device__ inline void gload_lds16(const void* g, void* l) {
  __builtin_amdgcn_global_load_lds(
      (const __attribute__((address_space(1))) unsigned int*)g,
      (__attribute__((address_space(3))) unsigned int*)l, 16, 0, 0);
}

__global__ void fill_i32(int* p, int v, int n) {
  int i = blockIdx.x * blockDim.x + threadIdx.x;
  if (i < n) p[i] = v;
}

// ---------------- batched fp32 -> bf16 conversion with padding ----------------
struct CDesc { const float* in; unsigned short* out; int rowsOut, Rreal, C, Cp, wg_end; };
struct CBatch { CDesc d[5]; };
__global__ void conv_batch(CBatch cb) {
  int bid = blockIdx.x;
  int di = 0;
  while (bid >= cb.d[di].wg_end) ++di;
  const CDesc& g = cb.d[di];
  int rel = bid - (di ? cb.d[di - 1].wg_end : 0);
  size_t idx = (size_t)rel * 256 + threadIdx.x;
  size_t tot = (size_t)g.rowsOut * g.Cp;
  if (idx >= tot) return;
  int r = (int)(idx / g.Cp), c = (int)(idx % g.Cp);
  g.out[idx] = (r < g.Rreal && c < g.C) ? f2b(g.in[(size_t)r * g.C + c]) : (unsigned short)0;
}

// ---------------- batched transpose: W [K][N] f32 -> WT [Npad][Kp] bf16 ----------------
struct TDesc { const float* W; unsigned short* WT; int K, N, Kp, Npad, gx, wg_end; };
struct TBatch { TDesc d[16]; };
__global__ __launch_bounds__(256) void transpose_batch(TBatch tb) {
  __shared__ float t[32][33];
  int bid = blockIdx.x;
  int di = 0;
  while (bid >= tb.d[di].wg_end) ++di;
  const TDesc& g = tb.d[di];
  int rel = bid - (di ? tb.d[di - 1].wg_end : 0);
  int n0 = (rel % g.gx) * 32, k0 = (rel / g.gx) * 32;
  int tx = threadIdx.x & 31, ty = threadIdx.x >> 5;
  for (int r = ty; r < 32; r += 8) {
    int k = k0 + r, n = n0 + tx;
    t[r][tx] = (k < g.K && n < g.N) ? g.W[(size_t)k * g.N + n] : 0.f;
  }
  __syncthreads();
  for (int r = ty; r < 32; r += 8) {
    int n = n0 + r, k = k0 + tx;
    if (n < g.Npad && k < g.Kp)
      g.WT[(size_t)n * g.Kp + k] = (n < g.N) ? f2b(t[tx][r]) : (unsigned short)0;
  }
}

// ---------------- CSR build over dst ----------------
__global__ void count_deg(const int* __restrict__ ei, int* deg) {
  int e = blockIdx.x * blockDim.x + threadIdx.x;
  if (e >= ETOT) return;
  int dst = (e < E0) ? ei[E0 + e] : (e - E0);
  atomicAdd(&deg[dst], 1);
}

__global__ void scan_deg(const int* __restrict__ deg, int* rowptr, int* cursor) {
  __shared__ int part[1024];
  int tid = threadIdx.x;
  const int chunk = NN / 1024;  // 32
  int base = tid * chunk;
  int local[chunk];
  int sum = 0;
#pragma unroll
  for (int i = 0; i < chunk; ++i) { local[i] = sum; sum += deg[base + i]; }
  part[tid] = sum;
  __syncthreads();
  for (int off = 1; off < 1024; off <<= 1) {
    int t = (tid >= off) ? part[tid - off] : 0;
    __syncthreads();
    part[tid] += t;
    __syncthreads();
  }
  int offset = part[tid] - sum;
#pragma unroll
  for (int i = 0; i < chunk; ++i) {
    int v = offset + local[i];
    rowptr[base + i] = v;
    cursor[base + i] = v;
  }
  if (tid == 1023) rowptr[NN] = offset + sum;
}

__global__ void fill_csr(const int* __restrict__ ei, int* cursor, int* __restrict__ srcl) {
  int e = blockIdx.x * blockDim.x + threadIdx.x;
  if (e >= ETOT) return;
  int src, dst;
  if (e < E0) { src = ei[e]; dst = ei[E0 + e]; } else { src = dst = e - E0; }
  int p = atomicAdd(&cursor[dst], 1);
  srcl[p] = src;
}

// ---------------- bf16 MFMA GEMM, single-buffer LDS; optional fused GAT scores ----------
// (explicit dbuf reverted: m99/m100 lesson — implicit wave overlap wins and 16KB LDS
// keeps ~2x the resident blocks; measured round8 vs round12: 118 vs 130 us on g2/g3)
template <int ACT, int OBF, int SC>
__global__ __launch_bounds__(256) void gemm_mfma(
    const unsigned short* __restrict__ A, const unsigned short* __restrict__ BT,
    const float* __restrict__ bias, void* __restrict__ Cp,
    int Nreal, int K, int lda, int ldb, int ldc, int gx, int zpad,
    const float* __restrict__ asv, const float* __restrict__ adv,
    float* __restrict__ als, float* __restrict__ ald, int H) {
  __shared__ unsigned short As[128 * 32];
  __shared__ unsigned short Bs[128 * 32];
  const int nwg = gridDim.x;
  const int chunk = nwg >> 3;
  const int bid = blockIdx.x;
  const int swz = (bid & 7) * chunk + (bid >> 3);
  const int bm = (swz / gx) * 128, bn = (swz % gx) * 128;
  const int tid = threadIdx.x;
  const int wv = tid >> 6, lane = tid & 63;
  const int sr = lane >> 2;
  const int sk = ((lane & 3) ^ ((lane >> 3) & 3)) * 8;
  const int r16 = lane & 15, kq = lane >> 4;
  const int slot8 = (kq ^ ((r16 >> 1) & 3)) * 8;
  const int wr = wv >> 1, wc = wv & 1;
  f32x4 acc[4][4];
#pragma unroll
  for (int i = 0; i < 4; ++i)
#pragma unroll
    for (int j = 0; j < 4; ++j) acc[i][j] = (f32x4){0.f, 0.f, 0.f, 0.f};

  const unsigned short* Abase = A + (size_t)bm * lda;
  const unsigned short* Bbase = BT + (size_t)bn * ldb;
  for (int k0 = 0; k0 < K; k0 += 32) {
    gload_lds16(Abase + (size_t)(wv * 16 + sr) * lda + k0 + sk, &As[wv * 512]);
    gload_lds16(Abase + (size_t)(64 + wv * 16 + sr) * lda + k0 + sk, &As[2048 + wv * 512]);
    gload_lds16(Bbase + (size_t)(wv * 16 + sr) * ldb + k0 + sk, &Bs[wv * 512]);
    gload_lds16(Bbase + (size_t)(64 + wv * 16 + sr) * ldb + k0 + sk, &Bs[2048 + wv * 512]);
    __syncthreads();
    bf16x8 af[4], bfr[4];
#pragma unroll
    for (int i = 0; i < 4; ++i)
      af[i] = *(const bf16x8*)&As[(wr * 64 + i * 16 + r16) * 32 + slot8];
#pragma unroll
    for (int j = 0; j < 4; ++j)
      bfr[j] = *(const bf16x8*)&Bs[(wc * 64 + j * 16 + r16) * 32 + slot8];
#pragma unroll
    for (int i = 0; i < 4; ++i)
#pragma unroll
      for (int j = 0; j < 4; ++j)
        acc[i][j] = __builtin_amdgcn_mfma_f32_16x16x32_bf16(af[i], bfr[j], acc[i][j], 0, 0, 0);
    __syncthreads();
  }
#pragma unroll
  for (int i = 0; i < 4; ++i) {
    int row = bm + wr * 64 + i * 16 + kq * 4;
#pragma unroll
    for (int j = 0; j < 4; ++j) {
      int col = bn + wc * 64 + j * 16 + r16;
      bool real = col < Nreal;
      if (!real && !zpad) continue;
      float bv = (bias && real) ? bias[col] : 0.f;
#pragma unroll
      for (int r = 0; r < 4; ++r) {
        float v = acc[i][j][r] + bv;
        if (ACT == 1) v = v > 0.f ? v : 0.f;
        else if (ACT == 2) v = tanhf(v);
        else if (ACT == 3) v = fabsf(tanhf(v));
        if (!real) v = 0.f;
        if (OBF) ((unsigned short*)Cp)[(size_t)(row + r) * ldc + col] = f2b(v);
        else ((float*)Cp)[(size_t)(row + r) * ldc + col] = v;
      }
    }
  }
  if (SC) {
    // fused GAT scores: head h spans exactly this block's 128 cols
    const int h = bn >> 7;
    float* scr = (float*)&As[0];  // 128 rows x {wc0_s, wc0_d, wc1_s, wc1_d} = 2KB
    float a_s[4], a_d[4];
#pragma unroll
    for (int j = 0; j < 4; ++j) {
      int cwh = wc * 64 + j * 16 + r16;
      a_s[j] = asv[h * 128 + cwh];
      a_d[j] = adv[h * 128 + cwh];
    }
    __syncthreads();
#pragma unroll
    for (int i = 0; i < 4; ++i)
#pragma unroll
      for (int r = 0; r < 4; ++r) {
        float sp = 0.f, dp = 0.f;
#pragma unroll
        for (int j = 0; j < 4; ++j) {
          sp = fmaf(acc[i][j][r], a_s[j], sp);
          dp = fmaf(acc[i][j][r], a_d[j], dp);
        }
#pragma unroll
        for (int m = 1; m < 16; m <<= 1) {
          sp += __shfl_xor(sp, m);
          dp += __shfl_xor(dp, m);
        }
        if (r16 == 0) {
          int rl = wr * 64 + i * 16 + kq * 4 + r;
          scr[rl * 4 + wc * 2 + 0] = sp;
          scr[rl * 4 + wc * 2 + 1] = dp;
        }
      }
    __syncthreads();
    if (tid < 128) {
      float s = scr[tid * 4 + 0] + scr[tid * 4 + 2];
      float d = scr[tid * 4 + 1] + scr[tid * 4 + 3];
      als[(size_t)(bm + tid) * H + h] = s;
      ald[(size_t)(bm + tid) * H + h] = d;
    }
  }
}

// ---------------- batched runtime-act MFMA GEMM (single-buffer) ----------------
// act: 0 none, 1 relu, 2 tanh, 3 abs(tanh), 4 tanh+rownorm (f32 out, row<Mreal guard)
struct GDesc {
  const unsigned short* A; const unsigned short* BT; const float* bias; void* C;
  int Nreal, K, lda, ldb, ldc, gx, zpad, act, obf, Mreal, wg_end;
};
struct GBatch { GDesc d[5]; };
__global__ __launch_bounds__(256) void gemm_batch(GBatch gb) {
  __shared__ unsigned short As[128 * 32];
  __shared__ unsigned short Bs[128 * 32];
  int bid = blockIdx.x;
  int di = 0;
  while (bid >= gb.d[di].wg_end) ++di;
  const GDesc& g = gb.d[di];
  int rel = bid - (di ? gb.d[di - 1].wg_end : 0);
  const int bm = (rel / g.gx) * 128, bn = (rel % g.gx) * 128;
  const int tid = threadIdx.x;
  const int wv = tid >> 6, lane = tid & 63;
  const int sr = lane >> 2;
  const int sk = ((lane & 3) ^ ((lane >> 3) & 3)) * 8;
  const int r16 = lane & 15, kq = lane >> 4;
  const int slot8 = (kq ^ ((r16 >> 1) & 3)) * 8;
  const int wr = wv >> 1, wc = wv & 1;
  f32x4 acc[4][4];
#pragma unroll
  for (int i = 0; i < 4; ++i)
#pragma unroll
    for (int j = 0; j < 4; ++j) acc[i][j] = (f32x4){0.f, 0.f, 0.f, 0.f};

  const unsigned short* Abase = g.A + (size_t)bm * g.lda;
  const unsigned short* Bbase = g.BT + (size_t)bn * g.ldb;
  for (int k0 = 0; k0 < g.K; k0 += 32) {
    gload_lds16(Abase + (size_t)(wv * 16 + sr) * g.lda + k0 + sk, &As[wv * 512]);
    gload_lds16(Abase + (size_t)(64 + wv * 16 + sr) * g.lda + k0 + sk, &As[2048 + wv * 512]);
    gload_lds16(Bbase + (size_t)(wv * 16 + sr) * g.ldb + k0 + sk, &Bs[wv * 512]);
    gload_lds16(Bbase + (size_t)(64 + wv * 16 + sr) * g.ldb + k0 + sk, &Bs[2048 + wv * 512]);
    __syncthreads();
    bf16x8 af[4], bfr[4];
#pragma unroll
    for (int i = 0; i < 4; ++i)
      af[i] = *(const bf16x8*)&As[(wr * 64 + i * 16 + r16) * 32 + slot8];
#pragma unroll
    for (int j = 0; j < 4; ++j)
      bfr[j] = *(const bf16x8*)&Bs[(wc * 64 + j * 16 + r16) * 32 + slot8];
#pragma unroll
    for (int i = 0; i < 4; ++i)
#pragma unroll
      for (int j = 0; j < 4; ++j)
        acc[i][j] = __builtin_amdgcn_mfma_f32_16x16x32_bf16(af[i], bfr[j], acc[i][j], 0, 0, 0);
    __syncthreads();
  }
  if (g.act == 4) {
    if (wc == 0) {
#pragma unroll
      for (int i = 0; i < 4; ++i)
#pragma unroll
        for (int r = 0; r < 4; ++r) {
          int row = bm + wr * 64 + i * 16 + kq * 4 + r;
          float vv[4];
#pragma unroll
          for (int j = 0; j < 4; ++j) vv[j] = tanhf(acc[i][j][r] + g.bias[j * 16 + r16]);
          float ss = vv[0] * vv[0] + vv[1] * vv[1] + vv[2] * vv[2] + vv[3] * vv[3];
          ss += __shfl_xor(ss, 1);
          ss += __shfl_xor(ss, 2);
          ss += __shfl_xor(ss, 4);
          ss += __shfl_xor(ss, 8);
          float inv = 1.f / fmaxf(sqrtf(ss), 1e-12f);
          if (row < g.Mreal)
#pragma unroll
            for (int j = 0; j < 4; ++j)
              ((float*)g.C)[(size_t)row * g.ldc + j * 16 + r16] = vv[j] * inv;
        }
    }
    return;
  }
#pragma unroll
  for (int i = 0; i < 4; ++i) {
    int row = bm + wr * 64 + i * 16 + kq * 4;
#pragma unroll
    for (int j = 0; j < 4; ++j) {
      int col = bn + wc * 64 + j * 16 + r16;
      bool real = col < g.Nreal;
      if (!real && !g.zpad) continue;
      float bv = (g.bias && real) ? g.bias[col] : 0.f;
#pragma unroll
      for (int r = 0; r < 4; ++r) {
        float v = acc[i][j][r] + bv;
        if (g.act == 1) v = v > 0.f ? v : 0.f;
        else if (g.act == 2) v = tanhf(v);
        else if (g.act == 3) v = fabsf(tanhf(v));
        if (!real) v = 0.f;
        if (g.obf) ((unsigned short*)g.C)[(size_t)(row + r) * g.ldc + col] = f2b(v);
        else ((float*)g.C)[(size_t)(row + r) * g.ldc + col] = v;
      }
    }
  }
}

// ---------------- split-K MFMA GEMM for z1 (single-buffer, f32 partials) ----------------
__global__ __launch_bounds__(256) void gemm_mfma_sk(
    const unsigned short* __restrict__ A, const unsigned short* __restrict__ BT,
    float* __restrict__ PART, int lda, int ldb, int ldc) {
  __shared__ unsigned short As[128 * 32];
  __shared__ unsigned short Bs[128 * 32];
  const int bid = blockIdx.x;
  const int swz = (bid & 7) * 208 + (bid >> 3);
  const int s = swz / 104;
  const int pos = swz - s * 104;
  const int bm = (pos / 13) * 128, bn = (pos % 13) * 128;
  const int base = s * 37 + (s < 6 ? s : 6);
  const int nsteps = 37 + (s < 6 ? 1 : 0);
  const int tid = threadIdx.x;
  const int wv = tid >> 6, lane = tid & 63;
  const int sr = lane >> 2;
  const int sk = ((lane & 3) ^ ((lane >> 3) & 3)) * 8;
  const int r16 = lane & 15, kq = lane >> 4;
  const int slot8 = (kq ^ ((r16 >> 1) & 3)) * 8;
  const int wr = wv >> 1, wc = wv & 1;
  f32x4 acc[4][4];
#pragma unroll
  for (int i = 0; i < 4; ++i)
#pragma unroll
    for (int j = 0; j < 4; ++j) acc[i][j] = (f32x4){0.f, 0.f, 0.f, 0.f};

  const unsigned short* Abase = A + (size_t)bm * lda;
  const unsigned short* Bbase = BT + (size_t)bn * ldb;
  for (int ks = 0; ks < nsteps; ++ks) {
    int k0 = (base + ks) * 32;
    gload_lds16(Abase + (size_t)(wv * 16 + sr) * lda + k0 + sk, &As[wv * 512]);
    gload_lds16(Abase + (size_t)(64 + wv * 16 + sr) * lda + k0 + sk, &As[2048 + wv * 512]);
    gload_lds16(Bbase + (size_t)(wv * 16 + sr) * ldb + k0 + sk, &Bs[wv * 512]);
    gload_lds16(Bbase + (size_t)(64 + wv * 16 + sr) * ldb + k0 + sk, &Bs[2048 + wv * 512]);
    __syncthreads();
    bf16x8 af[4], bfr[4];
#pragma unroll
    for (int i = 0; i < 4; ++i)
      af[i] = *(const bf16x8*)&As[(wr * 64 + i * 16 + r16) * 32 + slot8];
#pragma unroll
    for (int j = 0; j < 4; ++j)
      bfr[j] = *(const bf16x8*)&Bs[(wc * 64 + j * 16 + r16) * 32 + slot8];
#pragma unroll
    for (int i = 0; i < 4; ++i)
#pragma unroll
      for (int j = 0; j < 4; ++j)
        acc[i][j] = __builtin_amdgcn_mfma_f32_16x16x32_bf16(af[i], bfr[j], acc[i][j], 0, 0, 0);
    __syncthreads();
  }
  float* out = PART + (size_t)s * 1024 * ldc;
#pragma unroll
  for (int i = 0; i < 4; ++i) {
    int row = bm + wr * 64 + i * 16 + kq * 4;
#pragma unroll
    for (int j = 0; j < 4; ++j) {
      int col = bn + wc * 64 + j * 16 + r16;
      if (col >= 1600) continue;
#pragma unroll
      for (int r = 0; r < 4; ++r)
        out[(size_t)(row + r) * ldc + col] = acc[i][j][r];
    }
  }
}

// reduce 16 f32 K-slice partials + bias + relu -> ZB bf16 [1024][1664], float4 vectorized
__global__ void zred(const float* __restrict__ PART, const float* __restrict__ bias,
                     unsigned short* __restrict__ ZB) {
  int g = blockIdx.x * blockDim.x + threadIdx.x;
  if (g >= 1024 * 1664 / 8) return;
  size_t base = (size_t)g * 8;
  int c0 = (int)(base % 1664);
  ushort8 o;
  if (c0 >= 1600) {
#pragma unroll
    for (int t = 0; t < 8; ++t) o[t] = 0;
  } else {
    float s[8] = {0.f, 0.f, 0.f, 0.f, 0.f, 0.f, 0.f, 0.f};
#pragma unroll
    for (int k = 0; k < 16; ++k) {
      const float* p = &PART[(size_t)k * 1024 * 1664 + base];
      float4 a = *(const float4*)p;
      float4 b = *(const float4*)(p + 4);
      s[0] += a.x; s[1] += a.y; s[2] += a.z; s[3] += a.w;
      s[4] += b.x; s[5] += b.y; s[6] += b.z; s[7] += b.w;
    }
#pragma unroll
    for (int t = 0; t < 8; ++t) {
      float v = s[t] + bias[c0 + t];
      o[t] = f2b(v > 0.f ? v : 0.f);
    }
  }
  *(ushort8*)&ZB[base] = o;
}

// ---------------- fused tail: agg GEMM -> LDS -> col GEMM -> |tanh| -> rownorm -> DN ----
__global__ __launch_bounds__(256) void tail_fused(
    const unsigned short* __restrict__ CAT192, const unsigned short* __restrict__ WTAGG,
    const float* __restrict__ agg_b, const unsigned short* __restrict__ CAT128,
    const unsigned short* __restrict__ WTCOL, const float* __restrict__ col_b,
    float* __restrict__ DN) {
  __shared__ unsigned short S1[128 * 32];
  __shared__ unsigned short S2[128 * 32];
  __shared__ unsigned short ACAT[128 * 128];
  const int bm = blockIdx.x * 128;
  const int tid = threadIdx.x;
  const int wv = tid >> 6, lane = tid & 63;
  const int sr = lane >> 2;
  const int sk = ((lane & 3) ^ ((lane >> 3) & 3)) * 8;
  const int r16 = lane & 15, kq = lane >> 4;
  const int slot8 = (kq ^ ((r16 >> 1) & 3)) * 8;
  const int wr = wv >> 1, wc = wv & 1;
  f32x4 acc[4][4];
#pragma unroll
  for (int i = 0; i < 4; ++i)
#pragma unroll
    for (int j = 0; j < 4; ++j) acc[i][j] = (f32x4){0.f, 0.f, 0.f, 0.f};

  const unsigned short* Abase = CAT192 + (size_t)bm * 192;
  for (int k0 = 0; k0 < 192; k0 += 32) {
    gload_lds16(Abase + (size_t)(wv * 16 + sr) * 192 + k0 + sk, &S1[wv * 512]);
    gload_lds16(Abase + (size_t)(64 + wv * 16 + sr) * 192 + k0 + sk, &S1[2048 + wv * 512]);
    gload_lds16(WTAGG + (size_t)(wv * 16 + sr) * 192 + k0 + sk, &S2[wv * 512]);
    gload_lds16(WTAGG + (size_t)(64 + wv * 16 + sr) * 192 + k0 + sk, &S2[2048 + wv * 512]);
    __syncthreads();
    bf16x8 af[4], bfr[4];
#pragma unroll
    for (int i = 0; i < 4; ++i)
      af[i] = *(const bf16x8*)&S1[(wr * 64 + i * 16 + r16) * 32 + slot8];
#pragma unroll
    for (int j = 0; j < 4; ++j)
      bfr[j] = *(const bf16x8*)&S2[(wc * 64 + j * 16 + r16) * 32 + slot8];
#pragma unroll
    for (int i = 0; i < 4; ++i)
#pragma unroll
      for (int j = 0; j < 4; ++j)
        acc[i][j] = __builtin_amdgcn_mfma_f32_16x16x32_bf16(af[i], bfr[j], acc[i][j], 0, 0, 0);
    __syncthreads();
  }
  if (wc == 0) {
#pragma unroll
    for (int i = 0; i < 4; ++i)
#pragma unroll
      for (int j = 0; j < 4; ++j) {
        int col = j * 16 + r16;
#pragma unroll
        for (int r = 0; r < 4; ++r) {
          int rl = wr * 64 + i * 16 + kq * 4 + r;
          ACAT[rl * 128 + col] = f2b(acc[i][j][r] + agg_b[col]);
        }
      }
  }
  for (int idx = tid; idx < 128 * 8; idx += 256) {
    int row = idx >> 3, c8 = (idx & 7) * 8;
    *(ushort8*)&ACAT[row * 128 + 64 + c8] =
        *(const ushort8*)&CAT128[(size_t)(bm + row) * 128 + 64 + c8];
  }
#pragma unroll
  for (int i = 0; i < 4; ++i)
#pragma unroll
    for (int j = 0; j < 4; ++j) acc[i][j] = (f32x4){0.f, 0.f, 0.f, 0.f};
  __syncthreads();

  for (int k0 = 0; k0 < 128; k0 += 32) {
    gload_lds16(WTCOL + (size_t)(wv * 16 + sr) * 128 + k0 + sk, &S1[wv * 512]);
    gload_lds16(WTCOL + (size_t)(64 + wv * 16 + sr) * 128 + k0 + sk, &S1[2048 + wv * 512]);
    __syncthreads();
    bf16x8 af[4], bfr[4];
#pragma unroll
    for (int i = 0; i < 4; ++i)
      af[i] = *(const bf16x8*)&ACAT[(wr * 64 + i * 16 + r16) * 128 + k0 + kq * 8];
#pragma unroll
    for (int j = 0; j < 4; ++j)
      bfr[j] = *(const bf16x8*)&S1[(wc * 64 + j * 16 + r16) * 32 + slot8];
#pragma unroll
    for (int i = 0; i < 4; ++i)
#pragma unroll
      for (int j = 0; j < 4; ++j)
        acc[i][j] = __builtin_amdgcn_mfma_f32_16x16x32_bf16(af[i], bfr[j], acc[i][j], 0, 0, 0);
    __syncthreads();
  }
  if (wc == 0) {
#pragma unroll
    for (int i = 0; i < 4; ++i)
#pragma unroll
      for (int r = 0; r < 4; ++r) {
        int row = bm + wr * 64 + i * 16 + kq * 4 + r;
        float vv[4];
#pragma unroll
        for (int j = 0; j < 4; ++j) vv[j] = fabsf(tanhf(acc[i][j][r] + col_b[j * 16 + r16]));
        float ss = vv[0] * vv[0] + vv[1] * vv[1] + vv[2] * vv[2] + vv[3] * vv[3];
        ss += __shfl_xor(ss, 1);
        ss += __shfl_xor(ss, 2);
        ss += __shfl_xor(ss, 4);
        ss += __shfl_xor(ss, 8);
        float inv = 1.f / fmaxf(sqrtf(ss), 1e-12f);
#pragma unroll
        for (int j = 0; j < 4; ++j)
          DN[(size_t)row * 64 + j * 16 + r16] = vv[j] * inv;
      }
  }
}

// ---------------- GAT pieces ----------------
__global__ void gat_scores_bf(const unsigned short* __restrict__ hlin,
                              const float* __restrict__ a_s, const float* __restrict__ a_d,
                              float* __restrict__ als, float* __restrict__ ald,
                              int H, int C, int tot) {
  int idx = blockIdx.x * blockDim.x + threadIdx.x;
  if (idx >= tot) return;
  int n = idx / H, h = idx - n * H;
  const unsigned short* base = hlin + (size_t)n * H * C + (size_t)h * C;
  const float* as = a_s + h * C;
  const float* ad = a_d + h * C;
  float ss = 0.f, sd = 0.f;
  for (int c = 0; c < C; c += 8) {
    ushort8 v = *(const ushort8*)(base + c);
#pragma unroll
    for (int t = 0; t < 8; ++t) {
      float f = b2f(v[t]);
      ss = fmaf(f, as[c + t], ss);
      sd = fmaf(f, ad[c + t], sd);
    }
  }
  als[idx] = ss;
  ald[idx] = sd;
}

// aggregate with INLINE attention: p = exp(lrelu(als[src]+ald[node])) computed in-loop.
template <int F, int C>
__global__ __launch_bounds__(256) void gat_agg_v4(
    const int* __restrict__ rowptr, const int* __restrict__ srcl,
    const float* __restrict__ als, const float* __restrict__ ald,
    const unsigned short* __restrict__ hlin,
    const float* __restrict__ bias, unsigned short* __restrict__ out) {
  constexpr int H = F / C;
  constexpr int CPN = F / 8;
  int gidx = blockIdx.x * 256 + threadIdx.x;
  if (gidx >= NN * CPN) return;
  int node = gidx / CPN;
  int c0 = (gidx - node * CPN) * 8;
  int h = c0 / C;
  float aldv = ald[node * H + h];
  float s = 0.f;
  float acc[8] = {0.f, 0.f, 0.f, 0.f, 0.f, 0.f, 0.f, 0.f};
  int start = rowptr[node], end = rowptr[node + 1];
  for (int k = start; k < end; ++k) {
    int src = srcl[k];
    float e = als[src * H + h] + aldv;
    e = (e >= 0.f) ? e : 0.2f * e;
    float p = __expf(e);
    s += p;
    ushort8 hv = *(const ushort8*)(hlin + (size_t)src * F + c0);
#pragma unroll
    for (int t = 0; t < 8; ++t) acc[t] = fmaf(p, b2f(hv[t]), acc[t]);
  }
  float inv_s = 1.f / s;
  ushort8 o;
#pragma unroll
  for (int t = 0; t < 8; ++t) {
    float val = acc[t] * inv_s + bias[c0 + t];
    o[t] = f2b(val > 0.f ? val : 0.f);
  }
  *(ushort8*)(out + (size_t)node * F + c0) = o;
}

__global__ void pool_max(const unsigned short* __restrict__ xb,
                         unsigned short* __restrict__ xgb) {
  int g = blockIdx.x, c = threadIdx.x;  // 128 threads
  const unsigned short* base = xb + (size_t)g * 32 * 128 + c;
  float m = -FLT_MAX;
#pragma unroll 8
  for (int n = 0; n < 32; ++n) m = fmaxf(m, b2f(base[n * 128]));
  xgb[g * 128 + c] = f2b(m);
}

__global__ __launch_bounds__(256) void freq_k(const float* __restrict__ dn,
                                              const float* __restrict__ sn,
                                              float* __restrict__ C, int M, int N) {
  __shared__ float As[16][64];
  __shared__ float Bs[16][65];
  int tid = threadIdx.x;
  int tx = tid & 15, ty = tid >> 4;
  int bi = blockIdx.y * 16, bj = blockIdx.x * 16;
#pragma unroll
  for (int t = 0; t < 4; ++t) {
    int idx = tid * 4 + t;
    int r = idx >> 6, c = idx & 63;
    As[r][c] = (bi + r < M) ? dn[(bi + r) * 64 + c] : 0.f;
    Bs[r][c] = (bj + r < N) ? sn[(bj + r) * 64 + c] : 0.f;
  }
  __syncthreads();
  float acc = 0.f;
#pragma unroll
  for (int k = 0; k < 64; ++k) acc = fmaf(As[ty][k], Bs[tx][k], acc);
  if (bi + ty < M && bj + tx < N) C[(size_t)(bi + ty) * N + (bj + tx)] = 5.f * acc;
}

// ---------------- launch ----------------
extern "C" void kernel_launch(void* const* d_in, const int* in_sizes, int n_in,
                              void* d_out, int out_size, void* d_ws, size_t ws_size,
                              hipStream_t stream) {
  const float* x = (const float*)d_in[0];
  const int* ei = (const int*)d_in[1];
  const float* w = (const float*)d_in[3];
  const float* z = (const float*)d_in[4];
  const float* v = (const float*)d_in[5];
  const float* side = (const float*)d_in[6];
  const float* gW[4] = {(const float*)d_in[7], (const float*)d_in[11],
                        (const float*)d_in[15], (const float*)d_in[19]};
  const float* gas[4] = {(const float*)d_in[8], (const float*)d_in[12],
                         (const float*)d_in[16], (const float*)d_in[20]};
  const float* gad[4] = {(const float*)d_in[9], (const float*)d_in[13],
                         (const float*)d_in[17], (const float*)d_in[21]};
  const float* gb[4] = {(const float*)d_in[10], (const float*)d_in[14],
                        (const float*)d_in[18], (const float*)d_in[22]};
  const float* x5_W = (const float*)d_in[23]; const float* x5_b = (const float*)d_in[24];
  const float* x6_W = (const float*)d_in[25]; const float* x6_b = (const float*)d_in[26];
  const float* w1_W = (const float*)d_in[27]; const float* w1_b = (const float*)d_in[28];
  const float* w2_W = (const float*)d_in[29]; const float* w2_b = (const float*)d_in[30];
  const float* z1_W = (const float*)d_in[31]; const float* z1_b = (const float*)d_in[32];
  const float* z2_W = (const float*)d_in[33]; const float* z2_b = (const float*)d_in[34];
  const float* v1_W = (const float*)d_in[35]; const float* v1_b = (const float*)d_in[36];
  const float* v2_W = (const float*)d_in[37]; const float* v2_b = (const float*)d_in[38];
  const float* agg_W = (const float*)d_in[39]; const float* agg_b = (const float*)d_in[40];
  const float* col_W = (const float*)d_in[41]; const float* col_b = (const float*)d_in[42];
  const float* s1_W = (const float*)d_in[43]; const float* s1_b = (const float*)d_in[44];
  const float* s2_W = (const float*)d_in[45]; const float* s2_b = (const float*)d_in[46];

  char* wsb = (char*)d_ws;
  size_t off = 0;
  auto alloc = [&](size_t bytes) {
    void* p = wsb + off;
    off = (off + bytes + 255) & ~(size_t)255;
    return p;
  };
  unsigned short* HLIN = (unsigned short*)alloc((size_t)NN * 1024 * 2);
  unsigned short* XB = (unsigned short*)alloc((size_t)NN * 1024 * 2);
  unsigned short* WTZ = (unsigned short*)alloc((size_t)1664 * 19136 * 2);
  unsigned short* ZA = (unsigned short*)alloc((size_t)1024 * 19136 * 2);
  unsigned short* WT1 = (unsigned short*)alloc((size_t)768 * 128 * 2);
  unsigned short* WT2 = (unsigned short*)alloc((size_t)1024 * 768 * 2);
  unsigned short* WT3 = (unsigned short*)alloc((size_t)1024 * 1024 * 2);
  unsigned short* WT4 = (unsigned short*)alloc((size_t)128 * 1024 * 2);
  unsigned short* WTW1 = (unsigned short*)alloc((size_t)768 * 768 * 2);
  unsigned short* WTW2 = (unsigned short*)alloc((size_t)128 * 768 * 2);
  unsigned short* WTZ2 = (unsigned short*)alloc((size_t)128 * 1664 * 2);
  unsigned short* WTV1 = (unsigned short*)alloc((size_t)256 * 1024 * 2);
  unsigned short* WTV2 = (unsigned short*)alloc((size_t)128 * 256 * 2);
  unsigned short* WTX5 = (unsigned short*)alloc((size_t)128 * 128 * 2);
  unsigned short* WTX6 = (unsigned short*)alloc((size_t)128 * 64 * 2);
  unsigned short* WTAGG = (unsigned short*)alloc((size_t)128 * 192 * 2);
  unsigned short* WTCOL = (unsigned short*)alloc((size_t)128 * 128 * 2);
  unsigned short* WTS1 = (unsigned short*)alloc((size_t)128 * 1056 * 2);
  unsigned short* WTS2 = (unsigned short*)alloc((size_t)128 * 64 * 2);
  unsigned short* WB = (unsigned short*)alloc((size_t)1024 * 768 * 2);
  unsigned short* VB = (unsigned short*)alloc((size_t)1024 * 1024 * 2);
  unsigned short* SIDEB = (unsigned short*)alloc((size_t)1024 * 1056 * 2);
  unsigned short* XGB = (unsigned short*)alloc((size_t)1024 * 128 * 2);
  unsigned short* ZB = (unsigned short*)alloc((size_t)1024 * 1664 * 2);
  unsigned short* X5O = (unsigned short*)alloc((size_t)1024 * 128 * 2);
  unsigned short* WMID = (unsigned short*)alloc((size_t)1024 * 768 * 2);
  unsigned short* VMID = (unsigned short*)alloc((size_t)1024 * 256 * 2);
  unsigned short* SEMID = (unsigned short*)alloc((size_t)1024 * 128 * 2);
  unsigned short* CAT192 = (unsigned short*)alloc((size_t)1024 * 192 * 2);
  unsigned short* CAT128 = (unsigned short*)alloc((size_t)1024 * 128 * 2);
  float* ALS = (float*)alloc((size_t)NN * 8 * 4);
  float* ALD = (float*)alloc((size_t)NN * 8 * 4);
  int* DEG = (int*)alloc((size_t)NN * 4);
  int* ROWPTR = (int*)alloc((size_t)(NN + 1) * 4);
  int* CURSOR = (int*)alloc((size_t)NN * 4);
  int* SRCL = (int*)alloc((size_t)ETOT * 4);
  float* PART = (float*)HLIN;  // 16x1024x1664 f32 = 109MB over dead HLIN+XB (134MB)

  // CSR build
  hipLaunchKernelGGL(fill_i32, dim3((NN + 255) / 256), dim3(256), 0, stream, DEG, 0, NN);
  hipLaunchKernelGGL(count_deg, dim3((ETOT + 255) / 256), dim3(256), 0, stream, ei, DEG);
  hipLaunchKernelGGL(scan_deg, dim3(1), dim3(1024), 0, stream, DEG, ROWPTR, CURSOR);
  hipLaunchKernelGGL(fill_csr, dim3((ETOT + 255) / 256), dim3(256), 0, stream, ei, CURSOR, SRCL);

  // batched weight transposes
  {
    TBatch tb;
    int acc_wg = 0, i = 0;
    auto add = [&](const float* W, unsigned short* WT, int K, int N, int Kp, int Npad) {
      int gx = Npad / 32, gy = Kp / 32;
      acc_wg += gx * gy;
      tb.d[i++] = {W, WT, K, N, Kp, Npad, gx, acc_wg};
    };
    add(z1_W, WTZ, 19127, 1600, 19136, 1664);
    add(gW[0], WT1, 109, 768, 128, 768);
    add(gW[1], WT2, 768, 1024, 768, 1024);
    add(gW[2], WT3, 1024, 1024, 1024, 1024);
    add(gW[3], WT4, 1024, 128, 1024, 128);
    add(w1_W, WTW1, 750, 750, 768, 768);
    add(w2_W, WTW2, 750, 64, 768, 128);
    add(z2_W, WTZ2, 1600, 64, 1664, 128);
    add(v1_W, WTV1, 1024, 256, 1024, 256);
    add(v2_W, WTV2, 256, 64, 256, 128);
    add(x5_W, WTX5, 128, 64, 128, 128);
    add(x6_W, WTX6, 64, 64, 64, 128);
    add(agg_W, WTAGG, 192, 64, 192, 128);
    add(col_W, WTCOL, 128, 64, 128, 128);
    add(s1_W, WTS1, 1050, 64, 1056, 128);
    add(s2_W, WTS2, 64, 64, 64, 128);
    hipLaunchKernelGGL(transpose_batch, dim3(acc_wg), dim3(256), 0, stream, tb);
  }

  // batched input conversions
  {
    CBatch cb;
    int acc_wg = 0, i = 0;
    auto add = [&](const float* in, unsigned short* out, int rowsOut, int Rreal, int C, int Cp) {
      acc_wg += (int)(((size_t)rowsOut * Cp + 255) / 256);
      cb.d[i++] = {in, out, rowsOut, Rreal, C, Cp, acc_wg};
    };
    add(z, ZA, NB, NB, 19127, 19136);
    add(x, XB, NN, NN, 109, 128);
    add(w, WB, 1024, 1024, 750, 768);
    add(v, VB, 1024, 1024, 1024, 1024);
    add(side, SIDEB, 1024, 994, 1050, 1056);
    hipLaunchKernelGGL(conv_batch, dim3(acc_wg), dim3(256), 0, stream, cb);
  }

  // GAT layers (scores fused into GEMM for C=128 layers)
  const int Hs[4] = {8, 8, 8, 1};
  const int Kp[4] = {128, 768, 1024, 1024};
  const unsigned short* WTs[4] = {WT1, WT2, WT3, WT4};
  const int Fs[4] = {768, 1024, 1024, 128};
  for (int l = 0; l < 4; ++l) {
    int H = Hs[l], F = Fs[l], C = F / H;
    int gx = F / 128;
    int nwg = gx * (NN / 128);
    if (C == 128) {
      hipLaunchKernelGGL((gemm_mfma<0, 1, 1>), dim3(nwg), dim3(256), 0, stream,
                         XB, WTs[l], (const float*)nullptr, (void*)HLIN, F, Kp[l],
                         Kp[l], Kp[l], F, gx, 0, gas[l], gad[l], ALS, ALD, H);
    } else {
      hipLaunchKernelGGL((gemm_mfma<0, 1, 0>), dim3(nwg), dim3(256), 0, stream,
                         XB, WTs[l], (const float*)nullptr, (void*)HLIN, F, Kp[l],
                         Kp[l], Kp[l], F, gx, 0, (const float*)nullptr,
                         (const float*)nullptr, (float*)nullptr, (float*)nullptr, H);
      int totNH = NN * H;
      hipLaunchKernelGGL(gat_scores_bf, dim3((totNH + 255) / 256), dim3(256), 0, stream,
                         HLIN, gas[l], gad[l], ALS, ALD, H, C, totNH);
    }
    if (l == 0)
      hipLaunchKernelGGL((gat_agg_v4<768, 96>), dim3(NN * 96 / 256), dim3(256), 0, stream,
                         ROWPTR, SRCL, ALS, ALD, HLIN, gb[l], XB);
    else if (l == 3)
      hipLaunchKernelGGL((gat_agg_v4<128, 128>), dim3(NN * 16 / 256), dim3(256), 0, stream,
                         ROWPTR, SRCL, ALS, ALD, HLIN, gb[l], XB);
    else
      hipLaunchKernelGGL((gat_agg_v4<1024, 128>), dim3(NN * 128 / 256), dim3(256), 0, stream,
                         ROWPTR, SRCL, ALS, ALD, HLIN, gb[l], XB);
  }

  // global max pool -> XGB bf16
  hipLaunchKernelGGL(pool_max, dim3(NB), dim3(128), 0, stream, XB, XGB);

  // B1: independent tail GEMMs {w1, v1, s1, x5}
  {
    GBatch b;
    int acc_wg = 0, i = 0;
    auto add = [&](const unsigned short* A, const unsigned short* BT, const float* bias,
                   void* C, int Npad, int Nreal, int K, int lda, int ldb, int ldc,
                   int zpad, int act, int obf, int Mreal) {
      int gx = Npad / 128;
      acc_wg += gx * 8;
      b.d[i++] = {A, BT, bias, C, Nreal, K, lda, ldb, ldc, gx, zpad, act, obf, Mreal, acc_wg};
    };
    add(WB, WTW1, w1_b, WMID, 768, 750, 768, 768, 768, 768, 1, 1, 1, 1024);
    add(VB, WTV1, v1_b, VMID, 256, 256, 1024, 1024, 1024, 256, 0, 1, 1, 1024);
    add(SIDEB, WTS1, s1_b, SEMID, 128, 64, 1056, 1056, 1056, 128, 1, 1, 1, 1024);
    add(XGB, WTX5, x5_b, X5O, 128, 64, 128, 128, 128, 128, 1, 1, 1, 1024);
    while (i < 5) { b.d[i] = b.d[i - 1]; b.d[i].wg_end = acc_wg; ++i; }
    hipLaunchKernelGGL(gemm_batch, dim3(acc_wg), dim3(256), 0, stream, b);
  }

  // z1 split-K (16 slices, f32 partials) + reduce -> ZB bf16
  hipLaunchKernelGGL(gemm_mfma_sk, dim3(1664), dim3(256), 0, stream, ZA, WTZ, PART, 19136, 19136, 1664);
  hipLaunchKernelGGL(zred, dim3((1024 * 1664 / 8 + 255) / 256), dim3(256), 0, stream, PART, z1_b, ZB);

  // output pointers
  float* outp = (float*)d_out;
  float* DN = outp + (size_t)NB * NSIDE;
  float* SN = DN + (size_t)NB * 64;

  // B2: {x6, w2, z2, v2, s2(tanh+rownorm -> SN)}
  {
    GBatch b;
    int acc_wg = 0, i = 0;
    auto add = [&](const unsigned short* A, const unsigned short* BT, const float* bias,
                   void* C, int Npad, int Nreal, int K, int lda, int ldb, int ldc,
                   int zpad, int act, int obf, int Mreal) {
      int gx = Npad / 128;
      acc_wg += gx * 8;
      b.d[i++] = {A, BT, bias, C, Nreal, K, lda, ldb, ldc, gx, zpad, act, obf, Mreal, acc_wg};
    };
    add(X5O, WTX6, x6_b, CAT192 + 0, 128, 64, 64, 128, 64, 192, 0, 1, 1, 1024);
    add(WMID, WTW2, w2_b, CAT192 + 64, 128, 64, 768, 768, 768, 192, 0, 1, 1, 1024);
    add(ZB, WTZ2, z2_b, CAT192 + 128, 128, 64, 1664, 1664, 1664, 192, 0, 1, 1, 1024);
    add(VMID, WTV2, v2_b, CAT128 + 64, 128, 64, 256, 256, 256, 128, 0, 1, 1, 1024);
    add(SEMID, WTS2, s2_b, SN, 128, 64, 64, 128, 64, 64, 0, 4, 0, 994);
    hipLaunchKernelGGL(gemm_batch, dim3(acc_wg), dim3(256), 0, stream, b);
  }

  // fused tail: agg GEMM -> col GEMM -> |tanh| -> rownorm -> DN
  hipLaunchKernelGGL(tail_fused, dim3(8), dim3(256), 0, stream,
                     CAT192, WTAGG, agg_b, CAT128, WTCOL, col_b, DN);

  // similarity
  hipLaunchKernelGGL(freq_k, dim3((NSIDE + 15) / 16, (NB + 15) / 16), dim3(256), 0, stream,
                     DN, SN, outp, NB, NSIDE);
}

// Round 14
// 953.197 us; speedup vs baseline: 1.0268x; 1.0268x over previous
//
#include <hip/hip_runtime.h>
#include <math.h>
#include <float.h>

#define E0 131072
#define NN 32768
#define NB 1024
#define NSIDE 994
#define ETOT (E0 + NN)

typedef short bf16x8 __attribute__((ext_vector_type(8)));
typedef unsigned short ushort8 __attribute__((ext_vector_type(8)));
typedef unsigned short ushort16 __attribute__((ext_vector_type(16)));
typedef float f32x4 __attribute__((ext_vector_type(4)));

__device__ inline float b2f(unsigned short u) { return __uint_as_float(((unsigned)u) << 16); }
__device__ inline unsigned short f2b(float f) {
  unsigned u = __float_as_uint(f);
  return (unsigned short)((u + 0x7fffu + ((u >> 16) & 1u)) >> 16);
}

__device__ inline void gload_lds16(const void* g, void* l) {
  __builtin_amdgcn_global_load_lds(
      (const __attribute__((address_space(1))) unsigned int*)g,
      (__attribute__((address_space(3))) unsigned int*)l, 16, 0, 0);
}

__global__ void fill_i32(int* p, int v, int n) {
  int i = blockIdx.x * blockDim.x + threadIdx.x;
  if (i < n) p[i] = v;
}

// ---------------- batched fp32 -> bf16 conversion with padding ----------------
struct CDesc { const float* in; unsigned short* out; int rowsOut, Rreal, C, Cp, wg_end; };
struct CBatch { CDesc d[5]; };
__global__ void conv_batch(CBatch cb) {
  int bid = blockIdx.x;
  int di = 0;
  while (bid >= cb.d[di].wg_end) ++di;
  const CDesc& g = cb.d[di];
  int rel = bid - (di ? cb.d[di - 1].wg_end : 0);
  size_t idx = (size_t)rel * 256 + threadIdx.x;
  size_t tot = (size_t)g.rowsOut * g.Cp;
  if (idx >= tot) return;
  int r = (int)(idx / g.Cp), c = (int)(idx % g.Cp);
  g.out[idx] = (r < g.Rreal && c < g.C) ? f2b(g.in[(size_t)r * g.C + c]) : (unsigned short)0;
}

// ---------------- batched transpose: W [K][N] f32 -> WT [Npad][Kp] bf16 ----------------
struct TDesc { const float* W; unsigned short* WT; int K, N, Kp, Npad, gx, wg_end; };
struct TBatch { TDesc d[16]; };
__global__ __launch_bounds__(256) void transpose_batch(TBatch tb) {
  __shared__ float t[32][33];
  int bid = blockIdx.x;
  int di = 0;
  while (bid >= tb.d[di].wg_end) ++di;
  const TDesc& g = tb.d[di];
  int rel = bid - (di ? tb.d[di - 1].wg_end : 0);
  int n0 = (rel % g.gx) * 32, k0 = (rel / g.gx) * 32;
  int tx = threadIdx.x & 31, ty = threadIdx.x >> 5;
  for (int r = ty; r < 32; r += 8) {
    int k = k0 + r, n = n0 + tx;
    t[r][tx] = (k < g.K && n < g.N) ? g.W[(size_t)k * g.N + n] : 0.f;
  }
  __syncthreads();
  for (int r = ty; r < 32; r += 8) {
    int n = n0 + r, k = k0 + tx;
    if (n < g.Npad && k < g.Kp)
      g.WT[(size_t)n * g.Kp + k] = (n < g.N) ? f2b(t[tx][r]) : (unsigned short)0;
  }
}

// ---------------- CSR build over dst ----------------
__global__ void count_deg(const int* __restrict__ ei, int* deg) {
  int e = blockIdx.x * blockDim.x + threadIdx.x;
  if (e >= ETOT) return;
  int dst = (e < E0) ? ei[E0 + e] : (e - E0);
  atomicAdd(&deg[dst], 1);
}

__global__ void scan_deg(const int* __restrict__ deg, int* rowptr, int* cursor) {
  __shared__ int part[1024];
  int tid = threadIdx.x;
  const int chunk = NN / 1024;  // 32
  int base = tid * chunk;
  int local[chunk];
  int sum = 0;
#pragma unroll
  for (int i = 0; i < chunk; ++i) { local[i] = sum; sum += deg[base + i]; }
  part[tid] = sum;
  __syncthreads();
  for (int off = 1; off < 1024; off <<= 1) {
    int t = (tid >= off) ? part[tid - off] : 0;
    __syncthreads();
    part[tid] += t;
    __syncthreads();
  }
  int offset = part[tid] - sum;
#pragma unroll
  for (int i = 0; i < chunk; ++i) {
    int v = offset + local[i];
    rowptr[base + i] = v;
    cursor[base + i] = v;
  }
  if (tid == 1023) rowptr[NN] = offset + sum;
}

__global__ void fill_csr(const int* __restrict__ ei, int* cursor, int* __restrict__ srcl) {
  int e = blockIdx.x * blockDim.x + threadIdx.x;
  if (e >= ETOT) return;
  int src, dst;
  if (e < E0) { src = ei[e]; dst = ei[E0 + e]; } else { src = dst = e - E0; }
  int p = atomicAdd(&cursor[dst], 1);
  srcl[p] = src;
}

// ---------------- bf16 MFMA GEMM, 2-phase dbuf; optional fused GAT scores ----------------
// NOTE: with the SC epilogue this kernel is VGPR-limited (~88 VGPR -> 5 waves/SIMD),
// so dbuf's 32KB LDS is free and its prefetch helps (measured r12 130us vs r13 138us).
template <int ACT, int OBF, int SC>
__global__ __launch_bounds__(256) void gemm_mfma(
    const unsigned short* __restrict__ A, const unsigned short* __restrict__ BT,
    const float* __restrict__ bias, void* __restrict__ Cp,
    int Nreal, int K, int lda, int ldb, int ldc, int gx, int zpad,
    const float* __restrict__ asv, const float* __restrict__ adv,
    float* __restrict__ als, float* __restrict__ ald, int H) {
  __shared__ unsigned short As[2][128 * 32];
  __shared__ unsigned short Bs[2][128 * 32];
  const int nwg = gridDim.x;
  const int chunk = nwg >> 3;
  const int bid = blockIdx.x;
  const int swz = (bid & 7) * chunk + (bid >> 3);
  const int bm = (swz / gx) * 128, bn = (swz % gx) * 128;
  const int tid = threadIdx.x;
  const int wv = tid >> 6, lane = tid & 63;
  const int sr = lane >> 2;
  const int sk = ((lane & 3) ^ ((lane >> 3) & 3)) * 8;
  const int r16 = lane & 15, kq = lane >> 4;
  const int slot8 = (kq ^ ((r16 >> 1) & 3)) * 8;
  const int wr = wv >> 1, wc = wv & 1;
  f32x4 acc[4][4];
#pragma unroll
  for (int i = 0; i < 4; ++i)
#pragma unroll
    for (int j = 0; j < 4; ++j) acc[i][j] = (f32x4){0.f, 0.f, 0.f, 0.f};

  const unsigned short* Abase = A + (size_t)bm * lda;
  const unsigned short* Bbase = BT + (size_t)bn * ldb;
  auto stage = [&](int buf, int k0) {
    gload_lds16(Abase + (size_t)(wv * 16 + sr) * lda + k0 + sk, &As[buf][wv * 512]);
    gload_lds16(Abase + (size_t)(64 + wv * 16 + sr) * lda + k0 + sk, &As[buf][2048 + wv * 512]);
    gload_lds16(Bbase + (size_t)(wv * 16 + sr) * ldb + k0 + sk, &Bs[buf][wv * 512]);
    gload_lds16(Bbase + (size_t)(64 + wv * 16 + sr) * ldb + k0 + sk, &Bs[buf][2048 + wv * 512]);
  };
  stage(0, 0);
  __syncthreads();
  int cur = 0;
  for (int k0 = 0; k0 < K; k0 += 32) {
    if (k0 + 32 < K) stage(cur ^ 1, k0 + 32);
    bf16x8 af[4], bfr[4];
#pragma unroll
    for (int i = 0; i < 4; ++i)
      af[i] = *(const bf16x8*)&As[cur][(wr * 64 + i * 16 + r16) * 32 + slot8];
#pragma unroll
    for (int j = 0; j < 4; ++j)
      bfr[j] = *(const bf16x8*)&Bs[cur][(wc * 64 + j * 16 + r16) * 32 + slot8];
#pragma unroll
    for (int i = 0; i < 4; ++i)
#pragma unroll
      for (int j = 0; j < 4; ++j)
        acc[i][j] = __builtin_amdgcn_mfma_f32_16x16x32_bf16(af[i], bfr[j], acc[i][j], 0, 0, 0);
    __syncthreads();
    cur ^= 1;
  }
#pragma unroll
  for (int i = 0; i < 4; ++i) {
    int row = bm + wr * 64 + i * 16 + kq * 4;
#pragma unroll
    for (int j = 0; j < 4; ++j) {
      int col = bn + wc * 64 + j * 16 + r16;
      bool real = col < Nreal;
      if (!real && !zpad) continue;
      float bv = (bias && real) ? bias[col] : 0.f;
#pragma unroll
      for (int r = 0; r < 4; ++r) {
        float v = acc[i][j][r] + bv;
        if (ACT == 1) v = v > 0.f ? v : 0.f;
        else if (ACT == 2) v = tanhf(v);
        else if (ACT == 3) v = fabsf(tanhf(v));
        if (!real) v = 0.f;
        if (OBF) ((unsigned short*)Cp)[(size_t)(row + r) * ldc + col] = f2b(v);
        else ((float*)Cp)[(size_t)(row + r) * ldc + col] = v;
      }
    }
  }
  if (SC) {
    // fused GAT scores: head h spans exactly this block's 128 cols
    const int h = bn >> 7;
    float* scr = (float*)&As[0][0];  // 128 rows x {wc0_s, wc0_d, wc1_s, wc1_d} = 2KB
    float a_s[4], a_d[4];
#pragma unroll
    for (int j = 0; j < 4; ++j) {
      int cwh = wc * 64 + j * 16 + r16;
      a_s[j] = asv[h * 128 + cwh];
      a_d[j] = adv[h * 128 + cwh];
    }
#pragma unroll
    for (int i = 0; i < 4; ++i)
#pragma unroll
      for (int r = 0; r < 4; ++r) {
        float sp = 0.f, dp = 0.f;
#pragma unroll
        for (int j = 0; j < 4; ++j) {
          sp = fmaf(acc[i][j][r], a_s[j], sp);
          dp = fmaf(acc[i][j][r], a_d[j], dp);
        }
#pragma unroll
        for (int m = 1; m < 16; m <<= 1) {
          sp += __shfl_xor(sp, m);
          dp += __shfl_xor(dp, m);
        }
        if (r16 == 0) {
          int rl = wr * 64 + i * 16 + kq * 4 + r;
          scr[rl * 4 + wc * 2 + 0] = sp;
          scr[rl * 4 + wc * 2 + 1] = dp;
        }
      }
    __syncthreads();
    if (tid < 128) {
      float s = scr[tid * 4 + 0] + scr[tid * 4 + 2];
      float d = scr[tid * 4 + 1] + scr[tid * 4 + 3];
      als[(size_t)(bm + tid) * H + h] = s;
      ald[(size_t)(bm + tid) * H + h] = d;
    }
  }
}

// ---------------- batched runtime-act MFMA GEMM (2-phase dbuf) ----------------
// act: 0 none, 1 relu, 2 tanh, 3 abs(tanh), 4 tanh+rownorm (f32 out, row<Mreal guard)
struct GDesc {
  const unsigned short* A; const unsigned short* BT; const float* bias; void* C;
  int Nreal, K, lda, ldb, ldc, gx, zpad, act, obf, Mreal, wg_end;
};
struct GBatch { GDesc d[5]; };
__global__ __launch_bounds__(256) void gemm_batch(GBatch gb) {
  __shared__ unsigned short As[2][128 * 32];
  __shared__ unsigned short Bs[2][128 * 32];
  int bid = blockIdx.x;
  int di = 0;
  while (bid >= gb.d[di].wg_end) ++di;
  const GDesc& g = gb.d[di];
  int rel = bid - (di ? gb.d[di - 1].wg_end : 0);
  const int bm = (rel / g.gx) * 128, bn = (rel % g.gx) * 128;
  const int tid = threadIdx.x;
  const int wv = tid >> 6, lane = tid & 63;
  const int sr = lane >> 2;
  const int sk = ((lane & 3) ^ ((lane >> 3) & 3)) * 8;
  const int r16 = lane & 15, kq = lane >> 4;
  const int slot8 = (kq ^ ((r16 >> 1) & 3)) * 8;
  const int wr = wv >> 1, wc = wv & 1;
  f32x4 acc[4][4];
#pragma unroll
  for (int i = 0; i < 4; ++i)
#pragma unroll
    for (int j = 0; j < 4; ++j) acc[i][j] = (f32x4){0.f, 0.f, 0.f, 0.f};

  const unsigned short* Abase = g.A + (size_t)bm * g.lda;
  const unsigned short* Bbase = g.BT + (size_t)bn * g.ldb;
  auto stage = [&](int buf, int k0) {
    gload_lds16(Abase + (size_t)(wv * 16 + sr) * g.lda + k0 + sk, &As[buf][wv * 512]);
    gload_lds16(Abase + (size_t)(64 + wv * 16 + sr) * g.lda + k0 + sk, &As[buf][2048 + wv * 512]);
    gload_lds16(Bbase + (size_t)(wv * 16 + sr) * g.ldb + k0 + sk, &Bs[buf][wv * 512]);
    gload_lds16(Bbase + (size_t)(64 + wv * 16 + sr) * g.ldb + k0 + sk, &Bs[buf][2048 + wv * 512]);
  };
  stage(0, 0);
  __syncthreads();
  int cur = 0;
  for (int k0 = 0; k0 < g.K; k0 += 32) {
    if (k0 + 32 < g.K) stage(cur ^ 1, k0 + 32);
    bf16x8 af[4], bfr[4];
#pragma unroll
    for (int i = 0; i < 4; ++i)
      af[i] = *(const bf16x8*)&As[cur][(wr * 64 + i * 16 + r16) * 32 + slot8];
#pragma unroll
    for (int j = 0; j < 4; ++j)
      bfr[j] = *(const bf16x8*)&Bs[cur][(wc * 64 + j * 16 + r16) * 32 + slot8];
#pragma unroll
    for (int i = 0; i < 4; ++i)
#pragma unroll
      for (int j = 0; j < 4; ++j)
        acc[i][j] = __builtin_amdgcn_mfma_f32_16x16x32_bf16(af[i], bfr[j], acc[i][j], 0, 0, 0);
    __syncthreads();
    cur ^= 1;
  }
  if (g.act == 4) {
    if (wc == 0) {
#pragma unroll
      for (int i = 0; i < 4; ++i)
#pragma unroll
        for (int r = 0; r < 4; ++r) {
          int row = bm + wr * 64 + i * 16 + kq * 4 + r;
          float vv[4];
#pragma unroll
          for (int j = 0; j < 4; ++j) vv[j] = tanhf(acc[i][j][r] + g.bias[j * 16 + r16]);
          float ss = vv[0] * vv[0] + vv[1] * vv[1] + vv[2] * vv[2] + vv[3] * vv[3];
          ss += __shfl_xor(ss, 1);
          ss += __shfl_xor(ss, 2);
          ss += __shfl_xor(ss, 4);
          ss += __shfl_xor(ss, 8);
          float inv = 1.f / fmaxf(sqrtf(ss), 1e-12f);
          if (row < g.Mreal)
#pragma unroll
            for (int j = 0; j < 4; ++j)
              ((float*)g.C)[(size_t)row * g.ldc + j * 16 + r16] = vv[j] * inv;
        }
    }
    return;
  }
#pragma unroll
  for (int i = 0; i < 4; ++i) {
    int row = bm + wr * 64 + i * 16 + kq * 4;
#pragma unroll
    for (int j = 0; j < 4; ++j) {
      int col = bn + wc * 64 + j * 16 + r16;
      bool real = col < g.Nreal;
      if (!real && !g.zpad) continue;
      float bv = (g.bias && real) ? g.bias[col] : 0.f;
#pragma unroll
      for (int r = 0; r < 4; ++r) {
        float v = acc[i][j][r] + bv;
        if (g.act == 1) v = v > 0.f ? v : 0.f;
        else if (g.act == 2) v = tanhf(v);
        else if (g.act == 3) v = fabsf(tanhf(v));
        if (!real) v = 0.f;
        if (g.obf) ((unsigned short*)g.C)[(size_t)(row + r) * g.ldc + col] = f2b(v);
        else ((float*)g.C)[(size_t)(row + r) * g.ldc + col] = v;
      }
    }
  }
}

// ---------------- split-K MFMA GEMM for z1 (single-buffer, f32 partials) ----------------
__global__ __launch_bounds__(256) void gemm_mfma_sk(
    const unsigned short* __restrict__ A, const unsigned short* __restrict__ BT,
    float* __restrict__ PART, int lda, int ldb, int ldc) {
  __shared__ unsigned short As[128 * 32];
  __shared__ unsigned short Bs[128 * 32];
  const int bid = blockIdx.x;
  const int swz = (bid & 7) * 208 + (bid >> 3);
  const int s = swz / 104;
  const int pos = swz - s * 104;
  const int bm = (pos / 13) * 128, bn = (pos % 13) * 128;
  const int base = s * 37 + (s < 6 ? s : 6);
  const int nsteps = 37 + (s < 6 ? 1 : 0);
  const int tid = threadIdx.x;
  const int wv = tid >> 6, lane = tid & 63;
  const int sr = lane >> 2;
  const int sk = ((lane & 3) ^ ((lane >> 3) & 3)) * 8;
  const int r16 = lane & 15, kq = lane >> 4;
  const int slot8 = (kq ^ ((r16 >> 1) & 3)) * 8;
  const int wr = wv >> 1, wc = wv & 1;
  f32x4 acc[4][4];
#pragma unroll
  for (int i = 0; i < 4; ++i)
#pragma unroll
    for (int j = 0; j < 4; ++j) acc[i][j] = (f32x4){0.f, 0.f, 0.f, 0.f};

  const unsigned short* Abase = A + (size_t)bm * lda;
  const unsigned short* Bbase = BT + (size_t)bn * ldb;
  for (int ks = 0; ks < nsteps; ++ks) {
    int k0 = (base + ks) * 32;
    gload_lds16(Abase + (size_t)(wv * 16 + sr) * lda + k0 + sk, &As[wv * 512]);
    gload_lds16(Abase + (size_t)(64 + wv * 16 + sr) * lda + k0 + sk, &As[2048 + wv * 512]);
    gload_lds16(Bbase + (size_t)(wv * 16 + sr) * ldb + k0 + sk, &Bs[wv * 512]);
    gload_lds16(Bbase + (size_t)(64 + wv * 16 + sr) * ldb + k0 + sk, &Bs[2048 + wv * 512]);
    __syncthreads();
    bf16x8 af[4], bfr[4];
#pragma unroll
    for (int i = 0; i < 4; ++i)
      af[i] = *(const bf16x8*)&As[(wr * 64 + i * 16 + r16) * 32 + slot8];
#pragma unroll
    for (int j = 0; j < 4; ++j)
      bfr[j] = *(const bf16x8*)&Bs[(wc * 64 + j * 16 + r16) * 32 + slot8];
#pragma unroll
    for (int i = 0; i < 4; ++i)
#pragma unroll
      for (int j = 0; j < 4; ++j)
        acc[i][j] = __builtin_amdgcn_mfma_f32_16x16x32_bf16(af[i], bfr[j], acc[i][j], 0, 0, 0);
    __syncthreads();
  }
  float* out = PART + (size_t)s * 1024 * ldc;
#pragma unroll
  for (int i = 0; i < 4; ++i) {
    int row = bm + wr * 64 + i * 16 + kq * 4;
#pragma unroll
    for (int j = 0; j < 4; ++j) {
      int col = bn + wc * 64 + j * 16 + r16;
      if (col >= 1600) continue;
#pragma unroll
      for (int r = 0; r < 4; ++r)
        out[(size_t)(row + r) * ldc + col] = acc[i][j][r];
    }
  }
}

// reduce 16 f32 K-slice partials + bias + relu -> ZB bf16 [1024][1664], float4 vectorized
__global__ void zred(const float* __restrict__ PART, const float* __restrict__ bias,
                     unsigned short* __restrict__ ZB) {
  int g = blockIdx.x * blockDim.x + threadIdx.x;
  if (g >= 1024 * 1664 / 8) return;
  size_t base = (size_t)g * 8;
  int c0 = (int)(base % 1664);
  ushort8 o;
  if (c0 >= 1600) {
#pragma unroll
    for (int t = 0; t < 8; ++t) o[t] = 0;
  } else {
    float s[8] = {0.f, 0.f, 0.f, 0.f, 0.f, 0.f, 0.f, 0.f};
#pragma unroll
    for (int k = 0; k < 16; ++k) {
      const float* p = &PART[(size_t)k * 1024 * 1664 + base];
      float4 a = *(const float4*)p;
      float4 b = *(const float4*)(p + 4);
      s[0] += a.x; s[1] += a.y; s[2] += a.z; s[3] += a.w;
      s[4] += b.x; s[5] += b.y; s[6] += b.z; s[7] += b.w;
    }
#pragma unroll
    for (int t = 0; t < 8; ++t) {
      float v = s[t] + bias[c0 + t];
      o[t] = f2b(v > 0.f ? v : 0.f);
    }
  }
  *(ushort8*)&ZB[base] = o;
}

// ---------------- fused tail: agg GEMM -> LDS -> col GEMM -> |tanh| -> rownorm -> DN ----
__global__ __launch_bounds__(256) void tail_fused(
    const unsigned short* __restrict__ CAT192, const unsigned short* __restrict__ WTAGG,
    const float* __restrict__ agg_b, const unsigned short* __restrict__ CAT128,
    const unsigned short* __restrict__ WTCOL, const float* __restrict__ col_b,
    float* __restrict__ DN) {
  __shared__ unsigned short S1[128 * 32];
  __shared__ unsigned short S2[128 * 32];
  __shared__ unsigned short ACAT[128 * 128];
  const int bm = blockIdx.x * 128;
  const int tid = threadIdx.x;
  const int wv = tid >> 6, lane = tid & 63;
  const int sr = lane >> 2;
  const int sk = ((lane & 3) ^ ((lane >> 3) & 3)) * 8;
  const int r16 = lane & 15, kq = lane >> 4;
  const int slot8 = (kq ^ ((r16 >> 1) & 3)) * 8;
  const int wr = wv >> 1, wc = wv & 1;
  f32x4 acc[4][4];
#pragma unroll
  for (int i = 0; i < 4; ++i)
#pragma unroll
    for (int j = 0; j < 4; ++j) acc[i][j] = (f32x4){0.f, 0.f, 0.f, 0.f};

  const unsigned short* Abase = CAT192 + (size_t)bm * 192;
  for (int k0 = 0; k0 < 192; k0 += 32) {
    gload_lds16(Abase + (size_t)(wv * 16 + sr) * 192 + k0 + sk, &S1[wv * 512]);
    gload_lds16(Abase + (size_t)(64 + wv * 16 + sr) * 192 + k0 + sk, &S1[2048 + wv * 512]);
    gload_lds16(WTAGG + (size_t)(wv * 16 + sr) * 192 + k0 + sk, &S2[wv * 512]);
    gload_lds16(WTAGG + (size_t)(64 + wv * 16 + sr) * 192 + k0 + sk, &S2[2048 + wv * 512]);
    __syncthreads();
    bf16x8 af[4], bfr[4];
#pragma unroll
    for (int i = 0; i < 4; ++i)
      af[i] = *(const bf16x8*)&S1[(wr * 64 + i * 16 + r16) * 32 + slot8];
#pragma unroll
    for (int j = 0; j < 4; ++j)
      bfr[j] = *(const bf16x8*)&S2[(wc * 64 + j * 16 + r16) * 32 + slot8];
#pragma unroll
    for (int i = 0; i < 4; ++i)
#pragma unroll
      for (int j = 0; j < 4; ++j)
        acc[i][j] = __builtin_amdgcn_mfma_f32_16x16x32_bf16(af[i], bfr[j], acc[i][j], 0, 0, 0);
    __syncthreads();
  }
  if (wc == 0) {
#pragma unroll
    for (int i = 0; i < 4; ++i)
#pragma unroll
      for (int j = 0; j < 4; ++j) {
        int col = j * 16 + r16;
#pragma unroll
        for (int r = 0; r < 4; ++r) {
          int rl = wr * 64 + i * 16 + kq * 4 + r;
          ACAT[rl * 128 + col] = f2b(acc[i][j][r] + agg_b[col]);
        }
      }
  }
  for (int idx = tid; idx < 128 * 8; idx += 256) {
    int row = idx >> 3, c8 = (idx & 7) * 8;
    *(ushort8*)&ACAT[row * 128 + 64 + c8] =
        *(const ushort8*)&CAT128[(size_t)(bm + row) * 128 + 64 + c8];
  }
#pragma unroll
  for (int i = 0; i < 4; ++i)
#pragma unroll
    for (int j = 0; j < 4; ++j) acc[i][j] = (f32x4){0.f, 0.f, 0.f, 0.f};
  __syncthreads();

  for (int k0 = 0; k0 < 128; k0 += 32) {
    gload_lds16(WTCOL + (size_t)(wv * 16 + sr) * 128 + k0 + sk, &S1[wv * 512]);
    gload_lds16(WTCOL + (size_t)(64 + wv * 16 + sr) * 128 + k0 + sk, &S1[2048 + wv * 512]);
    __syncthreads();
    bf16x8 af[4], bfr[4];
#pragma unroll
    for (int i = 0; i < 4; ++i)
      af[i] = *(const bf16x8*)&ACAT[(wr * 64 + i * 16 + r16) * 128 + k0 + kq * 8];
#pragma unroll
    for (int j = 0; j < 4; ++j)
      bfr[j] = *(const bf16x8*)&S1[(wc * 64 + j * 16 + r16) * 32 + slot8];
#pragma unroll
    for (int i = 0; i < 4; ++i)
#pragma unroll
      for (int j = 0; j < 4; ++j)
        acc[i][j] = __builtin_amdgcn_mfma_f32_16x16x32_bf16(af[i], bfr[j], acc[i][j], 0, 0, 0);
    __syncthreads();
  }
  if (wc == 0) {
#pragma unroll
    for (int i = 0; i < 4; ++i)
#pragma unroll
      for (int r = 0; r < 4; ++r) {
        int row = bm + wr * 64 + i * 16 + kq * 4 + r;
        float vv[4];
#pragma unroll
        for (int j = 0; j < 4; ++j) vv[j] = fabsf(tanhf(acc[i][j][r] + col_b[j * 16 + r16]));
        float ss = vv[0] * vv[0] + vv[1] * vv[1] + vv[2] * vv[2] + vv[3] * vv[3];
        ss += __shfl_xor(ss, 1);
        ss += __shfl_xor(ss, 2);
        ss += __shfl_xor(ss, 4);
        ss += __shfl_xor(ss, 8);
        float inv = 1.f / fmaxf(sqrtf(ss), 1e-12f);
#pragma unroll
        for (int j = 0; j < 4; ++j)
          DN[(size_t)row * 64 + j * 16 + r16] = vv[j] * inv;
      }
  }
}

// ---------------- GAT pieces ----------------
__global__ void gat_scores_bf(const unsigned short* __restrict__ hlin,
                              const float* __restrict__ a_s, const float* __restrict__ a_d,
                              float* __restrict__ als, float* __restrict__ ald,
                              int H, int C, int tot) {
  int idx = blockIdx.x * blockDim.x + threadIdx.x;
  if (idx >= tot) return;
  int n = idx / H, h = idx - n * H;
  const unsigned short* base = hlin + (size_t)n * H * C + (size_t)h * C;
  const float* as = a_s + h * C;
  const float* ad = a_d + h * C;
  float ss = 0.f, sd = 0.f;
  for (int c = 0; c < C; c += 8) {
    ushort8 v = *(const ushort8*)(base + c);
#pragma unroll
    for (int t = 0; t < 8; ++t) {
      float f = b2f(v[t]);
      ss = fmaf(f, as[c + t], ss);
      sd = fmaf(f, ad[c + t], sd);
    }
  }
  als[idx] = ss;
  ald[idx] = sd;
}

// aggregate with INLINE attention; EPT = bf16 elems per thread (8 or 16).
// EPT=16 halves per-node threads -> halves redundant srcl/als/exp work per edge.
template <int F, int C, int EPT>
__global__ __launch_bounds__(256) void gat_agg_v5(
    const int* __restrict__ rowptr, const int* __restrict__ srcl,
    const float* __restrict__ als, const float* __restrict__ ald,
    const unsigned short* __restrict__ hlin,
    const float* __restrict__ bias, unsigned short* __restrict__ out) {
  constexpr int H = F / C;
  constexpr int CPN = F / EPT;
  int gidx = blockIdx.x * 256 + threadIdx.x;
  if (gidx >= NN * CPN) return;
  int node = gidx / CPN;
  int c0 = (gidx - node * CPN) * EPT;
  int h = c0 / C;
  float aldv = ald[node * H + h];
  float s = 0.f;
  float acc[EPT];
#pragma unroll
  for (int t = 0; t < EPT; ++t) acc[t] = 0.f;
  int start = rowptr[node], end = rowptr[node + 1];
  for (int k = start; k < end; ++k) {
    int src = srcl[k];
    float e = als[src * H + h] + aldv;
    e = (e >= 0.f) ? e : 0.2f * e;
    float p = __expf(e);
    s += p;
    if (EPT == 8) {
      ushort8 hv = *(const ushort8*)(hlin + (size_t)src * F + c0);
#pragma unroll
      for (int t = 0; t < 8; ++t) acc[t] = fmaf(p, b2f(hv[t]), acc[t]);
    } else {
      ushort16 hv = *(const ushort16*)(hlin + (size_t)src * F + c0);
#pragma unroll
      for (int t = 0; t < 16; ++t) acc[t] = fmaf(p, b2f(hv[t]), acc[t]);
    }
  }
  float inv_s = 1.f / s;
#pragma unroll
  for (int t8 = 0; t8 < EPT / 8; ++t8) {
    ushort8 o;
#pragma unroll
    for (int t = 0; t < 8; ++t) {
      float val = acc[t8 * 8 + t] * inv_s + bias[c0 + t8 * 8 + t];
      o[t] = f2b(val > 0.f ? val : 0.f);
    }
    *(ushort8*)(out + (size_t)node * F + c0 + t8 * 8) = o;
  }
}

__global__ void pool_max(const unsigned short* __restrict__ xb,
                         unsigned short* __restrict__ xgb) {
  int g = blockIdx.x, c = threadIdx.x;  // 128 threads
  const unsigned short* base = xb + (size_t)g * 32 * 128 + c;
  float m = -FLT_MAX;
#pragma unroll 8
  for (int n = 0; n < 32; ++n) m = fmaxf(m, b2f(base[n * 128]));
  xgb[g * 128 + c] = f2b(m);
}

__global__ __launch_bounds__(256) void freq_k(const float* __restrict__ dn,
                                              const float* __restrict__ sn,
                                              float* __restrict__ C, int M, int N) {
  __shared__ float As[16][64];
  __shared__ float Bs[16][65];
  int tid = threadIdx.x;
  int tx = tid & 15, ty = tid >> 4;
  int bi = blockIdx.y * 16, bj = blockIdx.x * 16;
#pragma unroll
  for (int t = 0; t < 4; ++t) {
    int idx = tid * 4 + t;
    int r = idx >> 6, c = idx & 63;
    As[r][c] = (bi + r < M) ? dn[(bi + r) * 64 + c] : 0.f;
    Bs[r][c] = (bj + r < N) ? sn[(bj + r) * 64 + c] : 0.f;
  }
  __syncthreads();
  float acc = 0.f;
#pragma unroll
  for (int k = 0; k < 64; ++k) acc = fmaf(As[ty][k], Bs[tx][k], acc);
  if (bi + ty < M && bj + tx < N) C[(size_t)(bi + ty) * N + (bj + tx)] = 5.f * acc;
}

// ---------------- launch ----------------
extern "C" void kernel_launch(void* const* d_in, const int* in_sizes, int n_in,
                              void* d_out, int out_size, void* d_ws, size_t ws_size,
                              hipStream_t stream) {
  const float* x = (const float*)d_in[0];
  const int* ei = (const int*)d_in[1];
  const float* w = (const float*)d_in[3];
  const float* z = (const float*)d_in[4];
  const float* v = (const float*)d_in[5];
  const float* side = (const float*)d_in[6];
  const float* gW[4] = {(const float*)d_in[7], (const float*)d_in[11],
                        (const float*)d_in[15], (const float*)d_in[19]};
  const float* gas[4] = {(const float*)d_in[8], (const float*)d_in[12],
                         (const float*)d_in[16], (const float*)d_in[20]};
  const float* gad[4] = {(const float*)d_in[9], (const float*)d_in[13],
                         (const float*)d_in[17], (const float*)d_in[21]};
  const float* gb[4] = {(const float*)d_in[10], (const float*)d_in[14],
                        (const float*)d_in[18], (const float*)d_in[22]};
  const float* x5_W = (const float*)d_in[23]; const float* x5_b = (const float*)d_in[24];
  const float* x6_W = (const float*)d_in[25]; const float* x6_b = (const float*)d_in[26];
  const float* w1_W = (const float*)d_in[27]; const float* w1_b = (const float*)d_in[28];
  const float* w2_W = (const float*)d_in[29]; const float* w2_b = (const float*)d_in[30];
  const float* z1_W = (const float*)d_in[31]; const float* z1_b = (const float*)d_in[32];
  const float* z2_W = (const float*)d_in[33]; const float* z2_b = (const float*)d_in[34];
  const float* v1_W = (const float*)d_in[35]; const float* v1_b = (const float*)d_in[36];
  const float* v2_W = (const float*)d_in[37]; const float* v2_b = (const float*)d_in[38];
  const float* agg_W = (const float*)d_in[39]; const float* agg_b = (const float*)d_in[40];
  const float* col_W = (const float*)d_in[41]; const float* col_b = (const float*)d_in[42];
  const float* s1_W = (const float*)d_in[43]; const float* s1_b = (const float*)d_in[44];
  const float* s2_W = (const float*)d_in[45]; const float* s2_b = (const float*)d_in[46];

  char* wsb = (char*)d_ws;
  size_t off = 0;
  auto alloc = [&](size_t bytes) {
    void* p = wsb + off;
    off = (off + bytes + 255) & ~(size_t)255;
    return p;
  };
  unsigned short* HLIN = (unsigned short*)alloc((size_t)NN * 1024 * 2);
  unsigned short* XB = (unsigned short*)alloc((size_t)NN * 1024 * 2);
  unsigned short* WTZ = (unsigned short*)alloc((size_t)1664 * 19136 * 2);
  unsigned short* ZA = (unsigned short*)alloc((size_t)1024 * 19136 * 2);
  unsigned short* WT1 = (unsigned short*)alloc((size_t)768 * 128 * 2);
  unsigned short* WT2 = (unsigned short*)alloc((size_t)1024 * 768 * 2);
  unsigned short* WT3 = (unsigned short*)alloc((size_t)1024 * 1024 * 2);
  unsigned short* WT4 = (unsigned short*)alloc((size_t)128 * 1024 * 2);
  unsigned short* WTW1 = (unsigned short*)alloc((size_t)768 * 768 * 2);
  unsigned short* WTW2 = (unsigned short*)alloc((size_t)128 * 768 * 2);
  unsigned short* WTZ2 = (unsigned short*)alloc((size_t)128 * 1664 * 2);
  unsigned short* WTV1 = (unsigned short*)alloc((size_t)256 * 1024 * 2);
  unsigned short* WTV2 = (unsigned short*)alloc((size_t)128 * 256 * 2);
  unsigned short* WTX5 = (unsigned short*)alloc((size_t)128 * 128 * 2);
  unsigned short* WTX6 = (unsigned short*)alloc((size_t)128 * 64 * 2);
  unsigned short* WTAGG = (unsigned short*)alloc((size_t)128 * 192 * 2);
  unsigned short* WTCOL = (unsigned short*)alloc((size_t)128 * 128 * 2);
  unsigned short* WTS1 = (unsigned short*)alloc((size_t)128 * 1056 * 2);
  unsigned short* WTS2 = (unsigned short*)alloc((size_t)128 * 64 * 2);
  unsigned short* WB = (unsigned short*)alloc((size_t)1024 * 768 * 2);
  unsigned short* VB = (unsigned short*)alloc((size_t)1024 * 1024 * 2);
  unsigned short* SIDEB = (unsigned short*)alloc((size_t)1024 * 1056 * 2);
  unsigned short* XGB = (unsigned short*)alloc((size_t)1024 * 128 * 2);
  unsigned short* ZB = (unsigned short*)alloc((size_t)1024 * 1664 * 2);
  unsigned short* X5O = (unsigned short*)alloc((size_t)1024 * 128 * 2);
  unsigned short* WMID = (unsigned short*)alloc((size_t)1024 * 768 * 2);
  unsigned short* VMID = (unsigned short*)alloc((size_t)1024 * 256 * 2);
  unsigned short* SEMID = (unsigned short*)alloc((size_t)1024 * 128 * 2);
  unsigned short* CAT192 = (unsigned short*)alloc((size_t)1024 * 192 * 2);
  unsigned short* CAT128 = (unsigned short*)alloc((size_t)1024 * 128 * 2);
  float* ALS = (float*)alloc((size_t)NN * 8 * 4);
  float* ALD = (float*)alloc((size_t)NN * 8 * 4);
  int* DEG = (int*)alloc((size_t)NN * 4);
  int* ROWPTR = (int*)alloc((size_t)(NN + 1) * 4);
  int* CURSOR = (int*)alloc((size_t)NN * 4);
  int* SRCL = (int*)alloc((size_t)ETOT * 4);
  float* PART = (float*)HLIN;  // 16x1024x1664 f32 = 109MB over dead HLIN+XB (134MB)

  // CSR build
  hipLaunchKernelGGL(fill_i32, dim3((NN + 255) / 256), dim3(256), 0, stream, DEG, 0, NN);
  hipLaunchKernelGGL(count_deg, dim3((ETOT + 255) / 256), dim3(256), 0, stream, ei, DEG);
  hipLaunchKernelGGL(scan_deg, dim3(1), dim3(1024), 0, stream, DEG, ROWPTR, CURSOR);
  hipLaunchKernelGGL(fill_csr, dim3((ETOT + 255) / 256), dim3(256), 0, stream, ei, CURSOR, SRCL);

  // batched weight transposes
  {
    TBatch tb;
    int acc_wg = 0, i = 0;
    auto add = [&](const float* W, unsigned short* WT, int K, int N, int Kp, int Npad) {
      int gx = Npad / 32, gy = Kp / 32;
      acc_wg += gx * gy;
      tb.d[i++] = {W, WT, K, N, Kp, Npad, gx, acc_wg};
    };
    add(z1_W, WTZ, 19127, 1600, 19136, 1664);
    add(gW[0], WT1, 109, 768, 128, 768);
    add(gW[1], WT2, 768, 1024, 768, 1024);
    add(gW[2], WT3, 1024, 1024, 1024, 1024);
    add(gW[3], WT4, 1024, 128, 1024, 128);
    add(w1_W, WTW1, 750, 750, 768, 768);
    add(w2_W, WTW2, 750, 64, 768, 128);
    add(z2_W, WTZ2, 1600, 64, 1664, 128);
    add(v1_W, WTV1, 1024, 256, 1024, 256);
    add(v2_W, WTV2, 256, 64, 256, 128);
    add(x5_W, WTX5, 128, 64, 128, 128);
    add(x6_W, WTX6, 64, 64, 64, 128);
    add(agg_W, WTAGG, 192, 64, 192, 128);
    add(col_W, WTCOL, 128, 64, 128, 128);
    add(s1_W, WTS1, 1050, 64, 1056, 128);
    add(s2_W, WTS2, 64, 64, 64, 128);
    hipLaunchKernelGGL(transpose_batch, dim3(acc_wg), dim3(256), 0, stream, tb);
  }

  // batched input conversions
  {
    CBatch cb;
    int acc_wg = 0, i = 0;
    auto add = [&](const float* in, unsigned short* out, int rowsOut, int Rreal, int C, int Cp) {
      acc_wg += (int)(((size_t)rowsOut * Cp + 255) / 256);
      cb.d[i++] = {in, out, rowsOut, Rreal, C, Cp, acc_wg};
    };
    add(z, ZA, NB, NB, 19127, 19136);
    add(x, XB, NN, NN, 109, 128);
    add(w, WB, 1024, 1024, 750, 768);
    add(v, VB, 1024, 1024, 1024, 1024);
    add(side, SIDEB, 1024, 994, 1050, 1056);
    hipLaunchKernelGGL(conv_batch, dim3(acc_wg), dim3(256), 0, stream, cb);
  }

  // GAT layers (scores fused into GEMM for C=128 layers)
  const int Hs[4] = {8, 8, 8, 1};
  const int Kp[4] = {128, 768, 1024, 1024};
  const unsigned short* WTs[4] = {WT1, WT2, WT3, WT4};
  const int Fs[4] = {768, 1024, 1024, 128};
  for (int l = 0; l < 4; ++l) {
    int H = Hs[l], F = Fs[l], C = F / H;
    int gx = F / 128;
    int nwg = gx * (NN / 128);
    if (C == 128) {
      hipLaunchKernelGGL((gemm_mfma<0, 1, 1>), dim3(nwg), dim3(256), 0, stream,
                         XB, WTs[l], (const float*)nullptr, (void*)HLIN, F, Kp[l],
                         Kp[l], Kp[l], F, gx, 0, gas[l], gad[l], ALS, ALD, H);
    } else {
      hipLaunchKernelGGL((gemm_mfma<0, 1, 0>), dim3(nwg), dim3(256), 0, stream,
                         XB, WTs[l], (const float*)nullptr, (void*)HLIN, F, Kp[l],
                         Kp[l], Kp[l], F, gx, 0, (const float*)nullptr,
                         (const float*)nullptr, (float*)nullptr, (float*)nullptr, H);
      int totNH = NN * H;
      hipLaunchKernelGGL(gat_scores_bf, dim3((totNH + 255) / 256), dim3(256), 0, stream,
                         HLIN, gas[l], gad[l], ALS, ALD, H, C, totNH);
    }
    if (l == 0)
      hipLaunchKernelGGL((gat_agg_v5<768, 96, 8>), dim3(NN * 96 / 256), dim3(256), 0, stream,
                         ROWPTR, SRCL, ALS, ALD, HLIN, gb[l], XB);
    else if (l == 3)
      hipLaunchKernelGGL((gat_agg_v5<128, 128, 8>), dim3(NN * 16 / 256), dim3(256), 0, stream,
                         ROWPTR, SRCL, ALS, ALD, HLIN, gb[l], XB);
    else
      hipLaunchKernelGGL((gat_agg_v5<1024, 128, 16>), dim3(NN * 64 / 256), dim3(256), 0, stream,
                         ROWPTR, SRCL, ALS, ALD, HLIN, gb[l], XB);
  }

  // global max pool -> XGB bf16
  hipLaunchKernelGGL(pool_max, dim3(NB), dim3(128), 0, stream, XB, XGB);

  // B1: independent tail GEMMs {w1, v1, s1, x5}
  {
    GBatch b;
    int acc_wg = 0, i = 0;
    auto add = [&](const unsigned short* A, const unsigned short* BT, const float* bias,
                   void* C, int Npad, int Nreal, int K, int lda, int ldb, int ldc,
                   int zpad, int act, int obf, int Mreal) {
      int gx = Npad / 128;
      acc_wg += gx * 8;
      b.d[i++] = {A, BT, bias, C, Nreal, K, lda, ldb, ldc, gx, zpad, act, obf, Mreal, acc_wg};
    };
    add(WB, WTW1, w1_b, WMID, 768, 750, 768, 768, 768, 768, 1, 1, 1, 1024);
    add(VB, WTV1, v1_b, VMID, 256, 256, 1024, 1024, 1024, 256, 0, 1, 1, 1024);
    add(SIDEB, WTS1, s1_b, SEMID, 128, 64, 1056, 1056, 1056, 128, 1, 1, 1, 1024);
    add(XGB, WTX5, x5_b, X5O, 128, 64, 128, 128, 128, 128, 1, 1, 1, 1024);
    while (i < 5) { b.d[i] = b.d[i - 1]; b.d[i].wg_end = acc_wg; ++i; }
    hipLaunchKernelGGL(gemm_batch, dim3(acc_wg), dim3(256), 0, stream, b);
  }

  // z1 split-K (16 slices, f32 partials) + reduce -> ZB bf16
  hipLaunchKernelGGL(gemm_mfma_sk, dim3(1664), dim3(256), 0, stream, ZA, WTZ, PART, 19136, 19136, 1664);
  hipLaunchKernelGGL(zred, dim3((1024 * 1664 / 8 + 255) / 256), dim3(256), 0, stream, PART, z1_b, ZB);

  // output pointers
  float* outp = (float*)d_out;
  float* DN = outp + (size_t)NB * NSIDE;
  float* SN = DN + (size_t)NB * 64;

  // B2: {x6, w2, z2, v2, s2(tanh+rownorm -> SN)}
  {
    GBatch b;
    int acc_wg = 0, i = 0;
    auto add = [&](const unsigned short* A, const unsigned short* BT, const float* bias,
                   void* C, int Npad, int Nreal, int K, int lda, int ldb, int ldc,
                   int zpad, int act, int obf, int Mreal) {
      int gx = Npad / 128;
      acc_wg += gx * 8;
      b.d[i++] = {A, BT, bias, C, Nreal, K, lda, ldb, ldc, gx, zpad, act, obf, Mreal, acc_wg};
    };
    add(X5O, WTX6, x6_b, CAT192 + 0, 128, 64, 64, 128, 64, 192, 0, 1, 1, 1024);
    add(WMID, WTW2, w2_b, CAT192 + 64, 128, 64, 768, 768, 768, 192, 0, 1, 1, 1024);
    add(ZB, WTZ2, z2_b, CAT192 + 128, 128, 64, 1664, 1664, 1664, 192, 0, 1, 1, 1024);
    add(VMID, WTV2, v2_b, CAT128 + 64, 128, 64, 256, 256, 256, 128, 0, 1, 1, 1024);
    add(SEMID, WTS2, s2_b, SN, 128, 64, 64, 128, 64, 64, 0, 4, 0, 994);
    hipLaunchKernelGGL(gemm_batch, dim3(acc_wg), dim3(256), 0, stream, b);
  }

  // fused tail: agg GEMM -> col GEMM -> |tanh| -> rownorm -> DN
  hipLaunchKernelGGL(tail_fused, dim3(8), dim3(256), 0, stream,
                     CAT192, WTAGG, agg_b, CAT128, WTCOL, col_b, DN);

  // similarity
  hipLaunchKernelGGL(freq_k, dim3((NSIDE + 15) / 16, (NB + 15) / 16), dim3(256), 0, stream,
                     DN, SN, outp, NB, NSIDE);
}

// Round 15
// 936.586 us; speedup vs baseline: 1.0450x; 1.0177x over previous
//
#include <hip/hip_runtime.h>
#include <math.h>
#include <float.h>

#define E0 131072
#define NN 32768
#define NB 1024
#define NSIDE 994
#define ETOT (E0 + NN)

typedef short bf16x8 __attribute__((ext_vector_type(8)));
typedef unsigned short ushort8 __attribute__((ext_vector_type(8)));
typedef unsigned short ushort16 __attribute__((ext_vector_type(16)));
typedef float f32x4 __attribute__((ext_vector_type(4)));

__device__ inline float b2f(unsigned short u) { return __uint_as_float(((unsigned)u) << 16); }
__device__ inline unsigned short f2b(float f) {
  unsigned u = __float_as_uint(f);
  return (unsigned short)((u + 0x7fffu + ((u >> 16) & 1u)) >> 16);
}

__device__ inline void gload_lds16(const void* g, void* l) {
  __builtin_amdgcn_global_load_lds(
      (const __attribute__((address_space(1))) unsigned int*)g,
      (__attribute__((address_space(3))) unsigned int*)l, 16, 0, 0);
}

__global__ void fill_i32(int* p, int v, int n) {
  int i = blockIdx.x * blockDim.x + threadIdx.x;
  if (i < n) p[i] = v;
}

// ---------------- batched fp32 -> bf16 conversion with padding ----------------
struct CDesc { const float* in; unsigned short* out; int rowsOut, Rreal, C, Cp, wg_end; };
struct CBatch { CDesc d[5]; };
__global__ void conv_batch(CBatch cb) {
  int bid = blockIdx.x;
  int di = 0;
  while (bid >= cb.d[di].wg_end) ++di;
  const CDesc& g = cb.d[di];
  int rel = bid - (di ? cb.d[di - 1].wg_end : 0);
  size_t idx = (size_t)rel * 256 + threadIdx.x;
  size_t tot = (size_t)g.rowsOut * g.Cp;
  if (idx >= tot) return;
  int r = (int)(idx / g.Cp), c = (int)(idx % g.Cp);
  g.out[idx] = (r < g.Rreal && c < g.C) ? f2b(g.in[(size_t)r * g.C + c]) : (unsigned short)0;
}

// ---------------- batched transpose: W [K][N] f32 -> WT [Npad][Kp] bf16 ----------------
struct TDesc { const float* W; unsigned short* WT; int K, N, Kp, Npad, gx, wg_end; };
struct TBatch { TDesc d[16]; };
__global__ __launch_bounds__(256) void transpose_batch(TBatch tb) {
  __shared__ float t[32][33];
  int bid = blockIdx.x;
  int di = 0;
  while (bid >= tb.d[di].wg_end) ++di;
  const TDesc& g = tb.d[di];
  int rel = bid - (di ? tb.d[di - 1].wg_end : 0);
  int n0 = (rel % g.gx) * 32, k0 = (rel / g.gx) * 32;
  int tx = threadIdx.x & 31, ty = threadIdx.x >> 5;
  for (int r = ty; r < 32; r += 8) {
    int k = k0 + r, n = n0 + tx;
    t[r][tx] = (k < g.K && n < g.N) ? g.W[(size_t)k * g.N + n] : 0.f;
  }
  __syncthreads();
  for (int r = ty; r < 32; r += 8) {
    int n = n0 + r, k = k0 + tx;
    if (n < g.Npad && k < g.Kp)
      g.WT[(size_t)n * g.Kp + k] = (n < g.N) ? f2b(t[tx][r]) : (unsigned short)0;
  }
}

// ---------------- CSR build over dst ----------------
__global__ void count_deg(const int* __restrict__ ei, int* deg) {
  int e = blockIdx.x * blockDim.x + threadIdx.x;
  if (e >= ETOT) return;
  int dst = (e < E0) ? ei[E0 + e] : (e - E0);
  atomicAdd(&deg[dst], 1);
}

__global__ void scan_deg(const int* __restrict__ deg, int* rowptr, int* cursor) {
  __shared__ int part[1024];
  int tid = threadIdx.x;
  const int chunk = NN / 1024;  // 32
  int base = tid * chunk;
  int local[chunk];
  int sum = 0;
#pragma unroll
  for (int i = 0; i < chunk; ++i) { local[i] = sum; sum += deg[base + i]; }
  part[tid] = sum;
  __syncthreads();
  for (int off = 1; off < 1024; off <<= 1) {
    int t = (tid >= off) ? part[tid - off] : 0;
    __syncthreads();
    part[tid] += t;
    __syncthreads();
  }
  int offset = part[tid] - sum;
#pragma unroll
  for (int i = 0; i < chunk; ++i) {
    int v = offset + local[i];
    rowptr[base + i] = v;
    cursor[base + i] = v;
  }
  if (tid == 1023) rowptr[NN] = offset + sum;
}

__global__ void fill_csr(const int* __restrict__ ei, int* cursor, int* __restrict__ srcl) {
  int e = blockIdx.x * blockDim.x + threadIdx.x;
  if (e >= ETOT) return;
  int src, dst;
  if (e < E0) { src = ei[e]; dst = ei[E0 + e]; } else { src = dst = e - E0; }
  int p = atomicAdd(&cursor[dst], 1);
  srcl[p] = src;
}

// ---------------- bf16 MFMA GEMM, 2-phase dbuf; optional fused GAT scores ----------------
template <int ACT, int OBF, int SC>
__global__ __launch_bounds__(256) void gemm_mfma(
    const unsigned short* __restrict__ A, const unsigned short* __restrict__ BT,
    const float* __restrict__ bias, void* __restrict__ Cp,
    int Nreal, int K, int lda, int ldb, int ldc, int gx, int zpad,
    const float* __restrict__ asv, const float* __restrict__ adv,
    float* __restrict__ als, float* __restrict__ ald, int H) {
  __shared__ unsigned short As[2][128 * 32];
  __shared__ unsigned short Bs[2][128 * 32];
  const int nwg = gridDim.x;
  const int chunk = nwg >> 3;
  const int bid = blockIdx.x;
  const int swz = (bid & 7) * chunk + (bid >> 3);
  const int bm = (swz / gx) * 128, bn = (swz % gx) * 128;
  const int tid = threadIdx.x;
  const int wv = tid >> 6, lane = tid & 63;
  const int sr = lane >> 2;
  const int sk = ((lane & 3) ^ ((lane >> 3) & 3)) * 8;
  const int r16 = lane & 15, kq = lane >> 4;
  const int slot8 = (kq ^ ((r16 >> 1) & 3)) * 8;
  const int wr = wv >> 1, wc = wv & 1;
  f32x4 acc[4][4];
#pragma unroll
  for (int i = 0; i < 4; ++i)
#pragma unroll
    for (int j = 0; j < 4; ++j) acc[i][j] = (f32x4){0.f, 0.f, 0.f, 0.f};

  const unsigned short* Abase = A + (size_t)bm * lda;
  const unsigned short* Bbase = BT + (size_t)bn * ldb;
  auto stage = [&](int buf, int k0) {
    gload_lds16(Abase + (size_t)(wv * 16 + sr) * lda + k0 + sk, &As[buf][wv * 512]);
    gload_lds16(Abase + (size_t)(64 + wv * 16 + sr) * lda + k0 + sk, &As[buf][2048 + wv * 512]);
    gload_lds16(Bbase + (size_t)(wv * 16 + sr) * ldb + k0 + sk, &Bs[buf][wv * 512]);
    gload_lds16(Bbase + (size_t)(64 + wv * 16 + sr) * ldb + k0 + sk, &Bs[buf][2048 + wv * 512]);
  };
  stage(0, 0);
  __syncthreads();
  int cur = 0;
  for (int k0 = 0; k0 < K; k0 += 32) {
    if (k0 + 32 < K) stage(cur ^ 1, k0 + 32);
    bf16x8 af[4], bfr[4];
#pragma unroll
    for (int i = 0; i < 4; ++i)
      af[i] = *(const bf16x8*)&As[cur][(wr * 64 + i * 16 + r16) * 32 + slot8];
#pragma unroll
    for (int j = 0; j < 4; ++j)
      bfr[j] = *(const bf16x8*)&Bs[cur][(wc * 64 + j * 16 + r16) * 32 + slot8];
#pragma unroll
    for (int i = 0; i < 4; ++i)
#pragma unroll
      for (int j = 0; j < 4; ++j)
        acc[i][j] = __builtin_amdgcn_mfma_f32_16x16x32_bf16(af[i], bfr[j], acc[i][j], 0, 0, 0);
    __syncthreads();
    cur ^= 1;
  }
#pragma unroll
  for (int i = 0; i < 4; ++i) {
    int row = bm + wr * 64 + i * 16 + kq * 4;
#pragma unroll
    for (int j = 0; j < 4; ++j) {
      int col = bn + wc * 64 + j * 16 + r16;
      bool real = col < Nreal;
      if (!real && !zpad) continue;
      float bv = (bias && real) ? bias[col] : 0.f;
#pragma unroll
      for (int r = 0; r < 4; ++r) {
        float v = acc[i][j][r] + bv;
        if (ACT == 1) v = v > 0.f ? v : 0.f;
        else if (ACT == 2) v = tanhf(v);
        else if (ACT == 3) v = fabsf(tanhf(v));
        if (!real) v = 0.f;
        if (OBF) ((unsigned short*)Cp)[(size_t)(row + r) * ldc + col] = f2b(v);
        else ((float*)Cp)[(size_t)(row + r) * ldc + col] = v;
      }
    }
  }
  if (SC) {
    const int h = bn >> 7;
    float* scr = (float*)&As[0][0];
    float a_s[4], a_d[4];
#pragma unroll
    for (int j = 0; j < 4; ++j) {
      int cwh = wc * 64 + j * 16 + r16;
      a_s[j] = asv[h * 128 + cwh];
      a_d[j] = adv[h * 128 + cwh];
    }
#pragma unroll
    for (int i = 0; i < 4; ++i)
#pragma unroll
      for (int r = 0; r < 4; ++r) {
        float sp = 0.f, dp = 0.f;
#pragma unroll
        for (int j = 0; j < 4; ++j) {
          sp = fmaf(acc[i][j][r], a_s[j], sp);
          dp = fmaf(acc[i][j][r], a_d[j], dp);
        }
#pragma unroll
        for (int m = 1; m < 16; m <<= 1) {
          sp += __shfl_xor(sp, m);
          dp += __shfl_xor(dp, m);
        }
        if (r16 == 0) {
          int rl = wr * 64 + i * 16 + kq * 4 + r;
          scr[rl * 4 + wc * 2 + 0] = sp;
          scr[rl * 4 + wc * 2 + 1] = dp;
        }
      }
    __syncthreads();
    if (tid < 128) {
      float s = scr[tid * 4 + 0] + scr[tid * 4 + 2];
      float d = scr[tid * 4 + 1] + scr[tid * 4 + 3];
      als[(size_t)(bm + tid) * H + h] = s;
      ald[(size_t)(bm + tid) * H + h] = d;
    }
  }
}

// ---------------- batched runtime-act MFMA GEMM (2-phase dbuf) ----------------
struct GDesc {
  const unsigned short* A; const unsigned short* BT; const float* bias; void* C;
  int Nreal, K, lda, ldb, ldc, gx, zpad, act, obf, Mreal, wg_end;
};
struct GBatch { GDesc d[5]; };
__global__ __launch_bounds__(256) void gemm_batch(GBatch gb) {
  __shared__ unsigned short As[2][128 * 32];
  __shared__ unsigned short Bs[2][128 * 32];
  int bid = blockIdx.x;
  int di = 0;
  while (bid >= gb.d[di].wg_end) ++di;
  const GDesc& g = gb.d[di];
  int rel = bid - (di ? gb.d[di - 1].wg_end : 0);
  const int bm = (rel / g.gx) * 128, bn = (rel % g.gx) * 128;
  const int tid = threadIdx.x;
  const int wv = tid >> 6, lane = tid & 63;
  const int sr = lane >> 2;
  const int sk = ((lane & 3) ^ ((lane >> 3) & 3)) * 8;
  const int r16 = lane & 15, kq = lane >> 4;
  const int slot8 = (kq ^ ((r16 >> 1) & 3)) * 8;
  const int wr = wv >> 1, wc = wv & 1;
  f32x4 acc[4][4];
#pragma unroll
  for (int i = 0; i < 4; ++i)
#pragma unroll
    for (int j = 0; j < 4; ++j) acc[i][j] = (f32x4){0.f, 0.f, 0.f, 0.f};

  const unsigned short* Abase = g.A + (size_t)bm * g.lda;
  const unsigned short* Bbase = g.BT + (size_t)bn * g.ldb;
  auto stage = [&](int buf, int k0) {
    gload_lds16(Abase + (size_t)(wv * 16 + sr) * g.lda + k0 + sk, &As[buf][wv * 512]);
    gload_lds16(Abase + (size_t)(64 + wv * 16 + sr) * g.lda + k0 + sk, &As[buf][2048 + wv * 512]);
    gload_lds16(Bbase + (size_t)(wv * 16 + sr) * g.ldb + k0 + sk, &Bs[buf][wv * 512]);
    gload_lds16(Bbase + (size_t)(64 + wv * 16 + sr) * g.ldb + k0 + sk, &Bs[buf][2048 + wv * 512]);
  };
  stage(0, 0);
  __syncthreads();
  int cur = 0;
  for (int k0 = 0; k0 < g.K; k0 += 32) {
    if (k0 + 32 < g.K) stage(cur ^ 1, k0 + 32);
    bf16x8 af[4], bfr[4];
#pragma unroll
    for (int i = 0; i < 4; ++i)
      af[i] = *(const bf16x8*)&As[cur][(wr * 64 + i * 16 + r16) * 32 + slot8];
#pragma unroll
    for (int j = 0; j < 4; ++j)
      bfr[j] = *(const bf16x8*)&Bs[cur][(wc * 64 + j * 16 + r16) * 32 + slot8];
#pragma unroll
    for (int i = 0; i < 4; ++i)
#pragma unroll
      for (int j = 0; j < 4; ++j)
        acc[i][j] = __builtin_amdgcn_mfma_f32_16x16x32_bf16(af[i], bfr[j], acc[i][j], 0, 0, 0);
    __syncthreads();
    cur ^= 1;
  }
  if (g.act == 4) {
    if (wc == 0) {
#pragma unroll
      for (int i = 0; i < 4; ++i)
#pragma unroll
        for (int r = 0; r < 4; ++r) {
          int row = bm + wr * 64 + i * 16 + kq * 4 + r;
          float vv[4];
#pragma unroll
          for (int j = 0; j < 4; ++j) vv[j] = tanhf(acc[i][j][r] + g.bias[j * 16 + r16]);
          float ss = vv[0] * vv[0] + vv[1] * vv[1] + vv[2] * vv[2] + vv[3] * vv[3];
          ss += __shfl_xor(ss, 1);
          ss += __shfl_xor(ss, 2);
          ss += __shfl_xor(ss, 4);
          ss += __shfl_xor(ss, 8);
          float inv = 1.f / fmaxf(sqrtf(ss), 1e-12f);
          if (row < g.Mreal)
#pragma unroll
            for (int j = 0; j < 4; ++j)
              ((float*)g.C)[(size_t)row * g.ldc + j * 16 + r16] = vv[j] * inv;
        }
    }
    return;
  }
#pragma unroll
  for (int i = 0; i < 4; ++i) {
    int row = bm + wr * 64 + i * 16 + kq * 4;
#pragma unroll
    for (int j = 0; j < 4; ++j) {
      int col = bn + wc * 64 + j * 16 + r16;
      bool real = col < g.Nreal;
      if (!real && !g.zpad) continue;
      float bv = (g.bias && real) ? g.bias[col] : 0.f;
#pragma unroll
      for (int r = 0; r < 4; ++r) {
        float v = acc[i][j][r] + bv;
        if (g.act == 1) v = v > 0.f ? v : 0.f;
        else if (g.act == 2) v = tanhf(v);
        else if (g.act == 3) v = fabsf(tanhf(v));
        if (!real) v = 0.f;
        if (g.obf) ((unsigned short*)g.C)[(size_t)(row + r) * g.ldc + col] = f2b(v);
        else ((float*)g.C)[(size_t)(row + r) * g.ldc + col] = v;
      }
    }
  }
}

// ---------------- split-K MFMA GEMM for z1 (8 slices, single-buffer, f32 partials) ------
// grid=832; s=bid&7 -> XCD round-robin, one K-slice per XCD (L2 locality).
__global__ __launch_bounds__(256) void gemm_mfma_sk(
    const unsigned short* __restrict__ A, const unsigned short* __restrict__ BT,
    float* __restrict__ PART, int lda, int ldb, int ldc) {
  __shared__ unsigned short As[128 * 32];
  __shared__ unsigned short Bs[128 * 32];
  const int bid = blockIdx.x;
  const int s = bid & 7;
  const int pos = bid >> 3;            // 0..103
  const int bm = (pos / 13) * 128, bn = (pos % 13) * 128;
  const int base = s * 74 + (s < 6 ? s : 6);
  const int nsteps = 74 + (s < 6 ? 1 : 0);
  const int tid = threadIdx.x;
  const int wv = tid >> 6, lane = tid & 63;
  const int sr = lane >> 2;
  const int sk = ((lane & 3) ^ ((lane >> 3) & 3)) * 8;
  const int r16 = lane & 15, kq = lane >> 4;
  const int slot8 = (kq ^ ((r16 >> 1) & 3)) * 8;
  const int wr = wv >> 1, wc = wv & 1;
  f32x4 acc[4][4];
#pragma unroll
  for (int i = 0; i < 4; ++i)
#pragma unroll
    for (int j = 0; j < 4; ++j) acc[i][j] = (f32x4){0.f, 0.f, 0.f, 0.f};

  const unsigned short* Abase = A + (size_t)bm * lda;
  const unsigned short* Bbase = BT + (size_t)bn * ldb;
  for (int ks = 0; ks < nsteps; ++ks) {
    int k0 = (base + ks) * 32;
    gload_lds16(Abase + (size_t)(wv * 16 + sr) * lda + k0 + sk, &As[wv * 512]);
    gload_lds16(Abase + (size_t)(64 + wv * 16 + sr) * lda + k0 + sk, &As[2048 + wv * 512]);
    gload_lds16(Bbase + (size_t)(wv * 16 + sr) * ldb + k0 + sk, &Bs[wv * 512]);
    gload_lds16(Bbase + (size_t)(64 + wv * 16 + sr) * ldb + k0 + sk, &Bs[2048 + wv * 512]);
    __syncthreads();
    bf16x8 af[4], bfr[4];
#pragma unroll
    for (int i = 0; i < 4; ++i)
      af[i] = *(const bf16x8*)&As[(wr * 64 + i * 16 + r16) * 32 + slot8];
#pragma unroll
    for (int j = 0; j < 4; ++j)
      bfr[j] = *(const bf16x8*)&Bs[(wc * 64 + j * 16 + r16) * 32 + slot8];
#pragma unroll
    for (int i = 0; i < 4; ++i)
#pragma unroll
      for (int j = 0; j < 4; ++j)
        acc[i][j] = __builtin_amdgcn_mfma_f32_16x16x32_bf16(af[i], bfr[j], acc[i][j], 0, 0, 0);
    __syncthreads();
  }
  float* out = PART + (size_t)s * 1024 * ldc;
#pragma unroll
  for (int i = 0; i < 4; ++i) {
    int row = bm + wr * 64 + i * 16 + kq * 4;
#pragma unroll
    for (int j = 0; j < 4; ++j) {
      int col = bn + wc * 64 + j * 16 + r16;
      if (col >= 1600) continue;
#pragma unroll
      for (int r = 0; r < 4; ++r)
        out[(size_t)(row + r) * ldc + col] = acc[i][j][r];
    }
  }
}

// reduce 8 f32 K-slice partials + bias + relu -> ZB bf16 [1024][1664]
__global__ void zred(const float* __restrict__ PART, const float* __restrict__ bias,
                     unsigned short* __restrict__ ZB) {
  int g = blockIdx.x * blockDim.x + threadIdx.x;
  if (g >= 1024 * 1664 / 8) return;
  size_t base = (size_t)g * 8;
  int c0 = (int)(base % 1664);
  ushort8 o;
  if (c0 >= 1600) {
#pragma unroll
    for (int t = 0; t < 8; ++t) o[t] = 0;
  } else {
    float s[8] = {0.f, 0.f, 0.f, 0.f, 0.f, 0.f, 0.f, 0.f};
#pragma unroll
    for (int k = 0; k < 8; ++k) {
      const float* p = &PART[(size_t)k * 1024 * 1664 + base];
      float4 a = *(const float4*)p;
      float4 b = *(const float4*)(p + 4);
      s[0] += a.x; s[1] += a.y; s[2] += a.z; s[3] += a.w;
      s[4] += b.x; s[5] += b.y; s[6] += b.z; s[7] += b.w;
    }
#pragma unroll
    for (int t = 0; t < 8; ++t) {
      float v = s[t] + bias[c0 + t];
      o[t] = f2b(v > 0.f ? v : 0.f);
    }
  }
  *(ushort8*)&ZB[base] = o;
}

// ---------------- fused tail: agg GEMM -> LDS -> col GEMM -> |tanh| -> rownorm -> DN ----
__global__ __launch_bounds__(256) void tail_fused(
    const unsigned short* __restrict__ CAT192, const unsigned short* __restrict__ WTAGG,
    const float* __restrict__ agg_b, const unsigned short* __restrict__ CAT128,
    const unsigned short* __restrict__ WTCOL, const float* __restrict__ col_b,
    float* __restrict__ DN) {
  __shared__ unsigned short S1[128 * 32];
  __shared__ unsigned short S2[128 * 32];
  __shared__ unsigned short ACAT[128 * 128];
  const int bm = blockIdx.x * 128;
  const int tid = threadIdx.x;
  const int wv = tid >> 6, lane = tid & 63;
  const int sr = lane >> 2;
  const int sk = ((lane & 3) ^ ((lane >> 3) & 3)) * 8;
  const int r16 = lane & 15, kq = lane >> 4;
  const int slot8 = (kq ^ ((r16 >> 1) & 3)) * 8;
  const int wr = wv >> 1, wc = wv & 1;
  f32x4 acc[4][4];
#pragma unroll
  for (int i = 0; i < 4; ++i)
#pragma unroll
    for (int j = 0; j < 4; ++j) acc[i][j] = (f32x4){0.f, 0.f, 0.f, 0.f};

  const unsigned short* Abase = CAT192 + (size_t)bm * 192;
  for (int k0 = 0; k0 < 192; k0 += 32) {
    gload_lds16(Abase + (size_t)(wv * 16 + sr) * 192 + k0 + sk, &S1[wv * 512]);
    gload_lds16(Abase + (size_t)(64 + wv * 16 + sr) * 192 + k0 + sk, &S1[2048 + wv * 512]);
    gload_lds16(WTAGG + (size_t)(wv * 16 + sr) * 192 + k0 + sk, &S2[wv * 512]);
    gload_lds16(WTAGG + (size_t)(64 + wv * 16 + sr) * 192 + k0 + sk, &S2[2048 + wv * 512]);
    __syncthreads();
    bf16x8 af[4], bfr[4];
#pragma unroll
    for (int i = 0; i < 4; ++i)
      af[i] = *(const bf16x8*)&S1[(wr * 64 + i * 16 + r16) * 32 + slot8];
#pragma unroll
    for (int j = 0; j < 4; ++j)
      bfr[j] = *(const bf16x8*)&S2[(wc * 64 + j * 16 + r16) * 32 + slot8];
#pragma unroll
    for (int i = 0; i < 4; ++i)
#pragma unroll
      for (int j = 0; j < 4; ++j)
        acc[i][j] = __builtin_amdgcn_mfma_f32_16x16x32_bf16(af[i], bfr[j], acc[i][j], 0, 0, 0);
    __syncthreads();
  }
  if (wc == 0) {
#pragma unroll
    for (int i = 0; i < 4; ++i)
#pragma unroll
      for (int j = 0; j < 4; ++j) {
        int col = j * 16 + r16;
#pragma unroll
        for (int r = 0; r < 4; ++r) {
          int rl = wr * 64 + i * 16 + kq * 4 + r;
          ACAT[rl * 128 + col] = f2b(acc[i][j][r] + agg_b[col]);
        }
      }
  }
  for (int idx = tid; idx < 128 * 8; idx += 256) {
    int row = idx >> 3, c8 = (idx & 7) * 8;
    *(ushort8*)&ACAT[row * 128 + 64 + c8] =
        *(const ushort8*)&CAT128[(size_t)(bm + row) * 128 + 64 + c8];
  }
#pragma unroll
  for (int i = 0; i < 4; ++i)
#pragma unroll
    for (int j = 0; j < 4; ++j) acc[i][j] = (f32x4){0.f, 0.f, 0.f, 0.f};
  __syncthreads();

  for (int k0 = 0; k0 < 128; k0 += 32) {
    gload_lds16(WTCOL + (size_t)(wv * 16 + sr) * 128 + k0 + sk, &S1[wv * 512]);
    gload_lds16(WTCOL + (size_t)(64 + wv * 16 + sr) * 128 + k0 + sk, &S1[2048 + wv * 512]);
    __syncthreads();
    bf16x8 af[4], bfr[4];
#pragma unroll
    for (int i = 0; i < 4; ++i)
      af[i] = *(const bf16x8*)&ACAT[(wr * 64 + i * 16 + r16) * 128 + k0 + kq * 8];
#pragma unroll
    for (int j = 0; j < 4; ++j)
      bfr[j] = *(const bf16x8*)&S1[(wc * 64 + j * 16 + r16) * 32 + slot8];
#pragma unroll
    for (int i = 0; i < 4; ++i)
#pragma unroll
      for (int j = 0; j < 4; ++j)
        acc[i][j] = __builtin_amdgcn_mfma_f32_16x16x32_bf16(af[i], bfr[j], acc[i][j], 0, 0, 0);
    __syncthreads();
  }
  if (wc == 0) {
#pragma unroll
    for (int i = 0; i < 4; ++i)
#pragma unroll
      for (int r = 0; r < 4; ++r) {
        int row = bm + wr * 64 + i * 16 + kq * 4 + r;
        float vv[4];
#pragma unroll
        for (int j = 0; j < 4; ++j) vv[j] = fabsf(tanhf(acc[i][j][r] + col_b[j * 16 + r16]));
        float ss = vv[0] * vv[0] + vv[1] * vv[1] + vv[2] * vv[2] + vv[3] * vv[3];
        ss += __shfl_xor(ss, 1);
        ss += __shfl_xor(ss, 2);
        ss += __shfl_xor(ss, 4);
        ss += __shfl_xor(ss, 8);
        float inv = 1.f / fmaxf(sqrtf(ss), 1e-12f);
#pragma unroll
        for (int j = 0; j < 4; ++j)
          DN[(size_t)row * 64 + j * 16 + r16] = vv[j] * inv;
      }
  }
}

// ---------------- GAT pieces ----------------
__global__ void gat_scores_bf(const unsigned short* __restrict__ hlin,
                              const float* __restrict__ a_s, const float* __restrict__ a_d,
                              float* __restrict__ als, float* __restrict__ ald,
                              int H, int C, int tot) {
  int idx = blockIdx.x * blockDim.x + threadIdx.x;
  if (idx >= tot) return;
  int n = idx / H, h = idx - n * H;
  const unsigned short* base = hlin + (size_t)n * H * C + (size_t)h * C;
  const float* as = a_s + h * C;
  const float* ad = a_d + h * C;
  float ss = 0.f, sd = 0.f;
  for (int c = 0; c < C; c += 8) {
    ushort8 v = *(const ushort8*)(base + c);
#pragma unroll
    for (int t = 0; t < 8; ++t) {
      float f = b2f(v[t]);
      ss = fmaf(f, as[c + t], ss);
      sd = fmaf(f, ad[c + t], sd);
    }
  }
  als[idx] = ss;
  ald[idx] = sd;
}

// aggregate with INLINE attention; EPT=16 (chunks never straddle heads: C % 16 == 0).
template <int F, int C, int EPT>
__global__ __launch_bounds__(256) void gat_agg_v5(
    const int* __restrict__ rowptr, const int* __restrict__ srcl,
    const float* __restrict__ als, const float* __restrict__ ald,
    const unsigned short* __restrict__ hlin,
    const float* __restrict__ bias, unsigned short* __restrict__ out) {
  constexpr int H = F / C;
  constexpr int CPN = F / EPT;
  int gidx = blockIdx.x * 256 + threadIdx.x;
  if (gidx >= NN * CPN) return;
  int node = gidx / CPN;
  int c0 = (gidx - node * CPN) * EPT;
  int h = c0 / C;
  float aldv = ald[node * H + h];
  float s = 0.f;
  float acc[EPT];
#pragma unroll
  for (int t = 0; t < EPT; ++t) acc[t] = 0.f;
  int start = rowptr[node], end = rowptr[node + 1];
  for (int k = start; k < end; ++k) {
    int src = srcl[k];
    float e = als[src * H + h] + aldv;
    e = (e >= 0.f) ? e : 0.2f * e;
    float p = __expf(e);
    s += p;
    if (EPT == 8) {
      ushort8 hv = *(const ushort8*)(hlin + (size_t)src * F + c0);
#pragma unroll
      for (int t = 0; t < 8; ++t) acc[t] = fmaf(p, b2f(hv[t]), acc[t]);
    } else {
      ushort16 hv = *(const ushort16*)(hlin + (size_t)src * F + c0);
#pragma unroll
      for (int t = 0; t < 16; ++t) acc[t] = fmaf(p, b2f(hv[t]), acc[t]);
    }
  }
  float inv_s = 1.f / s;
#pragma unroll
  for (int t8 = 0; t8 < EPT / 8; ++t8) {
    ushort8 o;
#pragma unroll
    for (int t = 0; t < 8; ++t) {
      float val = acc[t8 * 8 + t] * inv_s + bias[c0 + t8 * 8 + t];
      o[t] = f2b(val > 0.f ? val : 0.f);
    }
    *(ushort8*)(out + (size_t)node * F + c0 + t8 * 8) = o;
  }
}

__global__ void pool_max(const unsigned short* __restrict__ xb,
                         unsigned short* __restrict__ xgb) {
  int g = blockIdx.x, c = threadIdx.x;  // 128 threads
  const unsigned short* base = xb + (size_t)g * 32 * 128 + c;
  float m = -FLT_MAX;
#pragma unroll 8
  for (int n = 0; n < 32; ++n) m = fmaxf(m, b2f(base[n * 128]));
  xgb[g * 128 + c] = f2b(m);
}

__global__ __launch_bounds__(256) void freq_k(const float* __restrict__ dn,
                                              const float* __restrict__ sn,
                                              float* __restrict__ C, int M, int N) {
  __shared__ float As[16][64];
  __shared__ float Bs[16][65];
  int tid = threadIdx.x;
  int tx = tid & 15, ty = tid >> 4;
  int bi = blockIdx.y * 16, bj = blockIdx.x * 16;
#pragma unroll
  for (int t = 0; t < 4; ++t) {
    int idx = tid * 4 + t;
    int r = idx >> 6, c = idx & 63;
    As[r][c] = (bi + r < M) ? dn[(bi + r) * 64 + c] : 0.f;
    Bs[r][c] = (bj + r < N) ? sn[(bj + r) * 64 + c] : 0.f;
  }
  __syncthreads();
  float acc = 0.f;
#pragma unroll
  for (int k = 0; k < 64; ++k) acc = fmaf(As[ty][k], Bs[tx][k], acc);
  if (bi + ty < M && bj + tx < N) C[(size_t)(bi + ty) * N + (bj + tx)] = 5.f * acc;
}

// ---------------- launch ----------------
extern "C" void kernel_launch(void* const* d_in, const int* in_sizes, int n_in,
                              void* d_out, int out_size, void* d_ws, size_t ws_size,
                              hipStream_t stream) {
  const float* x = (const float*)d_in[0];
  const int* ei = (const int*)d_in[1];
  const float* w = (const float*)d_in[3];
  const float* z = (const float*)d_in[4];
  const float* v = (const float*)d_in[5];
  const float* side = (const float*)d_in[6];
  const float* gW[4] = {(const float*)d_in[7], (const float*)d_in[11],
                        (const float*)d_in[15], (const float*)d_in[19]};
  const float* gas[4] = {(const float*)d_in[8], (const float*)d_in[12],
                         (const float*)d_in[16], (const float*)d_in[20]};
  const float* gad[4] = {(const float*)d_in[9], (const float*)d_in[13],
                         (const float*)d_in[17], (const float*)d_in[21]};
  const float* gb[4] = {(const float*)d_in[10], (const float*)d_in[14],
                        (const float*)d_in[18], (const float*)d_in[22]};
  const float* x5_W = (const float*)d_in[23]; const float* x5_b = (const float*)d_in[24];
  const float* x6_W = (const float*)d_in[25]; const float* x6_b = (const float*)d_in[26];
  const float* w1_W = (const float*)d_in[27]; const float* w1_b = (const float*)d_in[28];
  const float* w2_W = (const float*)d_in[29]; const float* w2_b = (const float*)d_in[30];
  const float* z1_W = (const float*)d_in[31]; const float* z1_b = (const float*)d_in[32];
  const float* z2_W = (const float*)d_in[33]; const float* z2_b = (const float*)d_in[34];
  const float* v1_W = (const float*)d_in[35]; const float* v1_b = (const float*)d_in[36];
  const float* v2_W = (const float*)d_in[37]; const float* v2_b = (const float*)d_in[38];
  const float* agg_W = (const float*)d_in[39]; const float* agg_b = (const float*)d_in[40];
  const float* col_W = (const float*)d_in[41]; const float* col_b = (const float*)d_in[42];
  const float* s1_W = (const float*)d_in[43]; const float* s1_b = (const float*)d_in[44];
  const float* s2_W = (const float*)d_in[45]; const float* s2_b = (const float*)d_in[46];

  char* wsb = (char*)d_ws;
  size_t off = 0;
  auto alloc = [&](size_t bytes) {
    void* p = wsb + off;
    off = (off + bytes + 255) & ~(size_t)255;
    return p;
  };
  unsigned short* HLIN = (unsigned short*)alloc((size_t)NN * 1024 * 2);
  unsigned short* XB = (unsigned short*)alloc((size_t)NN * 1024 * 2);
  unsigned short* WTZ = (unsigned short*)alloc((size_t)1664 * 19136 * 2);
  unsigned short* ZA = (unsigned short*)alloc((size_t)1024 * 19136 * 2);
  unsigned short* WT1 = (unsigned short*)alloc((size_t)768 * 128 * 2);
  unsigned short* WT2 = (unsigned short*)alloc((size_t)1024 * 768 * 2);
  unsigned short* WT3 = (unsigned short*)alloc((size_t)1024 * 1024 * 2);
  unsigned short* WT4 = (unsigned short*)alloc((size_t)128 * 1024 * 2);
  unsigned short* WTW1 = (unsigned short*)alloc((size_t)768 * 768 * 2);
  unsigned short* WTW2 = (unsigned short*)alloc((size_t)128 * 768 * 2);
  unsigned short* WTZ2 = (unsigned short*)alloc((size_t)128 * 1664 * 2);
  unsigned short* WTV1 = (unsigned short*)alloc((size_t)256 * 1024 * 2);
  unsigned short* WTV2 = (unsigned short*)alloc((size_t)128 * 256 * 2);
  unsigned short* WTX5 = (unsigned short*)alloc((size_t)128 * 128 * 2);
  unsigned short* WTX6 = (unsigned short*)alloc((size_t)128 * 64 * 2);
  unsigned short* WTAGG = (unsigned short*)alloc((size_t)128 * 192 * 2);
  unsigned short* WTCOL = (unsigned short*)alloc((size_t)128 * 128 * 2);
  unsigned short* WTS1 = (unsigned short*)alloc((size_t)128 * 1056 * 2);
  unsigned short* WTS2 = (unsigned short*)alloc((size_t)128 * 64 * 2);
  unsigned short* WB = (unsigned short*)alloc((size_t)1024 * 768 * 2);
  unsigned short* VB = (unsigned short*)alloc((size_t)1024 * 1024 * 2);
  unsigned short* SIDEB = (unsigned short*)alloc((size_t)1024 * 1056 * 2);
  unsigned short* XGB = (unsigned short*)alloc((size_t)1024 * 128 * 2);
  unsigned short* ZB = (unsigned short*)alloc((size_t)1024 * 1664 * 2);
  unsigned short* X5O = (unsigned short*)alloc((size_t)1024 * 128 * 2);
  unsigned short* WMID = (unsigned short*)alloc((size_t)1024 * 768 * 2);
  unsigned short* VMID = (unsigned short*)alloc((size_t)1024 * 256 * 2);
  unsigned short* SEMID = (unsigned short*)alloc((size_t)1024 * 128 * 2);
  unsigned short* CAT192 = (unsigned short*)alloc((size_t)1024 * 192 * 2);
  unsigned short* CAT128 = (unsigned short*)alloc((size_t)1024 * 128 * 2);
  float* ALS = (float*)alloc((size_t)NN * 8 * 4);
  float* ALD = (float*)alloc((size_t)NN * 8 * 4);
  int* DEG = (int*)alloc((size_t)NN * 4);
  int* ROWPTR = (int*)alloc((size_t)(NN + 1) * 4);
  int* CURSOR = (int*)alloc((size_t)NN * 4);
  int* SRCL = (int*)alloc((size_t)ETOT * 4);
  float* PART = (float*)HLIN;  // 8x1024x1664 f32 = 54.5MB over dead HLIN

  // CSR build
  hipLaunchKernelGGL(fill_i32, dim3((NN + 255) / 256), dim3(256), 0, stream, DEG, 0, NN);
  hipLaunchKernelGGL(count_deg, dim3((ETOT + 255) / 256), dim3(256), 0, stream, ei, DEG);
  hipLaunchKernelGGL(scan_deg, dim3(1), dim3(1024), 0, stream, DEG, ROWPTR, CURSOR);
  hipLaunchKernelGGL(fill_csr, dim3((ETOT + 255) / 256), dim3(256), 0, stream, ei, CURSOR, SRCL);

  // batched weight transposes
  {
    TBatch tb;
    int acc_wg = 0, i = 0;
    auto add = [&](const float* W, unsigned short* WT, int K, int N, int Kp, int Npad) {
      int gx = Npad / 32, gy = Kp / 32;
      acc_wg += gx * gy;
      tb.d[i++] = {W, WT, K, N, Kp, Npad, gx, acc_wg};
    };
    add(z1_W, WTZ, 19127, 1600, 19136, 1664);
    add(gW[0], WT1, 109, 768, 128, 768);
    add(gW[1], WT2, 768, 1024, 768, 1024);
    add(gW[2], WT3, 1024, 1024, 1024, 1024);
    add(gW[3], WT4, 1024, 128, 1024, 128);
    add(w1_W, WTW1, 750, 750, 768, 768);
    add(w2_W, WTW2, 750, 64, 768, 128);
    add(z2_W, WTZ2, 1600, 64, 1664, 128);
    add(v1_W, WTV1, 1024, 256, 1024, 256);
    add(v2_W, WTV2, 256, 64, 256, 128);
    add(x5_W, WTX5, 128, 64, 128, 128);
    add(x6_W, WTX6, 64, 64, 64, 128);
    add(agg_W, WTAGG, 192, 64, 192, 128);
    add(col_W, WTCOL, 128, 64, 128, 128);
    add(s1_W, WTS1, 1050, 64, 1056, 128);
    add(s2_W, WTS2, 64, 64, 64, 128);
    hipLaunchKernelGGL(transpose_batch, dim3(acc_wg), dim3(256), 0, stream, tb);
  }

  // batched input conversions
  {
    CBatch cb;
    int acc_wg = 0, i = 0;
    auto add = [&](const float* in, unsigned short* out, int rowsOut, int Rreal, int C, int Cp) {
      acc_wg += (int)(((size_t)rowsOut * Cp + 255) / 256);
      cb.d[i++] = {in, out, rowsOut, Rreal, C, Cp, acc_wg};
    };
    add(z, ZA, NB, NB, 19127, 19136);
    add(x, XB, NN, NN, 109, 128);
    add(w, WB, 1024, 1024, 750, 768);
    add(v, VB, 1024, 1024, 1024, 1024);
    add(side, SIDEB, 1024, 994, 1050, 1056);
    hipLaunchKernelGGL(conv_batch, dim3(acc_wg), dim3(256), 0, stream, cb);
  }

  // GAT layers (scores fused into GEMM for C=128 layers)
  const int Hs[4] = {8, 8, 8, 1};
  const int Kp[4] = {128, 768, 1024, 1024};
  const unsigned short* WTs[4] = {WT1, WT2, WT3, WT4};
  const int Fs[4] = {768, 1024, 1024, 128};
  for (int l = 0; l < 4; ++l) {
    int H = Hs[l], F = Fs[l], C = F / H;
    int gx = F / 128;
    int nwg = gx * (NN / 128);
    if (C == 128) {
      hipLaunchKernelGGL((gemm_mfma<0, 1, 1>), dim3(nwg), dim3(256), 0, stream,
                         XB, WTs[l], (const float*)nullptr, (void*)HLIN, F, Kp[l],
                         Kp[l], Kp[l], F, gx, 0, gas[l], gad[l], ALS, ALD, H);
    } else {
      hipLaunchKernelGGL((gemm_mfma<0, 1, 0>), dim3(nwg), dim3(256), 0, stream,
                         XB, WTs[l], (const float*)nullptr, (void*)HLIN, F, Kp[l],
                         Kp[l], Kp[l], F, gx, 0, (const float*)nullptr,
                         (const float*)nullptr, (float*)nullptr, (float*)nullptr, H);
      int totNH = NN * H;
      hipLaunchKernelGGL(gat_scores_bf, dim3((totNH + 255) / 256), dim3(256), 0, stream,
                         HLIN, gas[l], gad[l], ALS, ALD, H, C, totNH);
    }
    if (l == 0)
      hipLaunchKernelGGL((gat_agg_v5<768, 96, 16>), dim3(NN * 48 / 256), dim3(256), 0, stream,
                         ROWPTR, SRCL, ALS, ALD, HLIN, gb[l], XB);
    else if (l == 3)
      hipLaunchKernelGGL((gat_agg_v5<128, 128, 16>), dim3(NN * 8 / 256), dim3(256), 0, stream,
                         ROWPTR, SRCL, ALS, ALD, HLIN, gb[l], XB);
    else
      hipLaunchKernelGGL((gat_agg_v5<1024, 128, 16>), dim3(NN * 64 / 256), dim3(256), 0, stream,
                         ROWPTR, SRCL, ALS, ALD, HLIN, gb[l], XB);
  }

  // global max pool -> XGB bf16
  hipLaunchKernelGGL(pool_max, dim3(NB), dim3(128), 0, stream, XB, XGB);

  // B1: independent tail GEMMs {w1, v1, s1, x5}
  {
    GBatch b;
    int acc_wg = 0, i = 0;
    auto add = [&](const unsigned short* A, const unsigned short* BT, const float* bias,
                   void* C, int Npad, int Nreal, int K, int lda, int ldb, int ldc,
                   int zpad, int act, int obf, int Mreal) {
      int gx = Npad / 128;
      acc_wg += gx * 8;
      b.d[i++] = {A, BT, bias, C, Nreal, K, lda, ldb, ldc, gx, zpad, act, obf, Mreal, acc_wg};
    };
    add(WB, WTW1, w1_b, WMID, 768, 750, 768, 768, 768, 768, 1, 1, 1, 1024);
    add(VB, WTV1, v1_b, VMID, 256, 256, 1024, 1024, 1024, 256, 0, 1, 1, 1024);
    add(SIDEB, WTS1, s1_b, SEMID, 128, 64, 1056, 1056, 1056, 128, 1, 1, 1, 1024);
    add(XGB, WTX5, x5_b, X5O, 128, 64, 128, 128, 128, 128, 1, 1, 1, 1024);
    while (i < 5) { b.d[i] = b.d[i - 1]; b.d[i].wg_end = acc_wg; ++i; }
    hipLaunchKernelGGL(gemm_batch, dim3(acc_wg), dim3(256), 0, stream, b);
  }

  // z1 split-K (8 slices, f32 partials) + reduce -> ZB bf16
  hipLaunchKernelGGL(gemm_mfma_sk, dim3(832), dim3(256), 0, stream, ZA, WTZ, PART, 19136, 19136, 1664);
  hipLaunchKernelGGL(zred, dim3((1024 * 1664 / 8 + 255) / 256), dim3(256), 0, stream, PART, z1_b, ZB);

  // output pointers
  float* outp = (float*)d_out;
  float* DN = outp + (size_t)NB * NSIDE;
  float* SN = DN + (size_t)NB * 64;

  // B2: {x6, w2, z2, v2, s2(tanh+rownorm -> SN)}
  {
    GBatch b;
    int acc_wg = 0, i = 0;
    auto add = [&](const unsigned short* A, const unsigned short* BT, const float* bias,
                   void* C, int Npad, int Nreal, int K, int lda, int ldb, int ldc,
                   int zpad, int act, int obf, int Mreal) {
      int gx = Npad / 128;
      acc_wg += gx * 8;
      b.d[i++] = {A, BT, bias, C, Nreal, K, lda, ldb, ldc, gx, zpad, act, obf, Mreal, acc_wg};
    };
    add(X5O, WTX6, x6_b, CAT192 + 0, 128, 64, 64, 128, 64, 192, 0, 1, 1, 1024);
    add(WMID, WTW2, w2_b, CAT192 + 64, 128, 64, 768, 768, 768, 192, 0, 1, 1, 1024);
    add(ZB, WTZ2, z2_b, CAT192 + 128, 128, 64, 1664, 1664, 1664, 192, 0, 1, 1, 1024);
    add(VMID, WTV2, v2_b, CAT128 + 64, 128, 64, 256, 256, 256, 128, 0, 1, 1, 1024);
    add(SEMID, WTS2, s2_b, SN, 128, 64, 64, 128, 64, 64, 0, 4, 0, 994);
    hipLaunchKernelGGL(gemm_batch, dim3(acc_wg), dim3(256), 0, stream, b);
  }

  // fused tail: agg GEMM -> col GEMM -> |tanh| -> rownorm -> DN
  hipLaunchKernelGGL(tail_fused, dim3(8), dim3(256), 0, stream,
                     CAT192, WTAGG, agg_b, CAT128, WTCOL, col_b, DN);

  // similarity
  hipLaunchKernelGGL(freq_k, dim3((NSIDE + 15) / 16, (NB + 15) / 16), dim3(256), 0, stream,
                     DN, SN, outp, NB, NSIDE);
}

// Round 16
// 861.371 us; speedup vs baseline: 1.1362x; 1.0873x over previous
//
#include <hip/hip_runtime.h>
#include <math.h>
#include <float.h>

#define E0 131072
#define NN 32768
#define NB 1024
#define NSIDE 994
#define ETOT (E0 + NN)

typedef short bf16x8 __attribute__((ext_vector_type(8)));
typedef unsigned short ushort8 __attribute__((ext_vector_type(8)));
typedef unsigned short ushort16 __attribute__((ext_vector_type(16)));
typedef float f32x4 __attribute__((ext_vector_type(4)));

__device__ inline float b2f(unsigned short u) { return __uint_as_float(((unsigned)u) << 16); }
__device__ inline unsigned short f2b(float f) {
  unsigned u = __float_as_uint(f);
  return (unsigned short)((u + 0x7fffu + ((u >> 16) & 1u)) >> 16);
}

__device__ inline void gload_lds16(const void* g, void* l) {
  __builtin_amdgcn_global_load_lds(
      (const __attribute__((address_space(1))) unsigned int*)g,
      (__attribute__((address_space(3))) unsigned int*)l, 16, 0, 0);
}

__global__ void fill_i32(int* p, int v, int n) {
  int i = blockIdx.x * blockDim.x + threadIdx.x;
  if (i < n) p[i] = v;
}

// ---------------- batched fp32 -> bf16 conversion with padding ----------------
struct CDesc { const float* in; unsigned short* out; int rowsOut, Rreal, C, Cp, wg_end; };
struct CBatch { CDesc d[5]; };
__global__ void conv_batch(CBatch cb) {
  int bid = blockIdx.x;
  int di = 0;
  while (bid >= cb.d[di].wg_end) ++di;
  const CDesc& g = cb.d[di];
  int rel = bid - (di ? cb.d[di - 1].wg_end : 0);
  size_t idx = (size_t)rel * 256 + threadIdx.x;
  size_t tot = (size_t)g.rowsOut * g.Cp;
  if (idx >= tot) return;
  int r = (int)(idx / g.Cp), c = (int)(idx % g.Cp);
  g.out[idx] = (r < g.Rreal && c < g.C) ? f2b(g.in[(size_t)r * g.C + c]) : (unsigned short)0;
}

// ---------------- batched transpose: W [K][N] f32 -> WT [Npad][Kp] bf16 ----------------
struct TDesc { const float* W; unsigned short* WT; int K, N, Kp, Npad, gx, wg_end; };
struct TBatch { TDesc d[16]; };
__global__ __launch_bounds__(256) void transpose_batch(TBatch tb) {
  __shared__ float t[32][33];
  int bid = blockIdx.x;
  int di = 0;
  while (bid >= tb.d[di].wg_end) ++di;
  const TDesc& g = tb.d[di];
  int rel = bid - (di ? tb.d[di - 1].wg_end : 0);
  int n0 = (rel % g.gx) * 32, k0 = (rel / g.gx) * 32;
  int tx = threadIdx.x & 31, ty = threadIdx.x >> 5;
  for (int r = ty; r < 32; r += 8) {
    int k = k0 + r, n = n0 + tx;
    t[r][tx] = (k < g.K && n < g.N) ? g.W[(size_t)k * g.N + n] : 0.f;
  }
  __syncthreads();
  for (int r = ty; r < 32; r += 8) {
    int n = n0 + r, k = k0 + tx;
    if (n < g.Npad && k < g.Kp)
      g.WT[(size_t)n * g.Kp + k] = (n < g.N) ? f2b(t[tx][r]) : (unsigned short)0;
  }
}

// ---------------- CSR build over dst ----------------
__global__ void count_deg(const int* __restrict__ ei, int* deg) {
  int e = blockIdx.x * blockDim.x + threadIdx.x;
  if (e >= ETOT) return;
  int dst = (e < E0) ? ei[E0 + e] : (e - E0);
  atomicAdd(&deg[dst], 1);
}

__global__ void scan_deg(const int* __restrict__ deg, int* rowptr, int* cursor) {
  __shared__ int part[1024];
  int tid = threadIdx.x;
  const int chunk = NN / 1024;  // 32
  int base = tid * chunk;
  int local[chunk];
  int sum = 0;
#pragma unroll
  for (int i = 0; i < chunk; ++i) { local[i] = sum; sum += deg[base + i]; }
  part[tid] = sum;
  __syncthreads();
  for (int off = 1; off < 1024; off <<= 1) {
    int t = (tid >= off) ? part[tid - off] : 0;
    __syncthreads();
    part[tid] += t;
    __syncthreads();
  }
  int offset = part[tid] - sum;
#pragma unroll
  for (int i = 0; i < chunk; ++i) {
    int v = offset + local[i];
    rowptr[base + i] = v;
    cursor[base + i] = v;
  }
  if (tid == 1023) rowptr[NN] = offset + sum;
}

__global__ void fill_csr(const int* __restrict__ ei, int* cursor, int* __restrict__ srcl) {
  int e = blockIdx.x * blockDim.x + threadIdx.x;
  if (e >= ETOT) return;
  int src, dst;
  if (e < E0) { src = ei[e]; dst = ei[E0 + e]; } else { src = dst = e - E0; }
  int p = atomicAdd(&cursor[dst], 1);
  srcl[p] = src;
}

// ---------------- bf16 MFMA GEMM, 128-tile, 2-phase dbuf; optional fused scores ---------
template <int ACT, int OBF, int SC>
__global__ __launch_bounds__(256) void gemm_mfma(
    const unsigned short* __restrict__ A, const unsigned short* __restrict__ BT,
    const float* __restrict__ bias, void* __restrict__ Cp,
    int Nreal, int K, int lda, int ldb, int ldc, int gx, int zpad,
    const float* __restrict__ asv, const float* __restrict__ adv,
    float* __restrict__ als, float* __restrict__ ald, int H) {
  __shared__ unsigned short As[2][128 * 32];
  __shared__ unsigned short Bs[2][128 * 32];
  const int nwg = gridDim.x;
  const int chunk = nwg >> 3;
  const int bid = blockIdx.x;
  const int swz = (bid & 7) * chunk + (bid >> 3);
  const int bm = (swz / gx) * 128, bn = (swz % gx) * 128;
  const int tid = threadIdx.x;
  const int wv = tid >> 6, lane = tid & 63;
  const int sr = lane >> 2;
  const int sk = ((lane & 3) ^ ((lane >> 3) & 3)) * 8;
  const int r16 = lane & 15, kq = lane >> 4;
  const int slot8 = (kq ^ ((r16 >> 1) & 3)) * 8;
  const int wr = wv >> 1, wc = wv & 1;
  f32x4 acc[4][4];
#pragma unroll
  for (int i = 0; i < 4; ++i)
#pragma unroll
    for (int j = 0; j < 4; ++j) acc[i][j] = (f32x4){0.f, 0.f, 0.f, 0.f};

  const unsigned short* Abase = A + (size_t)bm * lda;
  const unsigned short* Bbase = BT + (size_t)bn * ldb;
  auto stage = [&](int buf, int k0) {
    gload_lds16(Abase + (size_t)(wv * 16 + sr) * lda + k0 + sk, &As[buf][wv * 512]);
    gload_lds16(Abase + (size_t)(64 + wv * 16 + sr) * lda + k0 + sk, &As[buf][2048 + wv * 512]);
    gload_lds16(Bbase + (size_t)(wv * 16 + sr) * ldb + k0 + sk, &Bs[buf][wv * 512]);
    gload_lds16(Bbase + (size_t)(64 + wv * 16 + sr) * ldb + k0 + sk, &Bs[buf][2048 + wv * 512]);
  };
  stage(0, 0);
  __syncthreads();
  int cur = 0;
  for (int k0 = 0; k0 < K; k0 += 32) {
    if (k0 + 32 < K) stage(cur ^ 1, k0 + 32);
    bf16x8 af[4], bfr[4];
#pragma unroll
    for (int i = 0; i < 4; ++i)
      af[i] = *(const bf16x8*)&As[cur][(wr * 64 + i * 16 + r16) * 32 + slot8];
#pragma unroll
    for (int j = 0; j < 4; ++j)
      bfr[j] = *(const bf16x8*)&Bs[cur][(wc * 64 + j * 16 + r16) * 32 + slot8];
#pragma unroll
    for (int i = 0; i < 4; ++i)
#pragma unroll
      for (int j = 0; j < 4; ++j)
        acc[i][j] = __builtin_amdgcn_mfma_f32_16x16x32_bf16(af[i], bfr[j], acc[i][j], 0, 0, 0);
    __syncthreads();
    cur ^= 1;
  }
#pragma unroll
  for (int i = 0; i < 4; ++i) {
    int row = bm + wr * 64 + i * 16 + kq * 4;
#pragma unroll
    for (int j = 0; j < 4; ++j) {
      int col = bn + wc * 64 + j * 16 + r16;
      bool real = col < Nreal;
      if (!real && !zpad) continue;
      float bv = (bias && real) ? bias[col] : 0.f;
#pragma unroll
      for (int r = 0; r < 4; ++r) {
        float v = acc[i][j][r] + bv;
        if (ACT == 1) v = v > 0.f ? v : 0.f;
        else if (ACT == 2) v = tanhf(v);
        else if (ACT == 3) v = fabsf(tanhf(v));
        if (!real) v = 0.f;
        if (OBF) ((unsigned short*)Cp)[(size_t)(row + r) * ldc + col] = f2b(v);
        else ((float*)Cp)[(size_t)(row + r) * ldc + col] = v;
      }
    }
  }
  if (SC) {
    const int h = bn >> 7;
    float* scr = (float*)&As[0][0];
    float a_s[4], a_d[4];
#pragma unroll
    for (int j = 0; j < 4; ++j) {
      int cwh = wc * 64 + j * 16 + r16;
      a_s[j] = asv[h * 128 + cwh];
      a_d[j] = adv[h * 128 + cwh];
    }
#pragma unroll
    for (int i = 0; i < 4; ++i)
#pragma unroll
      for (int r = 0; r < 4; ++r) {
        float sp = 0.f, dp = 0.f;
#pragma unroll
        for (int j = 0; j < 4; ++j) {
          sp = fmaf(acc[i][j][r], a_s[j], sp);
          dp = fmaf(acc[i][j][r], a_d[j], dp);
        }
#pragma unroll
        for (int m = 1; m < 16; m <<= 1) {
          sp += __shfl_xor(sp, m);
          dp += __shfl_xor(dp, m);
        }
        if (r16 == 0) {
          int rl = wr * 64 + i * 16 + kq * 4 + r;
          scr[rl * 4 + wc * 2 + 0] = sp;
          scr[rl * 4 + wc * 2 + 1] = dp;
        }
      }
    __syncthreads();
    if (tid < 128) {
      float s = scr[tid * 4 + 0] + scr[tid * 4 + 2];
      float d = scr[tid * 4 + 1] + scr[tid * 4 + 3];
      als[(size_t)(bm + tid) * H + h] = s;
      ald[(size_t)(bm + tid) * H + h] = d;
    }
  }
}

// ---------------- 256x128-tile MFMA GEMM (8 waves) with fused GAT scores ---------------
// For g2/g3 (M=32768, Npad=Nreal=1024, C=128). Halves per-output barrier/prologue cost.
// Bit-identical per-output math to the 128-tile path (same fragment K-order).
__global__ __launch_bounds__(512) void gemm_mfma_wide(
    const unsigned short* __restrict__ A, const unsigned short* __restrict__ BT,
    unsigned short* __restrict__ Cp, int K, int lda, int ldb, int ldc, int gx,
    const float* __restrict__ asv, const float* __restrict__ adv,
    float* __restrict__ als, float* __restrict__ ald, int H) {
  __shared__ unsigned short As[2][256 * 32];
  __shared__ unsigned short Bs[2][128 * 32];
  const int nwg = gridDim.x;
  const int chunk = nwg >> 3;
  const int bid = blockIdx.x;
  const int swz = (bid & 7) * chunk + (bid >> 3);
  const int bm = (swz / gx) * 256, bn = (swz % gx) * 128;
  const int tid = threadIdx.x;
  const int wv = tid >> 6, lane = tid & 63;  // wv 0..7
  const int sr = lane >> 2;
  const int sk = ((lane & 3) ^ ((lane >> 3) & 3)) * 8;
  const int r16 = lane & 15, kq = lane >> 4;
  const int slot8 = (kq ^ ((r16 >> 1) & 3)) * 8;
  const int wr = wv >> 1, wc = wv & 1;  // wr 0..3 (64-row quadrant), wc 0..1
  f32x4 acc[4][4];
#pragma unroll
  for (int i = 0; i < 4; ++i)
#pragma unroll
    for (int j = 0; j < 4; ++j) acc[i][j] = (f32x4){0.f, 0.f, 0.f, 0.f};

  const unsigned short* Abase = A + (size_t)bm * lda;
  const unsigned short* Bbase = BT + (size_t)bn * ldb;
  auto stage = [&](int buf, int k0) {
    gload_lds16(Abase + (size_t)(wv * 16 + sr) * lda + k0 + sk, &As[buf][wv * 512]);
    gload_lds16(Abase + (size_t)(128 + wv * 16 + sr) * lda + k0 + sk, &As[buf][4096 + wv * 512]);
    gload_lds16(Bbase + (size_t)(wv * 16 + sr) * ldb + k0 + sk, &Bs[buf][wv * 512]);
  };
  stage(0, 0);
  __syncthreads();
  int cur = 0;
  for (int k0 = 0; k0 < K; k0 += 32) {
    if (k0 + 32 < K) stage(cur ^ 1, k0 + 32);
    bf16x8 af[4], bfr[4];
#pragma unroll
    for (int i = 0; i < 4; ++i)
      af[i] = *(const bf16x8*)&As[cur][(wr * 64 + i * 16 + r16) * 32 + slot8];
#pragma unroll
    for (int j = 0; j < 4; ++j)
      bfr[j] = *(const bf16x8*)&Bs[cur][(wc * 64 + j * 16 + r16) * 32 + slot8];
#pragma unroll
    for (int i = 0; i < 4; ++i)
#pragma unroll
      for (int j = 0; j < 4; ++j)
        acc[i][j] = __builtin_amdgcn_mfma_f32_16x16x32_bf16(af[i], bfr[j], acc[i][j], 0, 0, 0);
    __syncthreads();
    cur ^= 1;
  }
  // C write (full tile, no pad, no bias, no act, bf16 out)
#pragma unroll
  for (int i = 0; i < 4; ++i) {
    int row = bm + wr * 64 + i * 16 + kq * 4;
#pragma unroll
    for (int j = 0; j < 4; ++j) {
      int col = bn + wc * 64 + j * 16 + r16;
#pragma unroll
      for (int r = 0; r < 4; ++r)
        Cp[(size_t)(row + r) * ldc + col] = f2b(acc[i][j][r]);
    }
  }
  // fused GAT scores over 256 rows (head h spans exactly this block's 128 cols)
  {
    const int h = bn >> 7;
    float* scr = (float*)&As[0][0];  // 256 rows x 4 floats = 4KB
    float a_s[4], a_d[4];
#pragma unroll
    for (int j = 0; j < 4; ++j) {
      int cwh = wc * 64 + j * 16 + r16;
      a_s[j] = asv[h * 128 + cwh];
      a_d[j] = adv[h * 128 + cwh];
    }
#pragma unroll
    for (int i = 0; i < 4; ++i)
#pragma unroll
      for (int r = 0; r < 4; ++r) {
        float sp = 0.f, dp = 0.f;
#pragma unroll
        for (int j = 0; j < 4; ++j) {
          sp = fmaf(acc[i][j][r], a_s[j], sp);
          dp = fmaf(acc[i][j][r], a_d[j], dp);
        }
#pragma unroll
        for (int m = 1; m < 16; m <<= 1) {
          sp += __shfl_xor(sp, m);
          dp += __shfl_xor(dp, m);
        }
        if (r16 == 0) {
          int rl = wr * 64 + i * 16 + kq * 4 + r;  // 0..255
          scr[rl * 4 + wc * 2 + 0] = sp;
          scr[rl * 4 + wc * 2 + 1] = dp;
        }
      }
    __syncthreads();
    if (tid < 256) {
      float s = scr[tid * 4 + 0] + scr[tid * 4 + 2];
      float d = scr[tid * 4 + 1] + scr[tid * 4 + 3];
      als[(size_t)(bm + tid) * H + h] = s;
      ald[(size_t)(bm + tid) * H + h] = d;
    }
  }
}

// ---------------- batched runtime-act MFMA GEMM (2-phase dbuf) ----------------
struct GDesc {
  const unsigned short* A; const unsigned short* BT; const float* bias; void* C;
  int Nreal, K, lda, ldb, ldc, gx, zpad, act, obf, Mreal, wg_end;
};
struct GBatch { GDesc d[5]; };
__global__ __launch_bounds__(256) void gemm_batch(GBatch gb) {
  __shared__ unsigned short As[2][128 * 32];
  __shared__ unsigned short Bs[2][128 * 32];
  int bid = blockIdx.x;
  int di = 0;
  while (bid >= gb.d[di].wg_end) ++di;
  const GDesc& g = gb.d[di];
  int rel = bid - (di ? gb.d[di - 1].wg_end : 0);
  const int bm = (rel / g.gx) * 128, bn = (rel % g.gx) * 128;
  const int tid = threadIdx.x;
  const int wv = tid >> 6, lane = tid & 63;
  const int sr = lane >> 2;
  const int sk = ((lane & 3) ^ ((lane >> 3) & 3)) * 8;
  const int r16 = lane & 15, kq = lane >> 4;
  const int slot8 = (kq ^ ((r16 >> 1) & 3)) * 8;
  const int wr = wv >> 1, wc = wv & 1;
  f32x4 acc[4][4];
#pragma unroll
  for (int i = 0; i < 4; ++i)
#pragma unroll
    for (int j = 0; j < 4; ++j) acc[i][j] = (f32x4){0.f, 0.f, 0.f, 0.f};

  const unsigned short* Abase = g.A + (size_t)bm * g.lda;
  const unsigned short* Bbase = g.BT + (size_t)bn * g.ldb;
  auto stage = [&](int buf, int k0) {
    gload_lds16(Abase + (size_t)(wv * 16 + sr) * g.lda + k0 + sk, &As[buf][wv * 512]);
    gload_lds16(Abase + (size_t)(64 + wv * 16 + sr) * g.lda + k0 + sk, &As[buf][2048 + wv * 512]);
    gload_lds16(Bbase + (size_t)(wv * 16 + sr) * g.ldb + k0 + sk, &Bs[buf][wv * 512]);
    gload_lds16(Bbase + (size_t)(64 + wv * 16 + sr) * g.ldb + k0 + sk, &Bs[buf][2048 + wv * 512]);
  };
  stage(0, 0);
  __syncthreads();
  int cur = 0;
  for (int k0 = 0; k0 < g.K; k0 += 32) {
    if (k0 + 32 < g.K) stage(cur ^ 1, k0 + 32);
    bf16x8 af[4], bfr[4];
#pragma unroll
    for (int i = 0; i < 4; ++i)
      af[i] = *(const bf16x8*)&As[cur][(wr * 64 + i * 16 + r16) * 32 + slot8];
#pragma unroll
    for (int j = 0; j < 4; ++j)
      bfr[j] = *(const bf16x8*)&Bs[cur][(wc * 64 + j * 16 + r16) * 32 + slot8];
#pragma unroll
    for (int i = 0; i < 4; ++i)
#pragma unroll
      for (int j = 0; j < 4; ++j)
        acc[i][j] = __builtin_amdgcn_mfma_f32_16x16x32_bf16(af[i], bfr[j], acc[i][j], 0, 0, 0);
    __syncthreads();
    cur ^= 1;
  }
  if (g.act == 4) {
    if (wc == 0) {
#pragma unroll
      for (int i = 0; i < 4; ++i)
#pragma unroll
        for (int r = 0; r < 4; ++r) {
          int row = bm + wr * 64 + i * 16 + kq * 4 + r;
          float vv[4];
#pragma unroll
          for (int j = 0; j < 4; ++j) vv[j] = tanhf(acc[i][j][r] + g.bias[j * 16 + r16]);
          float ss = vv[0] * vv[0] + vv[1] * vv[1] + vv[2] * vv[2] + vv[3] * vv[3];
          ss += __shfl_xor(ss, 1);
          ss += __shfl_xor(ss, 2);
          ss += __shfl_xor(ss, 4);
          ss += __shfl_xor(ss, 8);
          float inv = 1.f / fmaxf(sqrtf(ss), 1e-12f);
          if (row < g.Mreal)
#pragma unroll
            for (int j = 0; j < 4; ++j)
              ((float*)g.C)[(size_t)row * g.ldc + j * 16 + r16] = vv[j] * inv;
        }
    }
    return;
  }
#pragma unroll
  for (int i = 0; i < 4; ++i) {
    int row = bm + wr * 64 + i * 16 + kq * 4;
#pragma unroll
    for (int j = 0; j < 4; ++j) {
      int col = bn + wc * 64 + j * 16 + r16;
      bool real = col < g.Nreal;
      if (!real && !g.zpad) continue;
      float bv = (g.bias && real) ? g.bias[col] : 0.f;
#pragma unroll
      for (int r = 0; r < 4; ++r) {
        float v = acc[i][j][r] + bv;
        if (g.act == 1) v = v > 0.f ? v : 0.f;
        else if (g.act == 2) v = tanhf(v);
        else if (g.act == 3) v = fabsf(tanhf(v));
        if (!real) v = 0.f;
        if (g.obf) ((unsigned short*)g.C)[(size_t)(row + r) * g.ldc + col] = f2b(v);
        else ((float*)g.C)[(size_t)(row + r) * g.ldc + col] = v;
      }
    }
  }
}

// ---------------- split-K MFMA GEMM for z1 (8 slices, single-buffer, f32 partials) ------
__global__ __launch_bounds__(256) void gemm_mfma_sk(
    const unsigned short* __restrict__ A, const unsigned short* __restrict__ BT,
    float* __restrict__ PART, int lda, int ldb, int ldc) {
  __shared__ unsigned short As[128 * 32];
  __shared__ unsigned short Bs[128 * 32];
  const int bid = blockIdx.x;
  const int s = bid & 7;
  const int pos = bid >> 3;
  const int bm = (pos / 13) * 128, bn = (pos % 13) * 128;
  const int base = s * 74 + (s < 6 ? s : 6);
  const int nsteps = 74 + (s < 6 ? 1 : 0);
  const int tid = threadIdx.x;
  const int wv = tid >> 6, lane = tid & 63;
  const int sr = lane >> 2;
  const int sk = ((lane & 3) ^ ((lane >> 3) & 3)) * 8;
  const int r16 = lane & 15, kq = lane >> 4;
  const int slot8 = (kq ^ ((r16 >> 1) & 3)) * 8;
  const int wr = wv >> 1, wc = wv & 1;
  f32x4 acc[4][4];
#pragma unroll
  for (int i = 0; i < 4; ++i)
#pragma unroll
    for (int j = 0; j < 4; ++j) acc[i][j] = (f32x4){0.f, 0.f, 0.f, 0.f};

  const unsigned short* Abase = A + (size_t)bm * lda;
  const unsigned short* Bbase = BT + (size_t)bn * ldb;
  for (int ks = 0; ks < nsteps; ++ks) {
    int k0 = (base + ks) * 32;
    gload_lds16(Abase + (size_t)(wv * 16 + sr) * lda + k0 + sk, &As[wv * 512]);
    gload_lds16(Abase + (size_t)(64 + wv * 16 + sr) * lda + k0 + sk, &As[2048 + wv * 512]);
    gload_lds16(Bbase + (size_t)(wv * 16 + sr) * ldb + k0 + sk, &Bs[wv * 512]);
    gload_lds16(Bbase + (size_t)(64 + wv * 16 + sr) * ldb + k0 + sk, &Bs[2048 + wv * 512]);
    __syncthreads();
    bf16x8 af[4], bfr[4];
#pragma unroll
    for (int i = 0; i < 4; ++i)
      af[i] = *(const bf16x8*)&As[(wr * 64 + i * 16 + r16) * 32 + slot8];
#pragma unroll
    for (int j = 0; j < 4; ++j)
      bfr[j] = *(const bf16x8*)&Bs[(wc * 64 + j * 16 + r16) * 32 + slot8];
#pragma unroll
    for (int i = 0; i < 4; ++i)
#pragma unroll
      for (int j = 0; j < 4; ++j)
        acc[i][j] = __builtin_amdgcn_mfma_f32_16x16x32_bf16(af[i], bfr[j], acc[i][j], 0, 0, 0);
    __syncthreads();
  }
  float* out = PART + (size_t)s * 1024 * ldc;
#pragma unroll
  for (int i = 0; i < 4; ++i) {
    int row = bm + wr * 64 + i * 16 + kq * 4;
#pragma unroll
    for (int j = 0; j < 4; ++j) {
      int col = bn + wc * 64 + j * 16 + r16;
      if (col >= 1600) continue;
#pragma unroll
      for (int r = 0; r < 4; ++r)
        out[(size_t)(row + r) * ldc + col] = acc[i][j][r];
    }
  }
}

// reduce 8 f32 K-slice partials + bias + relu -> ZB bf16 [1024][1664]
__global__ void zred(const float* __restrict__ PART, const float* __restrict__ bias,
                     unsigned short* __restrict__ ZB) {
  int g = blockIdx.x * blockDim.x + threadIdx.x;
  if (g >= 1024 * 1664 / 8) return;
  size_t base = (size_t)g * 8;
  int c0 = (int)(base % 1664);
  ushort8 o;
  if (c0 >= 1600) {
#pragma unroll
    for (int t = 0; t < 8; ++t) o[t] = 0;
  } else {
    float s[8] = {0.f, 0.f, 0.f, 0.f, 0.f, 0.f, 0.f, 0.f};
#pragma unroll
    for (int k = 0; k < 8; ++k) {
      const float* p = &PART[(size_t)k * 1024 * 1664 + base];
      float4 a = *(const float4*)p;
      float4 b = *(const float4*)(p + 4);
      s[0] += a.x; s[1] += a.y; s[2] += a.z; s[3] += a.w;
      s[4] += b.x; s[5] += b.y; s[6] += b.z; s[7] += b.w;
    }
#pragma unroll
    for (int t = 0; t < 8; ++t) {
      float v = s[t] + bias[c0 + t];
      o[t] = f2b(v > 0.f ? v : 0.f);
    }
  }
  *(ushort8*)&ZB[base] = o;
}

// ---------------- fused tail: agg GEMM -> LDS -> col GEMM -> |tanh| -> rownorm -> DN ----
__global__ __launch_bounds__(256) void tail_fused(
    const unsigned short* __restrict__ CAT192, const unsigned short* __restrict__ WTAGG,
    const float* __restrict__ agg_b, const unsigned short* __restrict__ CAT128,
    const unsigned short* __restrict__ WTCOL, const float* __restrict__ col_b,
    float* __restrict__ DN) {
  __shared__ unsigned short S1[128 * 32];
  __shared__ unsigned short S2[128 * 32];
  __shared__ unsigned short ACAT[128 * 128];
  const int bm = blockIdx.x * 128;
  const int tid = threadIdx.x;
  const int wv = tid >> 6, lane = tid & 63;
  const int sr = lane >> 2;
  const int sk = ((lane & 3) ^ ((lane >> 3) & 3)) * 8;
  const int r16 = lane & 15, kq = lane >> 4;
  const int slot8 = (kq ^ ((r16 >> 1) & 3)) * 8;
  const int wr = wv >> 1, wc = wv & 1;
  f32x4 acc[4][4];
#pragma unroll
  for (int i = 0; i < 4; ++i)
#pragma unroll
    for (int j = 0; j < 4; ++j) acc[i][j] = (f32x4){0.f, 0.f, 0.f, 0.f};

  const unsigned short* Abase = CAT192 + (size_t)bm * 192;
  for (int k0 = 0; k0 < 192; k0 += 32) {
    gload_lds16(Abase + (size_t)(wv * 16 + sr) * 192 + k0 + sk, &S1[wv * 512]);
    gload_lds16(Abase + (size_t)(64 + wv * 16 + sr) * 192 + k0 + sk, &S1[2048 + wv * 512]);
    gload_lds16(WTAGG + (size_t)(wv * 16 + sr) * 192 + k0 + sk, &S2[wv * 512]);
    gload_lds16(WTAGG + (size_t)(64 + wv * 16 + sr) * 192 + k0 + sk, &S2[2048 + wv * 512]);
    __syncthreads();
    bf16x8 af[4], bfr[4];
#pragma unroll
    for (int i = 0; i < 4; ++i)
      af[i] = *(const bf16x8*)&S1[(wr * 64 + i * 16 + r16) * 32 + slot8];
#pragma unroll
    for (int j = 0; j < 4; ++j)
      bfr[j] = *(const bf16x8*)&S2[(wc * 64 + j * 16 + r16) * 32 + slot8];
#pragma unroll
    for (int i = 0; i < 4; ++i)
#pragma unroll
      for (int j = 0; j < 4; ++j)
        acc[i][j] = __builtin_amdgcn_mfma_f32_16x16x32_bf16(af[i], bfr[j], acc[i][j], 0, 0, 0);
    __syncthreads();
  }
  if (wc == 0) {
#pragma unroll
    for (int i = 0; i < 4; ++i)
#pragma unroll
      for (int j = 0; j < 4; ++j) {
        int col = j * 16 + r16;
#pragma unroll
        for (int r = 0; r < 4; ++r) {
          int rl = wr * 64 + i * 16 + kq * 4 + r;
          ACAT[rl * 128 + col] = f2b(acc[i][j][r] + agg_b[col]);
        }
      }
  }
  for (int idx = tid; idx < 128 * 8; idx += 256) {
    int row = idx >> 3, c8 = (idx & 7) * 8;
    *(ushort8*)&ACAT[row * 128 + 64 + c8] =
        *(const ushort8*)&CAT128[(size_t)(bm + row) * 128 + 64 + c8];
  }
#pragma unroll
  for (int i = 0; i < 4; ++i)
#pragma unroll
    for (int j = 0; j < 4; ++j) acc[i][j] = (f32x4){0.f, 0.f, 0.f, 0.f};
  __syncthreads();

  for (int k0 = 0; k0 < 128; k0 += 32) {
    gload_lds16(WTCOL + (size_t)(wv * 16 + sr) * 128 + k0 + sk, &S1[wv * 512]);
    gload_lds16(WTCOL + (size_t)(64 + wv * 16 + sr) * 128 + k0 + sk, &S1[2048 + wv * 512]);
    __syncthreads();
    bf16x8 af[4], bfr[4];
#pragma unroll
    for (int i = 0; i < 4; ++i)
      af[i] = *(const bf16x8*)&ACAT[(wr * 64 + i * 16 + r16) * 128 + k0 + kq * 8];
#pragma unroll
    for (int j = 0; j < 4; ++j)
      bfr[j] = *(const bf16x8*)&S1[(wc * 64 + j * 16 + r16) * 32 + slot8];
#pragma unroll
    for (int i = 0; i < 4; ++i)
#pragma unroll
      for (int j = 0; j < 4; ++j)
        acc[i][j] = __builtin_amdgcn_mfma_f32_16x16x32_bf16(af[i], bfr[j], acc[i][j], 0, 0, 0);
    __syncthreads();
  }
  if (wc == 0) {
#pragma unroll
    for (int i = 0; i < 4; ++i)
#pragma unroll
      for (int r = 0; r < 4; ++r) {
        int row = bm + wr * 64 + i * 16 + kq * 4 + r;
        float vv[4];
#pragma unroll
        for (int j = 0; j < 4; ++j) vv[j] = fabsf(tanhf(acc[i][j][r] + col_b[j * 16 + r16]));
        float ss = vv[0] * vv[0] + vv[1] * vv[1] + vv[2] * vv[2] + vv[3] * vv[3];
        ss += __shfl_xor(ss, 1);
        ss += __shfl_xor(ss, 2);
        ss += __shfl_xor(ss, 4);
        ss += __shfl_xor(ss, 8);
        float inv = 1.f / fmaxf(sqrtf(ss), 1e-12f);
#pragma unroll
        for (int j = 0; j < 4; ++j)
          DN[(size_t)row * 64 + j * 16 + r16] = vv[j] * inv;
      }
  }
}

// ---------------- GAT pieces ----------------
__global__ void gat_scores_bf(const unsigned short* __restrict__ hlin,
                              const float* __restrict__ a_s, const float* __restrict__ a_d,
                              float* __restrict__ als, float* __restrict__ ald,
                              int H, int C, int tot) {
  int idx = blockIdx.x * blockDim.x + threadIdx.x;
  if (idx >= tot) return;
  int n = idx / H, h = idx - n * H;
  const unsigned short* base = hlin + (size_t)n * H * C + (size_t)h * C;
  const float* as = a_s + h * C;
  const float* ad = a_d + h * C;
  float ss = 0.f, sd = 0.f;
  for (int c = 0; c < C; c += 8) {
    ushort8 v = *(const ushort8*)(base + c);
#pragma unroll
    for (int t = 0; t < 8; ++t) {
      float f = b2f(v[t]);
      ss = fmaf(f, as[c + t], ss);
      sd = fmaf(f, ad[c + t], sd);
    }
  }
  als[idx] = ss;
  ald[idx] = sd;
}

// aggregate with INLINE attention; EPT=16 (chunks never straddle heads: C % 16 == 0).
template <int F, int C, int EPT>
__global__ __launch_bounds__(256) void gat_agg_v5(
    const int* __restrict__ rowptr, const int* __restrict__ srcl,
    const float* __restrict__ als, const float* __restrict__ ald,
    const unsigned short* __restrict__ hlin,
    const float* __restrict__ bias, unsigned short* __restrict__ out) {
  constexpr int H = F / C;
  constexpr int CPN = F / EPT;
  int gidx = blockIdx.x * 256 + threadIdx.x;
  if (gidx >= NN * CPN) return;
  int node = gidx / CPN;
  int c0 = (gidx - node * CPN) * EPT;
  int h = c0 / C;
  float aldv = ald[node * H + h];
  float s = 0.f;
  float acc[EPT];
#pragma unroll
  for (int t = 0; t < EPT; ++t) acc[t] = 0.f;
  int start = rowptr[node], end = rowptr[node + 1];
  for (int k = start; k < end; ++k) {
    int src = srcl[k];
    float e = als[src * H + h] + aldv;
    e = (e >= 0.f) ? e : 0.2f * e;
    float p = __expf(e);
    s += p;
    if (EPT == 8) {
      ushort8 hv = *(const ushort8*)(hlin + (size_t)src * F + c0);
#pragma unroll
      for (int t = 0; t < 8; ++t) acc[t] = fmaf(p, b2f(hv[t]), acc[t]);
    } else {
      ushort16 hv = *(const ushort16*)(hlin + (size_t)src * F + c0);
#pragma unroll
      for (int t = 0; t < 16; ++t) acc[t] = fmaf(p, b2f(hv[t]), acc[t]);
    }
  }
  float inv_s = 1.f / s;
#pragma unroll
  for (int t8 = 0; t8 < EPT / 8; ++t8) {
    ushort8 o;
#pragma unroll
    for (int t = 0; t < 8; ++t) {
      float val = acc[t8 * 8 + t] * inv_s + bias[c0 + t8 * 8 + t];
      o[t] = f2b(val > 0.f ? val : 0.f);
    }
    *(ushort8*)(out + (size_t)node * F + c0 + t8 * 8) = o;
  }
}

__global__ void pool_max(const unsigned short* __restrict__ xb,
                         unsigned short* __restrict__ xgb) {
  int g = blockIdx.x, c = threadIdx.x;  // 128 threads
  const unsigned short* base = xb + (size_t)g * 32 * 128 + c;
  float m = -FLT_MAX;
#pragma unroll 8
  for (int n = 0; n < 32; ++n) m = fmaxf(m, b2f(base[n * 128]));
  xgb[g * 128 + c] = f2b(m);
}

__global__ __launch_bounds__(256) void freq_k(const float* __restrict__ dn,
                                              const float* __restrict__ sn,
                                              float* __restrict__ C, int M, int N) {
  __shared__ float As[16][64];
  __shared__ float Bs[16][65];
  int tid = threadIdx.x;
  int tx = tid & 15, ty = tid >> 4;
  int bi = blockIdx.y * 16, bj = blockIdx.x * 16;
#pragma unroll
  for (int t = 0; t < 4; ++t) {
    int idx = tid * 4 + t;
    int r = idx >> 6, c = idx & 63;
    As[r][c] = (bi + r < M) ? dn[(bi + r) * 64 + c] : 0.f;
    Bs[r][c] = (bj + r < N) ? sn[(bj + r) * 64 + c] : 0.f;
  }
  __syncthreads();
  float acc = 0.f;
#pragma unroll
  for (int k = 0; k < 64; ++k) acc = fmaf(As[ty][k], Bs[tx][k], acc);
  if (bi + ty < M && bj + tx < N) C[(size_t)(bi + ty) * N + (bj + tx)] = 5.f * acc;
}

// ---------------- launch ----------------
extern "C" void kernel_launch(void* const* d_in, const int* in_sizes, int n_in,
                              void* d_out, int out_size, void* d_ws, size_t ws_size,
                              hipStream_t stream) {
  const float* x = (const float*)d_in[0];
  const int* ei = (const int*)d_in[1];
  const float* w = (const float*)d_in[3];
  const float* z = (const float*)d_in[4];
  const float* v = (const float*)d_in[5];
  const float* side = (const float*)d_in[6];
  const float* gW[4] = {(const float*)d_in[7], (const float*)d_in[11],
                        (const float*)d_in[15], (const float*)d_in[19]};
  const float* gas[4] = {(const float*)d_in[8], (const float*)d_in[12],
                         (const float*)d_in[16], (const float*)d_in[20]};
  const float* gad[4] = {(const float*)d_in[9], (const float*)d_in[13],
                         (const float*)d_in[17], (const float*)d_in[21]};
  const float* gb[4] = {(const float*)d_in[10], (const float*)d_in[14],
                        (const float*)d_in[18], (const float*)d_in[22]};
  const float* x5_W = (const float*)d_in[23]; const float* x5_b = (const float*)d_in[24];
  const float* x6_W = (const float*)d_in[25]; const float* x6_b = (const float*)d_in[26];
  const float* w1_W = (const float*)d_in[27]; const float* w1_b = (const float*)d_in[28];
  const float* w2_W = (const float*)d_in[29]; const float* w2_b = (const float*)d_in[30];
  const float* z1_W = (const float*)d_in[31]; const float* z1_b = (const float*)d_in[32];
  const float* z2_W = (const float*)d_in[33]; const float* z2_b = (const float*)d_in[34];
  const float* v1_W = (const float*)d_in[35]; const float* v1_b = (const float*)d_in[36];
  const float* v2_W = (const float*)d_in[37]; const float* v2_b = (const float*)d_in[38];
  const float* agg_W = (const float*)d_in[39]; const float* agg_b = (const float*)d_in[40];
  const float* col_W = (const float*)d_in[41]; const float* col_b = (const float*)d_in[42];
  const float* s1_W = (const float*)d_in[43]; const float* s1_b = (const float*)d_in[44];
  const float* s2_W = (const float*)d_in[45]; const float* s2_b = (const float*)d_in[46];

  char* wsb = (char*)d_ws;
  size_t off = 0;
  auto alloc = [&](size_t bytes) {
    void* p = wsb + off;
    off = (off + bytes + 255) & ~(size_t)255;
    return p;
  };
  unsigned short* HLIN = (unsigned short*)alloc((size_t)NN * 1024 * 2);
  unsigned short* XB = (unsigned short*)alloc((size_t)NN * 1024 * 2);
  unsigned short* WTZ = (unsigned short*)alloc((size_t)1664 * 19136 * 2);
  unsigned short* ZA = (unsigned short*)alloc((size_t)1024 * 19136 * 2);
  unsigned short* WT1 = (unsigned short*)alloc((size_t)768 * 128 * 2);
  unsigned short* WT2 = (unsigned short*)alloc((size_t)1024 * 768 * 2);
  unsigned short* WT3 = (unsigned short*)alloc((size_t)1024 * 1024 * 2);
  unsigned short* WT4 = (unsigned short*)alloc((size_t)128 * 1024 * 2);
  unsigned short* WTW1 = (unsigned short*)alloc((size_t)768 * 768 * 2);
  unsigned short* WTW2 = (unsigned short*)alloc((size_t)128 * 768 * 2);
  unsigned short* WTZ2 = (unsigned short*)alloc((size_t)128 * 1664 * 2);
  unsigned short* WTV1 = (unsigned short*)alloc((size_t)256 * 1024 * 2);
  unsigned short* WTV2 = (unsigned short*)alloc((size_t)128 * 256 * 2);
  unsigned short* WTX5 = (unsigned short*)alloc((size_t)128 * 128 * 2);
  unsigned short* WTX6 = (unsigned short*)alloc((size_t)128 * 64 * 2);
  unsigned short* WTAGG = (unsigned short*)alloc((size_t)128 * 192 * 2);
  unsigned short* WTCOL = (unsigned short*)alloc((size_t)128 * 128 * 2);
  unsigned short* WTS1 = (unsigned short*)alloc((size_t)128 * 1056 * 2);
  unsigned short* WTS2 = (unsigned short*)alloc((size_t)128 * 64 * 2);
  unsigned short* WB = (unsigned short*)alloc((size_t)1024 * 768 * 2);
  unsigned short* VB = (unsigned short*)alloc((size_t)1024 * 1024 * 2);
  unsigned short* SIDEB = (unsigned short*)alloc((size_t)1024 * 1056 * 2);
  unsigned short* XGB = (unsigned short*)alloc((size_t)1024 * 128 * 2);
  unsigned short* ZB = (unsigned short*)alloc((size_t)1024 * 1664 * 2);
  unsigned short* X5O = (unsigned short*)alloc((size_t)1024 * 128 * 2);
  unsigned short* WMID = (unsigned short*)alloc((size_t)1024 * 768 * 2);
  unsigned short* VMID = (unsigned short*)alloc((size_t)1024 * 256 * 2);
  unsigned short* SEMID = (unsigned short*)alloc((size_t)1024 * 128 * 2);
  unsigned short* CAT192 = (unsigned short*)alloc((size_t)1024 * 192 * 2);
  unsigned short* CAT128 = (unsigned short*)alloc((size_t)1024 * 128 * 2);
  float* ALS = (float*)alloc((size_t)NN * 8 * 4);
  float* ALD = (float*)alloc((size_t)NN * 8 * 4);
  int* DEG = (int*)alloc((size_t)NN * 4);
  int* ROWPTR = (int*)alloc((size_t)(NN + 1) * 4);
  int* CURSOR = (int*)alloc((size_t)NN * 4);
  int* SRCL = (int*)alloc((size_t)ETOT * 4);
  float* PART = (float*)HLIN;  // 8x1024x1664 f32 = 54.5MB over dead HLIN

  // CSR build
  hipLaunchKernelGGL(fill_i32, dim3((NN + 255) / 256), dim3(256), 0, stream, DEG, 0, NN);
  hipLaunchKernelGGL(count_deg, dim3((ETOT + 255) / 256), dim3(256), 0, stream, ei, DEG);
  hipLaunchKernelGGL(scan_deg, dim3(1), dim3(1024), 0, stream, DEG, ROWPTR, CURSOR);
  hipLaunchKernelGGL(fill_csr, dim3((ETOT + 255) / 256), dim3(256), 0, stream, ei, CURSOR, SRCL);

  // batched weight transposes
  {
    TBatch tb;
    int acc_wg = 0, i = 0;
    auto add = [&](const float* W, unsigned short* WT, int K, int N, int Kp, int Npad) {
      int gx = Npad / 32, gy = Kp / 32;
      acc_wg += gx * gy;
      tb.d[i++] = {W, WT, K, N, Kp, Npad, gx, acc_wg};
    };
    add(z1_W, WTZ, 19127, 1600, 19136, 1664);
    add(gW[0], WT1, 109, 768, 128, 768);
    add(gW[1], WT2, 768, 1024, 768, 1024);
    add(gW[2], WT3, 1024, 1024, 1024, 1024);
    add(gW[3], WT4, 1024, 128, 1024, 128);
    add(w1_W, WTW1, 750, 750, 768, 768);
    add(w2_W, WTW2, 750, 64, 768, 128);
    add(z2_W, WTZ2, 1600, 64, 1664, 128);
    add(v1_W, WTV1, 1024, 256, 1024, 256);
    add(v2_W, WTV2, 256, 64, 256, 128);
    add(x5_W, WTX5, 128, 64, 128, 128);
    add(x6_W, WTX6, 64, 64, 64, 128);
    add(agg_W, WTAGG, 192, 64, 192, 128);
    add(col_W, WTCOL, 128, 64, 128, 128);
    add(s1_W, WTS1, 1050, 64, 1056, 128);
    add(s2_W, WTS2, 64, 64, 64, 128);
    hipLaunchKernelGGL(transpose_batch, dim3(acc_wg), dim3(256), 0, stream, tb);
  }

  // batched input conversions
  {
    CBatch cb;
    int acc_wg = 0, i = 0;
    auto add = [&](const float* in, unsigned short* out, int rowsOut, int Rreal, int C, int Cp) {
      acc_wg += (int)(((size_t)rowsOut * Cp + 255) / 256);
      cb.d[i++] = {in, out, rowsOut, Rreal, C, Cp, acc_wg};
    };
    add(z, ZA, NB, NB, 19127, 19136);
    add(x, XB, NN, NN, 109, 128);
    add(w, WB, 1024, 1024, 750, 768);
    add(v, VB, 1024, 1024, 1024, 1024);
    add(side, SIDEB, 1024, 994, 1050, 1056);
    hipLaunchKernelGGL(conv_batch, dim3(acc_wg), dim3(256), 0, stream, cb);
  }

  // GAT layers
  const int Hs[4] = {8, 8, 8, 1};
  const int Kp[4] = {128, 768, 1024, 1024};
  const unsigned short* WTs[4] = {WT1, WT2, WT3, WT4};
  const int Fs[4] = {768, 1024, 1024, 128};
  for (int l = 0; l < 4; ++l) {
    int H = Hs[l], F = Fs[l], C = F / H;
    int gx = F / 128;
    if (l == 1 || l == 2) {
      // 256x128 tile wide kernel with fused scores (M=32768 -> 128 row-blocks x gx)
      int nwg = gx * (NN / 256);
      hipLaunchKernelGGL(gemm_mfma_wide, dim3(nwg), dim3(512), 0, stream,
                         XB, WTs[l], HLIN, Kp[l], Kp[l], Kp[l], F, gx,
                         gas[l], gad[l], ALS, ALD, H);
    } else if (C == 128) {
      int nwg = gx * (NN / 128);
      hipLaunchKernelGGL((gemm_mfma<0, 1, 1>), dim3(nwg), dim3(256), 0, stream,
                         XB, WTs[l], (const float*)nullptr, (void*)HLIN, F, Kp[l],
                         Kp[l], Kp[l], F, gx, 0, gas[l], gad[l], ALS, ALD, H);
    } else {
      int nwg = gx * (NN / 128);
      hipLaunchKernelGGL((gemm_mfma<0, 1, 0>), dim3(nwg), dim3(256), 0, stream,
                         XB, WTs[l], (const float*)nullptr, (void*)HLIN, F, Kp[l],
                         Kp[l], Kp[l], F, gx, 0, (const float*)nullptr,
                         (const float*)nullptr, (float*)nullptr, (float*)nullptr, H);
      int totNH = NN * H;
      hipLaunchKernelGGL(gat_scores_bf, dim3((totNH + 255) / 256), dim3(256), 0, stream,
                         HLIN, gas[l], gad[l], ALS, ALD, H, C, totNH);
    }
    if (l == 0)
      hipLaunchKernelGGL((gat_agg_v5<768, 96, 16>), dim3(NN * 48 / 256), dim3(256), 0, stream,
                         ROWPTR, SRCL, ALS, ALD, HLIN, gb[l], XB);
    else if (l == 3)
      hipLaunchKernelGGL((gat_agg_v5<128, 128, 16>), dim3(NN * 8 / 256), dim3(256), 0, stream,
                         ROWPTR, SRCL, ALS, ALD, HLIN, gb[l], XB);
    else
      hipLaunchKernelGGL((gat_agg_v5<1024, 128, 16>), dim3(NN * 64 / 256), dim3(256), 0, stream,
                         ROWPTR, SRCL, ALS, ALD, HLIN, gb[l], XB);
  }

  // global max pool -> XGB bf16
  hipLaunchKernelGGL(pool_max, dim3(NB), dim3(128), 0, stream, XB, XGB);

  // B1: independent tail GEMMs {w1, v1, s1, x5}
  {
    GBatch b;
    int acc_wg = 0, i = 0;
    auto add = [&](const unsigned short* A, const unsigned short* BT, const float* bias,
                   void* C, int Npad, int Nreal, int K, int lda, int ldb, int ldc,
                   int zpad, int act, int obf, int Mreal) {
      int gx = Npad / 128;
      acc_wg += gx * 8;
      b.d[i++] = {A, BT, bias, C, Nreal, K, lda, ldb, ldc, gx, zpad, act, obf, Mreal, acc_wg};
    };
    add(WB, WTW1, w1_b, WMID, 768, 750, 768, 768, 768, 768, 1, 1, 1, 1024);
    add(VB, WTV1, v1_b, VMID, 256, 256, 1024, 1024, 1024, 256, 0, 1, 1, 1024);
    add(SIDEB, WTS1, s1_b, SEMID, 128, 64, 1056, 1056, 1056, 128, 1, 1, 1, 1024);
    add(XGB, WTX5, x5_b, X5O, 128, 64, 128, 128, 128, 128, 1, 1, 1, 1024);
    while (i < 5) { b.d[i] = b.d[i - 1]; b.d[i].wg_end = acc_wg; ++i; }
    hipLaunchKernelGGL(gemm_batch, dim3(acc_wg), dim3(256), 0, stream, b);
  }

  // z1 split-K (8 slices, f32 partials) + reduce -> ZB bf16
  hipLaunchKernelGGL(gemm_mfma_sk, dim3(832), dim3(256), 0, stream, ZA, WTZ, PART, 19136, 19136, 1664);
  hipLaunchKernelGGL(zred, dim3((1024 * 1664 / 8 + 255) / 256), dim3(256), 0, stream, PART, z1_b, ZB);

  // output pointers
  float* outp = (float*)d_out;
  float* DN = outp + (size_t)NB * NSIDE;
  float* SN = DN + (size_t)NB * 64;

  // B2: {x6, w2, z2, v2, s2(tanh+rownorm -> SN)}
  {
    GBatch b;
    int acc_wg = 0, i = 0;
    auto add = [&](const unsigned short* A, const unsigned short* BT, const float* bias,
                   void* C, int Npad, int Nreal, int K, int lda, int ldb, int ldc,
                   int zpad, int act, int obf, int Mreal) {
      int gx = Npad / 128;
      acc_wg += gx * 8;
      b.d[i++] = {A, BT, bias, C, Nreal, K, lda, ldb, ldc, gx, zpad, act, obf, Mreal, acc_wg};
    };
    add(X5O, WTX6, x6_b, CAT192 + 0, 128, 64, 64, 128, 64, 192, 0, 1, 1, 1024);
    add(WMID, WTW2, w2_b, CAT192 + 64, 128, 64, 768, 768, 768, 192, 0, 1, 1, 1024);
    add(ZB, WTZ2, z2_b, CAT192 + 128, 128, 64, 1664, 1664, 1664, 192, 0, 1, 1, 1024);
    add(VMID, WTV2, v2_b, CAT128 + 64, 128, 64, 256, 256, 256, 128, 0, 1, 1, 1024);
    add(SEMID, WTS2, s2_b, SN, 128, 64, 64, 128, 64, 64, 0, 4, 0, 994);
    hipLaunchKernelGGL(gemm_batch, dim3(acc_wg), dim3(256), 0, stream, b);
  }

  // fused tail: agg GEMM -> col GEMM -> |tanh| -> rownorm -> DN
  hipLaunchKernelGGL(tail_fused, dim3(8), dim3(256), 0, stream,
                     CAT192, WTAGG, agg_b, CAT128, WTCOL, col_b, DN);

  // similarity
  hipLaunchKernelGGL(freq_k, dim3((NSIDE + 15) / 16, (NB + 15) / 16), dim3(256), 0, stream,
                     DN, SN, outp, NB, NSIDE);
}

// Round 17
// 860.257 us; speedup vs baseline: 1.1377x; 1.0013x over previous
//
#include <hip/hip_runtime.h>
#include <math.h>
#include <float.h>

#define E0 131072
#define NN 32768
#define NB 1024
#define NSIDE 994
#define ETOT (E0 + NN)

typedef short bf16x8 __attribute__((ext_vector_type(8)));
typedef unsigned short ushort8 __attribute__((ext_vector_type(8)));
typedef unsigned short ushort16 __attribute__((ext_vector_type(16)));
typedef float f32x4 __attribute__((ext_vector_type(4)));

__device__ inline float b2f(unsigned short u) { return __uint_as_float(((unsigned)u) << 16); }
__device__ inline unsigned short f2b(float f) {
  unsigned u = __float_as_uint(f);
  return (unsigned short)((u + 0x7fffu + ((u >> 16) & 1u)) >> 16);
}

__device__ inline void gload_lds16(const void* g, void* l) {
  __builtin_amdgcn_global_load_lds(
      (const __attribute__((address_space(1))) unsigned int*)g,
      (__attribute__((address_space(3))) unsigned int*)l, 16, 0, 0);
}

__global__ void fill_i32(int* p, int v, int n) {
  int i = blockIdx.x * blockDim.x + threadIdx.x;
  if (i < n) p[i] = v;
}

// ---------------- batched fp32 -> bf16 conversion with padding ----------------
struct CDesc { const float* in; unsigned short* out; int rowsOut, Rreal, C, Cp, wg_end; };
struct CBatch { CDesc d[5]; };
__global__ void conv_batch(CBatch cb) {
  int bid = blockIdx.x;
  int di = 0;
  while (bid >= cb.d[di].wg_end) ++di;
  const CDesc& g = cb.d[di];
  int rel = bid - (di ? cb.d[di - 1].wg_end : 0);
  size_t idx = (size_t)rel * 256 + threadIdx.x;
  size_t tot = (size_t)g.rowsOut * g.Cp;
  if (idx >= tot) return;
  int r = (int)(idx / g.Cp), c = (int)(idx % g.Cp);
  g.out[idx] = (r < g.Rreal && c < g.C) ? f2b(g.in[(size_t)r * g.C + c]) : (unsigned short)0;
}

// ---------------- batched transpose: W [K][N] f32 -> WT [Npad][Kp] bf16 ----------------
struct TDesc { const float* W; unsigned short* WT; int K, N, Kp, Npad, gx, wg_end; };
struct TBatch { TDesc d[16]; };
__global__ __launch_bounds__(256) void transpose_batch(TBatch tb) {
  __shared__ float t[32][33];
  int bid = blockIdx.x;
  int di = 0;
  while (bid >= tb.d[di].wg_end) ++di;
  const TDesc& g = tb.d[di];
  int rel = bid - (di ? tb.d[di - 1].wg_end : 0);
  int n0 = (rel % g.gx) * 32, k0 = (rel / g.gx) * 32;
  int tx = threadIdx.x & 31, ty = threadIdx.x >> 5;
  for (int r = ty; r < 32; r += 8) {
    int k = k0 + r, n = n0 + tx;
    t[r][tx] = (k < g.K && n < g.N) ? g.W[(size_t)k * g.N + n] : 0.f;
  }
  __syncthreads();
  for (int r = ty; r < 32; r += 8) {
    int n = n0 + r, k = k0 + tx;
    if (n < g.Npad && k < g.Kp)
      g.WT[(size_t)n * g.Kp + k] = (n < g.N) ? f2b(t[tx][r]) : (unsigned short)0;
  }
}

// ---------------- CSR build over dst ----------------
__global__ void count_deg(const int* __restrict__ ei, int* deg) {
  int e = blockIdx.x * blockDim.x + threadIdx.x;
  if (e >= ETOT) return;
  int dst = (e < E0) ? ei[E0 + e] : (e - E0);
  atomicAdd(&deg[dst], 1);
}

__global__ void scan_deg(const int* __restrict__ deg, int* rowptr, int* cursor) {
  __shared__ int part[1024];
  int tid = threadIdx.x;
  const int chunk = NN / 1024;  // 32
  int base = tid * chunk;
  int local[chunk];
  int sum = 0;
#pragma unroll
  for (int i = 0; i < chunk; ++i) { local[i] = sum; sum += deg[base + i]; }
  part[tid] = sum;
  __syncthreads();
  for (int off = 1; off < 1024; off <<= 1) {
    int t = (tid >= off) ? part[tid - off] : 0;
    __syncthreads();
    part[tid] += t;
    __syncthreads();
  }
  int offset = part[tid] - sum;
#pragma unroll
  for (int i = 0; i < chunk; ++i) {
    int v = offset + local[i];
    rowptr[base + i] = v;
    cursor[base + i] = v;
  }
  if (tid == 1023) rowptr[NN] = offset + sum;
}

__global__ void fill_csr(const int* __restrict__ ei, int* cursor, int* __restrict__ srcl) {
  int e = blockIdx.x * blockDim.x + threadIdx.x;
  if (e >= ETOT) return;
  int src, dst;
  if (e < E0) { src = ei[e]; dst = ei[E0 + e]; } else { src = dst = e - E0; }
  int p = atomicAdd(&cursor[dst], 1);
  srcl[p] = src;
}

// ---------------- bf16 MFMA GEMM, 128-tile, 2-phase dbuf; optional fused scores ---------
template <int ACT, int OBF, int SC>
__global__ __launch_bounds__(256) void gemm_mfma(
    const unsigned short* __restrict__ A, const unsigned short* __restrict__ BT,
    const float* __restrict__ bias, void* __restrict__ Cp,
    int Nreal, int K, int lda, int ldb, int ldc, int gx, int zpad,
    const float* __restrict__ asv, const float* __restrict__ adv,
    float* __restrict__ als, float* __restrict__ ald, int H) {
  __shared__ unsigned short As[2][128 * 32];
  __shared__ unsigned short Bs[2][128 * 32];
  const int nwg = gridDim.x;
  const int chunk = nwg >> 3;
  const int bid = blockIdx.x;
  const int swz = (bid & 7) * chunk + (bid >> 3);
  const int bm = (swz / gx) * 128, bn = (swz % gx) * 128;
  const int tid = threadIdx.x;
  const int wv = tid >> 6, lane = tid & 63;
  const int sr = lane >> 2;
  const int sk = ((lane & 3) ^ ((lane >> 3) & 3)) * 8;
  const int r16 = lane & 15, kq = lane >> 4;
  const int slot8 = (kq ^ ((r16 >> 1) & 3)) * 8;
  const int wr = wv >> 1, wc = wv & 1;
  f32x4 acc[4][4];
#pragma unroll
  for (int i = 0; i < 4; ++i)
#pragma unroll
    for (int j = 0; j < 4; ++j) acc[i][j] = (f32x4){0.f, 0.f, 0.f, 0.f};

  const unsigned short* Abase = A + (size_t)bm * lda;
  const unsigned short* Bbase = BT + (size_t)bn * ldb;
  auto stage = [&](int buf, int k0) {
    gload_lds16(Abase + (size_t)(wv * 16 + sr) * lda + k0 + sk, &As[buf][wv * 512]);
    gload_lds16(Abase + (size_t)(64 + wv * 16 + sr) * lda + k0 + sk, &As[buf][2048 + wv * 512]);
    gload_lds16(Bbase + (size_t)(wv * 16 + sr) * ldb + k0 + sk, &Bs[buf][wv * 512]);
    gload_lds16(Bbase + (size_t)(64 + wv * 16 + sr) * ldb + k0 + sk, &Bs[buf][2048 + wv * 512]);
  };
  stage(0, 0);
  __syncthreads();
  int cur = 0;
  for (int k0 = 0; k0 < K; k0 += 32) {
    if (k0 + 32 < K) stage(cur ^ 1, k0 + 32);
    bf16x8 af[4], bfr[4];
#pragma unroll
    for (int i = 0; i < 4; ++i)
      af[i] = *(const bf16x8*)&As[cur][(wr * 64 + i * 16 + r16) * 32 + slot8];
#pragma unroll
    for (int j = 0; j < 4; ++j)
      bfr[j] = *(const bf16x8*)&Bs[cur][(wc * 64 + j * 16 + r16) * 32 + slot8];
#pragma unroll
    for (int i = 0; i < 4; ++i)
#pragma unroll
      for (int j = 0; j < 4; ++j)
        acc[i][j] = __builtin_amdgcn_mfma_f32_16x16x32_bf16(af[i], bfr[j], acc[i][j], 0, 0, 0);
    __syncthreads();
    cur ^= 1;
  }
#pragma unroll
  for (int i = 0; i < 4; ++i) {
    int row = bm + wr * 64 + i * 16 + kq * 4;
#pragma unroll
    for (int j = 0; j < 4; ++j) {
      int col = bn + wc * 64 + j * 16 + r16;
      bool real = col < Nreal;
      if (!real && !zpad) continue;
      float bv = (bias && real) ? bias[col] : 0.f;
#pragma unroll
      for (int r = 0; r < 4; ++r) {
        float v = acc[i][j][r] + bv;
        if (ACT == 1) v = v > 0.f ? v : 0.f;
        else if (ACT == 2) v = tanhf(v);
        else if (ACT == 3) v = fabsf(tanhf(v));
        if (!real) v = 0.f;
        if (OBF) ((unsigned short*)Cp)[(size_t)(row + r) * ldc + col] = f2b(v);
        else ((float*)Cp)[(size_t)(row + r) * ldc + col] = v;
      }
    }
  }
  if (SC) {
    const int h = bn >> 7;
    float* scr = (float*)&As[0][0];
    float a_s[4], a_d[4];
#pragma unroll
    for (int j = 0; j < 4; ++j) {
      int cwh = wc * 64 + j * 16 + r16;
      a_s[j] = asv[h * 128 + cwh];
      a_d[j] = adv[h * 128 + cwh];
    }
#pragma unroll
    for (int i = 0; i < 4; ++i)
#pragma unroll
      for (int r = 0; r < 4; ++r) {
        float sp = 0.f, dp = 0.f;
#pragma unroll
        for (int j = 0; j < 4; ++j) {
          sp = fmaf(acc[i][j][r], a_s[j], sp);
          dp = fmaf(acc[i][j][r], a_d[j], dp);
        }
#pragma unroll
        for (int m = 1; m < 16; m <<= 1) {
          sp += __shfl_xor(sp, m);
          dp += __shfl_xor(dp, m);
        }
        if (r16 == 0) {
          int rl = wr * 64 + i * 16 + kq * 4 + r;
          scr[rl * 4 + wc * 2 + 0] = sp;
          scr[rl * 4 + wc * 2 + 1] = dp;
        }
      }
    __syncthreads();
    if (tid < 128) {
      float s = scr[tid * 4 + 0] + scr[tid * 4 + 2];
      float d = scr[tid * 4 + 1] + scr[tid * 4 + 3];
      als[(size_t)(bm + tid) * H + h] = s;
      ald[(size_t)(bm + tid) * H + h] = d;
    }
  }
}

// ---------------- 256x128-tile MFMA GEMM (8 waves); SC=1 adds fused GAT scores ---------
// Halves per-output barrier/prologue cost vs the 128-tile path; bit-identical math.
template <int SC>
__global__ __launch_bounds__(512) void gemm_mfma_wide(
    const unsigned short* __restrict__ A, const unsigned short* __restrict__ BT,
    unsigned short* __restrict__ Cp, int K, int lda, int ldb, int ldc, int gx,
    const float* __restrict__ asv, const float* __restrict__ adv,
    float* __restrict__ als, float* __restrict__ ald, int H) {
  __shared__ unsigned short As[2][256 * 32];
  __shared__ unsigned short Bs[2][128 * 32];
  const int nwg = gridDim.x;
  const int chunk = nwg >> 3;
  const int bid = blockIdx.x;
  const int swz = (bid & 7) * chunk + (bid >> 3);
  const int bm = (swz / gx) * 256, bn = (swz % gx) * 128;
  const int tid = threadIdx.x;
  const int wv = tid >> 6, lane = tid & 63;  // wv 0..7
  const int sr = lane >> 2;
  const int sk = ((lane & 3) ^ ((lane >> 3) & 3)) * 8;
  const int r16 = lane & 15, kq = lane >> 4;
  const int slot8 = (kq ^ ((r16 >> 1) & 3)) * 8;
  const int wr = wv >> 1, wc = wv & 1;
  f32x4 acc[4][4];
#pragma unroll
  for (int i = 0; i < 4; ++i)
#pragma unroll
    for (int j = 0; j < 4; ++j) acc[i][j] = (f32x4){0.f, 0.f, 0.f, 0.f};

  const unsigned short* Abase = A + (size_t)bm * lda;
  const unsigned short* Bbase = BT + (size_t)bn * ldb;
  auto stage = [&](int buf, int k0) {
    gload_lds16(Abase + (size_t)(wv * 16 + sr) * lda + k0 + sk, &As[buf][wv * 512]);
    gload_lds16(Abase + (size_t)(128 + wv * 16 + sr) * lda + k0 + sk, &As[buf][4096 + wv * 512]);
    gload_lds16(Bbase + (size_t)(wv * 16 + sr) * ldb + k0 + sk, &Bs[buf][wv * 512]);
  };
  stage(0, 0);
  __syncthreads();
  int cur = 0;
  for (int k0 = 0; k0 < K; k0 += 32) {
    if (k0 + 32 < K) stage(cur ^ 1, k0 + 32);
    bf16x8 af[4], bfr[4];
#pragma unroll
    for (int i = 0; i < 4; ++i)
      af[i] = *(const bf16x8*)&As[cur][(wr * 64 + i * 16 + r16) * 32 + slot8];
#pragma unroll
    for (int j = 0; j < 4; ++j)
      bfr[j] = *(const bf16x8*)&Bs[cur][(wc * 64 + j * 16 + r16) * 32 + slot8];
#pragma unroll
    for (int i = 0; i < 4; ++i)
#pragma unroll
      for (int j = 0; j < 4; ++j)
        acc[i][j] = __builtin_amdgcn_mfma_f32_16x16x32_bf16(af[i], bfr[j], acc[i][j], 0, 0, 0);
    __syncthreads();
    cur ^= 1;
  }
#pragma unroll
  for (int i = 0; i < 4; ++i) {
    int row = bm + wr * 64 + i * 16 + kq * 4;
#pragma unroll
    for (int j = 0; j < 4; ++j) {
      int col = bn + wc * 64 + j * 16 + r16;
#pragma unroll
      for (int r = 0; r < 4; ++r)
        Cp[(size_t)(row + r) * ldc + col] = f2b(acc[i][j][r]);
    }
  }
  if (SC) {
    const int h = bn >> 7;
    float* scr = (float*)&As[0][0];  // 256 rows x 4 floats = 4KB
    float a_s[4], a_d[4];
#pragma unroll
    for (int j = 0; j < 4; ++j) {
      int cwh = wc * 64 + j * 16 + r16;
      a_s[j] = asv[h * 128 + cwh];
      a_d[j] = adv[h * 128 + cwh];
    }
#pragma unroll
    for (int i = 0; i < 4; ++i)
#pragma unroll
      for (int r = 0; r < 4; ++r) {
        float sp = 0.f, dp = 0.f;
#pragma unroll
        for (int j = 0; j < 4; ++j) {
          sp = fmaf(acc[i][j][r], a_s[j], sp);
          dp = fmaf(acc[i][j][r], a_d[j], dp);
        }
#pragma unroll
        for (int m = 1; m < 16; m <<= 1) {
          sp += __shfl_xor(sp, m);
          dp += __shfl_xor(dp, m);
        }
        if (r16 == 0) {
          int rl = wr * 64 + i * 16 + kq * 4 + r;
          scr[rl * 4 + wc * 2 + 0] = sp;
          scr[rl * 4 + wc * 2 + 1] = dp;
        }
      }
    __syncthreads();
    if (tid < 256) {
      float s = scr[tid * 4 + 0] + scr[tid * 4 + 2];
      float d = scr[tid * 4 + 1] + scr[tid * 4 + 3];
      als[(size_t)(bm + tid) * H + h] = s;
      ald[(size_t)(bm + tid) * H + h] = d;
    }
  }
}

// ---------------- batched runtime-act MFMA GEMM (2-phase dbuf) ----------------
struct GDesc {
  const unsigned short* A; const unsigned short* BT; const float* bias; void* C;
  int Nreal, K, lda, ldb, ldc, gx, zpad, act, obf, Mreal, wg_end;
};
struct GBatch { GDesc d[5]; };
__global__ __launch_bounds__(256) void gemm_batch(GBatch gb) {
  __shared__ unsigned short As[2][128 * 32];
  __shared__ unsigned short Bs[2][128 * 32];
  int bid = blockIdx.x;
  int di = 0;
  while (bid >= gb.d[di].wg_end) ++di;
  const GDesc& g = gb.d[di];
  int rel = bid - (di ? gb.d[di - 1].wg_end : 0);
  const int bm = (rel / g.gx) * 128, bn = (rel % g.gx) * 128;
  const int tid = threadIdx.x;
  const int wv = tid >> 6, lane = tid & 63;
  const int sr = lane >> 2;
  const int sk = ((lane & 3) ^ ((lane >> 3) & 3)) * 8;
  const int r16 = lane & 15, kq = lane >> 4;
  const int slot8 = (kq ^ ((r16 >> 1) & 3)) * 8;
  const int wr = wv >> 1, wc = wv & 1;
  f32x4 acc[4][4];
#pragma unroll
  for (int i = 0; i < 4; ++i)
#pragma unroll
    for (int j = 0; j < 4; ++j) acc[i][j] = (f32x4){0.f, 0.f, 0.f, 0.f};

  const unsigned short* Abase = g.A + (size_t)bm * g.lda;
  const unsigned short* Bbase = g.BT + (size_t)bn * g.ldb;
  auto stage = [&](int buf, int k0) {
    gload_lds16(Abase + (size_t)(wv * 16 + sr) * g.lda + k0 + sk, &As[buf][wv * 512]);
    gload_lds16(Abase + (size_t)(64 + wv * 16 + sr) * g.lda + k0 + sk, &As[buf][2048 + wv * 512]);
    gload_lds16(Bbase + (size_t)(wv * 16 + sr) * g.ldb + k0 + sk, &Bs[buf][wv * 512]);
    gload_lds16(Bbase + (size_t)(64 + wv * 16 + sr) * g.ldb + k0 + sk, &Bs[buf][2048 + wv * 512]);
  };
  stage(0, 0);
  __syncthreads();
  int cur = 0;
  for (int k0 = 0; k0 < g.K; k0 += 32) {
    if (k0 + 32 < g.K) stage(cur ^ 1, k0 + 32);
    bf16x8 af[4], bfr[4];
#pragma unroll
    for (int i = 0; i < 4; ++i)
      af[i] = *(const bf16x8*)&As[cur][(wr * 64 + i * 16 + r16) * 32 + slot8];
#pragma unroll
    for (int j = 0; j < 4; ++j)
      bfr[j] = *(const bf16x8*)&Bs[cur][(wc * 64 + j * 16 + r16) * 32 + slot8];
#pragma unroll
    for (int i = 0; i < 4; ++i)
#pragma unroll
      for (int j = 0; j < 4; ++j)
        acc[i][j] = __builtin_amdgcn_mfma_f32_16x16x32_bf16(af[i], bfr[j], acc[i][j], 0, 0, 0);
    __syncthreads();
    cur ^= 1;
  }
  if (g.act == 4) {
    if (wc == 0) {
#pragma unroll
      for (int i = 0; i < 4; ++i)
#pragma unroll
        for (int r = 0; r < 4; ++r) {
          int row = bm + wr * 64 + i * 16 + kq * 4 + r;
          float vv[4];
#pragma unroll
          for (int j = 0; j < 4; ++j) vv[j] = tanhf(acc[i][j][r] + g.bias[j * 16 + r16]);
          float ss = vv[0] * vv[0] + vv[1] * vv[1] + vv[2] * vv[2] + vv[3] * vv[3];
          ss += __shfl_xor(ss, 1);
          ss += __shfl_xor(ss, 2);
          ss += __shfl_xor(ss, 4);
          ss += __shfl_xor(ss, 8);
          float inv = 1.f / fmaxf(sqrtf(ss), 1e-12f);
          if (row < g.Mreal)
#pragma unroll
            for (int j = 0; j < 4; ++j)
              ((float*)g.C)[(size_t)row * g.ldc + j * 16 + r16] = vv[j] * inv;
        }
    }
    return;
  }
#pragma unroll
  for (int i = 0; i < 4; ++i) {
    int row = bm + wr * 64 + i * 16 + kq * 4;
#pragma unroll
    for (int j = 0; j < 4; ++j) {
      int col = bn + wc * 64 + j * 16 + r16;
      bool real = col < g.Nreal;
      if (!real && !g.zpad) continue;
      float bv = (g.bias && real) ? g.bias[col] : 0.f;
#pragma unroll
      for (int r = 0; r < 4; ++r) {
        float v = acc[i][j][r] + bv;
        if (g.act == 1) v = v > 0.f ? v : 0.f;
        else if (g.act == 2) v = tanhf(v);
        else if (g.act == 3) v = fabsf(tanhf(v));
        if (!real) v = 0.f;
        if (g.obf) ((unsigned short*)g.C)[(size_t)(row + r) * g.ldc + col] = f2b(v);
        else ((float*)g.C)[(size_t)(row + r) * g.ldc + col] = v;
      }
    }
  }
}

// ---------------- split-K MFMA GEMM for z1 (8 slices, single-buffer, f32 partials) ------
__global__ __launch_bounds__(256) void gemm_mfma_sk(
    const unsigned short* __restrict__ A, const unsigned short* __restrict__ BT,
    float* __restrict__ PART, int lda, int ldb, int ldc) {
  __shared__ unsigned short As[128 * 32];
  __shared__ unsigned short Bs[128 * 32];
  const int bid = blockIdx.x;
  const int s = bid & 7;
  const int pos = bid >> 3;
  const int bm = (pos / 13) * 128, bn = (pos % 13) * 128;
  const int base = s * 74 + (s < 6 ? s : 6);
  const int nsteps = 74 + (s < 6 ? 1 : 0);
  const int tid = threadIdx.x;
  const int wv = tid >> 6, lane = tid & 63;
  const int sr = lane >> 2;
  const int sk = ((lane & 3) ^ ((lane >> 3) & 3)) * 8;
  const int r16 = lane & 15, kq = lane >> 4;
  const int slot8 = (kq ^ ((r16 >> 1) & 3)) * 8;
  const int wr = wv >> 1, wc = wv & 1;
  f32x4 acc[4][4];
#pragma unroll
  for (int i = 0; i < 4; ++i)
#pragma unroll
    for (int j = 0; j < 4; ++j) acc[i][j] = (f32x4){0.f, 0.f, 0.f, 0.f};

  const unsigned short* Abase = A + (size_t)bm * lda;
  const unsigned short* Bbase = BT + (size_t)bn * ldb;
  for (int ks = 0; ks < nsteps; ++ks) {
    int k0 = (base + ks) * 32;
    gload_lds16(Abase + (size_t)(wv * 16 + sr) * lda + k0 + sk, &As[wv * 512]);
    gload_lds16(Abase + (size_t)(64 + wv * 16 + sr) * lda + k0 + sk, &As[2048 + wv * 512]);
    gload_lds16(Bbase + (size_t)(wv * 16 + sr) * ldb + k0 + sk, &Bs[wv * 512]);
    gload_lds16(Bbase + (size_t)(64 + wv * 16 + sr) * ldb + k0 + sk, &Bs[2048 + wv * 512]);
    __syncthreads();
    bf16x8 af[4], bfr[4];
#pragma unroll
    for (int i = 0; i < 4; ++i)
      af[i] = *(const bf16x8*)&As[(wr * 64 + i * 16 + r16) * 32 + slot8];
#pragma unroll
    for (int j = 0; j < 4; ++j)
      bfr[j] = *(const bf16x8*)&Bs[(wc * 64 + j * 16 + r16) * 32 + slot8];
#pragma unroll
    for (int i = 0; i < 4; ++i)
#pragma unroll
      for (int j = 0; j < 4; ++j)
        acc[i][j] = __builtin_amdgcn_mfma_f32_16x16x32_bf16(af[i], bfr[j], acc[i][j], 0, 0, 0);
    __syncthreads();
  }
  float* out = PART + (size_t)s * 1024 * ldc;
#pragma unroll
  for (int i = 0; i < 4; ++i) {
    int row = bm + wr * 64 + i * 16 + kq * 4;
#pragma unroll
    for (int j = 0; j < 4; ++j) {
      int col = bn + wc * 64 + j * 16 + r16;
      if (col >= 1600) continue;
#pragma unroll
      for (int r = 0; r < 4; ++r)
        out[(size_t)(row + r) * ldc + col] = acc[i][j][r];
    }
  }
}

// reduce 8 f32 K-slice partials + bias + relu -> ZB bf16 [1024][1664]
__global__ void zred(const float* __restrict__ PART, const float* __restrict__ bias,
                     unsigned short* __restrict__ ZB) {
  int g = blockIdx.x * blockDim.x + threadIdx.x;
  if (g >= 1024 * 1664 / 8) return;
  size_t base = (size_t)g * 8;
  int c0 = (int)(base % 1664);
  ushort8 o;
  if (c0 >= 1600) {
#pragma unroll
    for (int t = 0; t < 8; ++t) o[t] = 0;
  } else {
    float s[8] = {0.f, 0.f, 0.f, 0.f, 0.f, 0.f, 0.f, 0.f};
#pragma unroll
    for (int k = 0; k < 8; ++k) {
      const float* p = &PART[(size_t)k * 1024 * 1664 + base];
      float4 a = *(const float4*)p;
      float4 b = *(const float4*)(p + 4);
      s[0] += a.x; s[1] += a.y; s[2] += a.z; s[3] += a.w;
      s[4] += b.x; s[5] += b.y; s[6] += b.z; s[7] += b.w;
    }
#pragma unroll
    for (int t = 0; t < 8; ++t) {
      float v = s[t] + bias[c0 + t];
      o[t] = f2b(v > 0.f ? v : 0.f);
    }
  }
  *(ushort8*)&ZB[base] = o;
}

// ---------------- fused tail: agg GEMM -> LDS -> col GEMM -> |tanh| -> rownorm -> DN ----
__global__ __launch_bounds__(256) void tail_fused(
    const unsigned short* __restrict__ CAT192, const unsigned short* __restrict__ WTAGG,
    const float* __restrict__ agg_b, const unsigned short* __restrict__ CAT128,
    const unsigned short* __restrict__ WTCOL, const float* __restrict__ col_b,
    float* __restrict__ DN) {
  __shared__ unsigned short S1[128 * 32];
  __shared__ unsigned short S2[128 * 32];
  __shared__ unsigned short ACAT[128 * 128];
  const int bm = blockIdx.x * 128;
  const int tid = threadIdx.x;
  const int wv = tid >> 6, lane = tid & 63;
  const int sr = lane >> 2;
  const int sk = ((lane & 3) ^ ((lane >> 3) & 3)) * 8;
  const int r16 = lane & 15, kq = lane >> 4;
  const int slot8 = (kq ^ ((r16 >> 1) & 3)) * 8;
  const int wr = wv >> 1, wc = wv & 1;
  f32x4 acc[4][4];
#pragma unroll
  for (int i = 0; i < 4; ++i)
#pragma unroll
    for (int j = 0; j < 4; ++j) acc[i][j] = (f32x4){0.f, 0.f, 0.f, 0.f};

  const unsigned short* Abase = CAT192 + (size_t)bm * 192;
  for (int k0 = 0; k0 < 192; k0 += 32) {
    gload_lds16(Abase + (size_t)(wv * 16 + sr) * 192 + k0 + sk, &S1[wv * 512]);
    gload_lds16(Abase + (size_t)(64 + wv * 16 + sr) * 192 + k0 + sk, &S1[2048 + wv * 512]);
    gload_lds16(WTAGG + (size_t)(wv * 16 + sr) * 192 + k0 + sk, &S2[wv * 512]);
    gload_lds16(WTAGG + (size_t)(64 + wv * 16 + sr) * 192 + k0 + sk, &S2[2048 + wv * 512]);
    __syncthreads();
    bf16x8 af[4], bfr[4];
#pragma unroll
    for (int i = 0; i < 4; ++i)
      af[i] = *(const bf16x8*)&S1[(wr * 64 + i * 16 + r16) * 32 + slot8];
#pragma unroll
    for (int j = 0; j < 4; ++j)
      bfr[j] = *(const bf16x8*)&S2[(wc * 64 + j * 16 + r16) * 32 + slot8];
#pragma unroll
    for (int i = 0; i < 4; ++i)
#pragma unroll
      for (int j = 0; j < 4; ++j)
        acc[i][j] = __builtin_amdgcn_mfma_f32_16x16x32_bf16(af[i], bfr[j], acc[i][j], 0, 0, 0);
    __syncthreads();
  }
  if (wc == 0) {
#pragma unroll
    for (int i = 0; i < 4; ++i)
#pragma unroll
      for (int j = 0; j < 4; ++j) {
        int col = j * 16 + r16;
#pragma unroll
        for (int r = 0; r < 4; ++r) {
          int rl = wr * 64 + i * 16 + kq * 4 + r;
          ACAT[rl * 128 + col] = f2b(acc[i][j][r] + agg_b[col]);
        }
      }
  }
  for (int idx = tid; idx < 128 * 8; idx += 256) {
    int row = idx >> 3, c8 = (idx & 7) * 8;
    *(ushort8*)&ACAT[row * 128 + 64 + c8] =
        *(const ushort8*)&CAT128[(size_t)(bm + row) * 128 + 64 + c8];
  }
#pragma unroll
  for (int i = 0; i < 4; ++i)
#pragma unroll
    for (int j = 0; j < 4; ++j) acc[i][j] = (f32x4){0.f, 0.f, 0.f, 0.f};
  __syncthreads();

  for (int k0 = 0; k0 < 128; k0 += 32) {
    gload_lds16(WTCOL + (size_t)(wv * 16 + sr) * 128 + k0 + sk, &S1[wv * 512]);
    gload_lds16(WTCOL + (size_t)(64 + wv * 16 + sr) * 128 + k0 + sk, &S1[2048 + wv * 512]);
    __syncthreads();
    bf16x8 af[4], bfr[4];
#pragma unroll
    for (int i = 0; i < 4; ++i)
      af[i] = *(const bf16x8*)&ACAT[(wr * 64 + i * 16 + r16) * 128 + k0 + kq * 8];
#pragma unroll
    for (int j = 0; j < 4; ++j)
      bfr[j] = *(const bf16x8*)&S1[(wc * 64 + j * 16 + r16) * 32 + slot8];
#pragma unroll
    for (int i = 0; i < 4; ++i)
#pragma unroll
      for (int j = 0; j < 4; ++j)
        acc[i][j] = __builtin_amdgcn_mfma_f32_16x16x32_bf16(af[i], bfr[j], acc[i][j], 0, 0, 0);
    __syncthreads();
  }
  if (wc == 0) {
#pragma unroll
    for (int i = 0; i < 4; ++i)
#pragma unroll
      for (int r = 0; r < 4; ++r) {
        int row = bm + wr * 64 + i * 16 + kq * 4 + r;
        float vv[4];
#pragma unroll
        for (int j = 0; j < 4; ++j) vv[j] = fabsf(tanhf(acc[i][j][r] + col_b[j * 16 + r16]));
        float ss = vv[0] * vv[0] + vv[1] * vv[1] + vv[2] * vv[2] + vv[3] * vv[3];
        ss += __shfl_xor(ss, 1);
        ss += __shfl_xor(ss, 2);
        ss += __shfl_xor(ss, 4);
        ss += __shfl_xor(ss, 8);
        float inv = 1.f / fmaxf(sqrtf(ss), 1e-12f);
#pragma unroll
        for (int j = 0; j < 4; ++j)
          DN[(size_t)row * 64 + j * 16 + r16] = vv[j] * inv;
      }
  }
}

// ---------------- GAT pieces ----------------
__global__ void gat_scores_bf(const unsigned short* __restrict__ hlin,
                              const float* __restrict__ a_s, const float* __restrict__ a_d,
                              float* __restrict__ als, float* __restrict__ ald,
                              int H, int C, int tot) {
  int idx = blockIdx.x * blockDim.x + threadIdx.x;
  if (idx >= tot) return;
  int n = idx / H, h = idx - n * H;
  const unsigned short* base = hlin + (size_t)n * H * C + (size_t)h * C;
  const float* as = a_s + h * C;
  const float* ad = a_d + h * C;
  float ss = 0.f, sd = 0.f;
  for (int c = 0; c < C; c += 8) {
    ushort8 v = *(const ushort8*)(base + c);
#pragma unroll
    for (int t = 0; t < 8; ++t) {
      float f = b2f(v[t]);
      ss = fmaf(f, as[c + t], ss);
      sd = fmaf(f, ad[c + t], sd);
    }
  }
  als[idx] = ss;
  ald[idx] = sd;
}

// aggregate with INLINE attention; EPT=16 (chunks never straddle heads: C % 16 == 0).
template <int F, int C, int EPT>
__global__ __launch_bounds__(256) void gat_agg_v5(
    const int* __restrict__ rowptr, const int* __restrict__ srcl,
    const float* __restrict__ als, const float* __restrict__ ald,
    const unsigned short* __restrict__ hlin,
    const float* __restrict__ bias, unsigned short* __restrict__ out) {
  constexpr int H = F / C;
  constexpr int CPN = F / EPT;
  int gidx = blockIdx.x * 256 + threadIdx.x;
  if (gidx >= NN * CPN) return;
  int node = gidx / CPN;
  int c0 = (gidx - node * CPN) * EPT;
  int h = c0 / C;
  float aldv = ald[node * H + h];
  float s = 0.f;
  float acc[EPT];
#pragma unroll
  for (int t = 0; t < EPT; ++t) acc[t] = 0.f;
  int start = rowptr[node], end = rowptr[node + 1];
  for (int k = start; k < end; ++k) {
    int src = srcl[k];
    float e = als[src * H + h] + aldv;
    e = (e >= 0.f) ? e : 0.2f * e;
    float p = __expf(e);
    s += p;
    if (EPT == 8) {
      ushort8 hv = *(const ushort8*)(hlin + (size_t)src * F + c0);
#pragma unroll
      for (int t = 0; t < 8; ++t) acc[t] = fmaf(p, b2f(hv[t]), acc[t]);
    } else {
      ushort16 hv = *(const ushort16*)(hlin + (size_t)src * F + c0);
#pragma unroll
      for (int t = 0; t < 16; ++t) acc[t] = fmaf(p, b2f(hv[t]), acc[t]);
    }
  }
  float inv_s = 1.f / s;
#pragma unroll
  for (int t8 = 0; t8 < EPT / 8; ++t8) {
    ushort8 o;
#pragma unroll
    for (int t = 0; t < 8; ++t) {
      float val = acc[t8 * 8 + t] * inv_s + bias[c0 + t8 * 8 + t];
      o[t] = f2b(val > 0.f ? val : 0.f);
    }
    *(ushort8*)(out + (size_t)node * F + c0 + t8 * 8) = o;
  }
}

__global__ void pool_max(const unsigned short* __restrict__ xb,
                         unsigned short* __restrict__ xgb) {
  int g = blockIdx.x, c = threadIdx.x;  // 128 threads
  const unsigned short* base = xb + (size_t)g * 32 * 128 + c;
  float m = -FLT_MAX;
#pragma unroll 8
  for (int n = 0; n < 32; ++n) m = fmaxf(m, b2f(base[n * 128]));
  xgb[g * 128 + c] = f2b(m);
}

__global__ __launch_bounds__(256) void freq_k(const float* __restrict__ dn,
                                              const float* __restrict__ sn,
                                              float* __restrict__ C, int M, int N) {
  __shared__ float As[16][64];
  __shared__ float Bs[16][65];
  int tid = threadIdx.x;
  int tx = tid & 15, ty = tid >> 4;
  int bi = blockIdx.y * 16, bj = blockIdx.x * 16;
#pragma unroll
  for (int t = 0; t < 4; ++t) {
    int idx = tid * 4 + t;
    int r = idx >> 6, c = idx & 63;
    As[r][c] = (bi + r < M) ? dn[(bi + r) * 64 + c] : 0.f;
    Bs[r][c] = (bj + r < N) ? sn[(bj + r) * 64 + c] : 0.f;
  }
  __syncthreads();
  float acc = 0.f;
#pragma unroll
  for (int k = 0; k < 64; ++k) acc = fmaf(As[ty][k], Bs[tx][k], acc);
  if (bi + ty < M && bj + tx < N) C[(size_t)(bi + ty) * N + (bj + tx)] = 5.f * acc;
}

// ---------------- launch ----------------
extern "C" void kernel_launch(void* const* d_in, const int* in_sizes, int n_in,
                              void* d_out, int out_size, void* d_ws, size_t ws_size,
                              hipStream_t stream) {
  const float* x = (const float*)d_in[0];
  const int* ei = (const int*)d_in[1];
  const float* w = (const float*)d_in[3];
  const float* z = (const float*)d_in[4];
  const float* v = (const float*)d_in[5];
  const float* side = (const float*)d_in[6];
  const float* gW[4] = {(const float*)d_in[7], (const float*)d_in[11],
                        (const float*)d_in[15], (const float*)d_in[19]};
  const float* gas[4] = {(const float*)d_in[8], (const float*)d_in[12],
                         (const float*)d_in[16], (const float*)d_in[20]};
  const float* gad[4] = {(const float*)d_in[9], (const float*)d_in[13],
                         (const float*)d_in[17], (const float*)d_in[21]};
  const float* gb[4] = {(const float*)d_in[10], (const float*)d_in[14],
                        (const float*)d_in[18], (const float*)d_in[22]};
  const float* x5_W = (const float*)d_in[23]; const float* x5_b = (const float*)d_in[24];
  const float* x6_W = (const float*)d_in[25]; const float* x6_b = (const float*)d_in[26];
  const float* w1_W = (const float*)d_in[27]; const float* w1_b = (const float*)d_in[28];
  const float* w2_W = (const float*)d_in[29]; const float* w2_b = (const float*)d_in[30];
  const float* z1_W = (const float*)d_in[31]; const float* z1_b = (const float*)d_in[32];
  const float* z2_W = (const float*)d_in[33]; const float* z2_b = (const float*)d_in[34];
  const float* v1_W = (const float*)d_in[35]; const float* v1_b = (const float*)d_in[36];
  const float* v2_W = (const float*)d_in[37]; const float* v2_b = (const float*)d_in[38];
  const float* agg_W = (const float*)d_in[39]; const float* agg_b = (const float*)d_in[40];
  const float* col_W = (const float*)d_in[41]; const float* col_b = (const float*)d_in[42];
  const float* s1_W = (const float*)d_in[43]; const float* s1_b = (const float*)d_in[44];
  const float* s2_W = (const float*)d_in[45]; const float* s2_b = (const float*)d_in[46];

  char* wsb = (char*)d_ws;
  size_t off = 0;
  auto alloc = [&](size_t bytes) {
    void* p = wsb + off;
    off = (off + bytes + 255) & ~(size_t)255;
    return p;
  };
  unsigned short* HLIN = (unsigned short*)alloc((size_t)NN * 1024 * 2);
  unsigned short* XB = (unsigned short*)alloc((size_t)NN * 1024 * 2);
  unsigned short* WTZ = (unsigned short*)alloc((size_t)1664 * 19136 * 2);
  unsigned short* ZA = (unsigned short*)alloc((size_t)1024 * 19136 * 2);
  unsigned short* WT1 = (unsigned short*)alloc((size_t)768 * 128 * 2);
  unsigned short* WT2 = (unsigned short*)alloc((size_t)1024 * 768 * 2);
  unsigned short* WT3 = (unsigned short*)alloc((size_t)1024 * 1024 * 2);
  unsigned short* WT4 = (unsigned short*)alloc((size_t)128 * 1024 * 2);
  unsigned short* WTW1 = (unsigned short*)alloc((size_t)768 * 768 * 2);
  unsigned short* WTW2 = (unsigned short*)alloc((size_t)128 * 768 * 2);
  unsigned short* WTZ2 = (unsigned short*)alloc((size_t)128 * 1664 * 2);
  unsigned short* WTV1 = (unsigned short*)alloc((size_t)256 * 1024 * 2);
  unsigned short* WTV2 = (unsigned short*)alloc((size_t)128 * 256 * 2);
  unsigned short* WTX5 = (unsigned short*)alloc((size_t)128 * 128 * 2);
  unsigned short* WTX6 = (unsigned short*)alloc((size_t)128 * 64 * 2);
  unsigned short* WTAGG = (unsigned short*)alloc((size_t)128 * 192 * 2);
  unsigned short* WTCOL = (unsigned short*)alloc((size_t)128 * 128 * 2);
  unsigned short* WTS1 = (unsigned short*)alloc((size_t)128 * 1056 * 2);
  unsigned short* WTS2 = (unsigned short*)alloc((size_t)128 * 64 * 2);
  unsigned short* WB = (unsigned short*)alloc((size_t)1024 * 768 * 2);
  unsigned short* VB = (unsigned short*)alloc((size_t)1024 * 1024 * 2);
  unsigned short* SIDEB = (unsigned short*)alloc((size_t)1024 * 1056 * 2);
  unsigned short* XGB = (unsigned short*)alloc((size_t)1024 * 128 * 2);
  unsigned short* ZB = (unsigned short*)alloc((size_t)1024 * 1664 * 2);
  unsigned short* X5O = (unsigned short*)alloc((size_t)1024 * 128 * 2);
  unsigned short* WMID = (unsigned short*)alloc((size_t)1024 * 768 * 2);
  unsigned short* VMID = (unsigned short*)alloc((size_t)1024 * 256 * 2);
  unsigned short* SEMID = (unsigned short*)alloc((size_t)1024 * 128 * 2);
  unsigned short* CAT192 = (unsigned short*)alloc((size_t)1024 * 192 * 2);
  unsigned short* CAT128 = (unsigned short*)alloc((size_t)1024 * 128 * 2);
  float* ALS = (float*)alloc((size_t)NN * 8 * 4);
  float* ALD = (float*)alloc((size_t)NN * 8 * 4);
  int* DEG = (int*)alloc((size_t)NN * 4);
  int* ROWPTR = (int*)alloc((size_t)(NN + 1) * 4);
  int* CURSOR = (int*)alloc((size_t)NN * 4);
  int* SRCL = (int*)alloc((size_t)ETOT * 4);
  float* PART = (float*)HLIN;  // 8x1024x1664 f32 = 54.5MB over dead HLIN

  // CSR build
  hipLaunchKernelGGL(fill_i32, dim3((NN + 255) / 256), dim3(256), 0, stream, DEG, 0, NN);
  hipLaunchKernelGGL(count_deg, dim3((ETOT + 255) / 256), dim3(256), 0, stream, ei, DEG);
  hipLaunchKernelGGL(scan_deg, dim3(1), dim3(1024), 0, stream, DEG, ROWPTR, CURSOR);
  hipLaunchKernelGGL(fill_csr, dim3((ETOT + 255) / 256), dim3(256), 0, stream, ei, CURSOR, SRCL);

  // batched weight transposes
  {
    TBatch tb;
    int acc_wg = 0, i = 0;
    auto add = [&](const float* W, unsigned short* WT, int K, int N, int Kp, int Npad) {
      int gx = Npad / 32, gy = Kp / 32;
      acc_wg += gx * gy;
      tb.d[i++] = {W, WT, K, N, Kp, Npad, gx, acc_wg};
    };
    add(z1_W, WTZ, 19127, 1600, 19136, 1664);
    add(gW[0], WT1, 109, 768, 128, 768);
    add(gW[1], WT2, 768, 1024, 768, 1024);
    add(gW[2], WT3, 1024, 1024, 1024, 1024);
    add(gW[3], WT4, 1024, 128, 1024, 128);
    add(w1_W, WTW1, 750, 750, 768, 768);
    add(w2_W, WTW2, 750, 64, 768, 128);
    add(z2_W, WTZ2, 1600, 64, 1664, 128);
    add(v1_W, WTV1, 1024, 256, 1024, 256);
    add(v2_W, WTV2, 256, 64, 256, 128);
    add(x5_W, WTX5, 128, 64, 128, 128);
    add(x6_W, WTX6, 64, 64, 64, 128);
    add(agg_W, WTAGG, 192, 64, 192, 128);
    add(col_W, WTCOL, 128, 64, 128, 128);
    add(s1_W, WTS1, 1050, 64, 1056, 128);
    add(s2_W, WTS2, 64, 64, 64, 128);
    hipLaunchKernelGGL(transpose_batch, dim3(acc_wg), dim3(256), 0, stream, tb);
  }

  // batched input conversions
  {
    CBatch cb;
    int acc_wg = 0, i = 0;
    auto add = [&](const float* in, unsigned short* out, int rowsOut, int Rreal, int C, int Cp) {
      acc_wg += (int)(((size_t)rowsOut * Cp + 255) / 256);
      cb.d[i++] = {in, out, rowsOut, Rreal, C, Cp, acc_wg};
    };
    add(z, ZA, NB, NB, 19127, 19136);
    add(x, XB, NN, NN, 109, 128);
    add(w, WB, 1024, 1024, 750, 768);
    add(v, VB, 1024, 1024, 1024, 1024);
    add(side, SIDEB, 1024, 994, 1050, 1056);
    hipLaunchKernelGGL(conv_batch, dim3(acc_wg), dim3(256), 0, stream, cb);
  }

  // GAT layers (all node GEMMs use the 256x128 wide tile)
  const int Hs[4] = {8, 8, 8, 1};
  const int Kp[4] = {128, 768, 1024, 1024};
  const unsigned short* WTs[4] = {WT1, WT2, WT3, WT4};
  const int Fs[4] = {768, 1024, 1024, 128};
  for (int l = 0; l < 4; ++l) {
    int H = Hs[l], F = Fs[l], C = F / H;
    int gx = F / 128;
    int nwg = gx * (NN / 256);
    if (C == 128) {
      hipLaunchKernelGGL((gemm_mfma_wide<1>), dim3(nwg), dim3(512), 0, stream,
                         XB, WTs[l], HLIN, Kp[l], Kp[l], Kp[l], F, gx,
                         gas[l], gad[l], ALS, ALD, H);
    } else {
      hipLaunchKernelGGL((gemm_mfma_wide<0>), dim3(nwg), dim3(512), 0, stream,
                         XB, WTs[l], HLIN, Kp[l], Kp[l], Kp[l], F, gx,
                         (const float*)nullptr, (const float*)nullptr,
                         (float*)nullptr, (float*)nullptr, H);
      int totNH = NN * H;
      hipLaunchKernelGGL(gat_scores_bf, dim3((totNH + 255) / 256), dim3(256), 0, stream,
                         HLIN, gas[l], gad[l], ALS, ALD, H, C, totNH);
    }
    if (l == 0)
      hipLaunchKernelGGL((gat_agg_v5<768, 96, 16>), dim3(NN * 48 / 256), dim3(256), 0, stream,
                         ROWPTR, SRCL, ALS, ALD, HLIN, gb[l], XB);
    else if (l == 3)
      hipLaunchKernelGGL((gat_agg_v5<128, 128, 16>), dim3(NN * 8 / 256), dim3(256), 0, stream,
                         ROWPTR, SRCL, ALS, ALD, HLIN, gb[l], XB);
    else
      hipLaunchKernelGGL((gat_agg_v5<1024, 128, 16>), dim3(NN * 64 / 256), dim3(256), 0, stream,
                         ROWPTR, SRCL, ALS, ALD, HLIN, gb[l], XB);
  }

  // global max pool -> XGB bf16
  hipLaunchKernelGGL(pool_max, dim3(NB), dim3(128), 0, stream, XB, XGB);

  // B1: independent tail GEMMs {w1, v1, s1, x5}
  {
    GBatch b;
    int acc_wg = 0, i = 0;
    auto add = [&](const unsigned short* A, const unsigned short* BT, const float* bias,
                   void* C, int Npad, int Nreal, int K, int lda, int ldb, int ldc,
                   int zpad, int act, int obf, int Mreal) {
      int gx = Npad / 128;
      acc_wg += gx * 8;
      b.d[i++] = {A, BT, bias, C, Nreal, K, lda, ldb, ldc, gx, zpad, act, obf, Mreal, acc_wg};
    };
    add(WB, WTW1, w1_b, WMID, 768, 750, 768, 768, 768, 768, 1, 1, 1, 1024);
    add(VB, WTV1, v1_b, VMID, 256, 256, 1024, 1024, 1024, 256, 0, 1, 1, 1024);
    add(SIDEB, WTS1, s1_b, SEMID, 128, 64, 1056, 1056, 1056, 128, 1, 1, 1, 1024);
    add(XGB, WTX5, x5_b, X5O, 128, 64, 128, 128, 128, 128, 1, 1, 1, 1024);
    while (i < 5) { b.d[i] = b.d[i - 1]; b.d[i].wg_end = acc_wg; ++i; }
    hipLaunchKernelGGL(gemm_batch, dim3(acc_wg), dim3(256), 0, stream, b);
  }

  // z1 split-K (8 slices, f32 partials) + reduce -> ZB bf16
  hipLaunchKernelGGL(gemm_mfma_sk, dim3(832), dim3(256), 0, stream, ZA, WTZ, PART, 19136, 19136, 1664);
  hipLaunchKernelGGL(zred, dim3((1024 * 1664 / 8 + 255) / 256), dim3(256), 0, stream, PART, z1_b, ZB);

  // output pointers
  float* outp = (float*)d_out;
  float* DN = outp + (size_t)NB * NSIDE;
  float* SN = DN + (size_t)NB * 64;

  // B2: {x6, w2, z2, v2, s2(tanh+rownorm -> SN)}
  {
    GBatch b;
    int acc_wg = 0, i = 0;
    auto add = [&](const unsigned short* A, const unsigned short* BT, const float* bias,
                   void* C, int Npad, int Nreal, int K, int lda, int ldb, int ldc,
                   int zpad, int act, int obf, int Mreal) {
      int gx = Npad / 128;
      acc_wg += gx * 8;
      b.d[i++] = {A, BT, bias, C, Nreal, K, lda, ldb, ldc, gx, zpad, act, obf, Mreal, acc_wg};
    };
    add(X5O, WTX6, x6_b, CAT192 + 0, 128, 64, 64, 128, 64, 192, 0, 1, 1, 1024);
    add(WMID, WTW2, w2_b, CAT192 + 64, 128, 64, 768, 768, 768, 192, 0, 1, 1, 1024);
    add(ZB, WTZ2, z2_b, CAT192 + 128, 128, 64, 1664, 1664, 1664, 192, 0, 1, 1, 1024);
    add(VMID, WTV2, v2_b, CAT128 + 64, 128, 64, 256, 256, 256, 128, 0, 1, 1, 1024);
    add(SEMID, WTS2, s2_b, SN, 128, 64, 64, 128, 64, 64, 0, 4, 0, 994);
    hipLaunchKernelGGL(gemm_batch, dim3(acc_wg), dim3(256), 0, stream, b);
  }

  // fused tail: agg GEMM -> col GEMM -> |tanh| -> rownorm -> DN
  hipLaunchKernelGGL(tail_fused, dim3(8), dim3(256), 0, stream,
                     CAT192, WTAGG, agg_b, CAT128, WTCOL, col_b, DN);

  // similarity
  hipLaunchKernelGGL(freq_k, dim3((NSIDE + 15) / 16, (NB + 15) / 16), dim3(256), 0, stream,
                     DN, SN, outp, NB, NSIDE);
}